// Round 1
// baseline (773.624 us; speedup 1.0000x reference)
//
#include <hip/hip_runtime.h>
#include <math.h>

#define N_NODES 16000
#define F_IN    16
#define HID     256
#define OUTD    128
#define KNN     8
#define LAYERS  3
#define NEDGE   (N_NODES * KNN)
#define KTILE   2048

// ---------------------------------------------------------------------------
// kNN: for each query, the 9 smallest d2 = sq[i]+sq[j]-2*dot (including self),
// tie-broken by lower index (matches jax.lax.top_k), then drop the first.
// 8 threads per query scan interleaved residue classes; LDS merge at the end.
// ---------------------------------------------------------------------------
__global__ __launch_bounds__(256) void knn_kernel(const float* __restrict__ coords,
                                                  int* __restrict__ nbr) {
    __shared__ float4 tile[KTILE];  // 32 KB; reused as merge scratch afterwards
    int tid = threadIdx.x;
    int seg = tid & 7;
    int ql  = tid >> 3;                    // 0..31
    int q   = blockIdx.x * 32 + ql;

    float qx = coords[q * 3 + 0], qy = coords[q * 3 + 1], qz = coords[q * 3 + 2];
    float sqi = qx * qx + qy * qy + qz * qz;

    float bd[9]; int bi[9];
#pragma unroll
    for (int p = 0; p < 9; ++p) { bd[p] = INFINITY; bi[p] = 0x7fffffff; }

    for (int base = 0; base < N_NODES; base += KTILE) {
        int cnt = min(KTILE, N_NODES - base);
        __syncthreads();
        for (int l = tid; l < cnt; l += 256) {
            int p = base + l;
            float cx = coords[p * 3 + 0], cy = coords[p * 3 + 1], cz = coords[p * 3 + 2];
            tile[l] = make_float4(cx, cy, cz, cx * cx + cy * cy + cz * cz);
        }
        __syncthreads();
        for (int m = seg; m < cnt; m += 8) {
            float4 c = tile[m];
            float t  = qx * c.x + qy * c.y + qz * c.z;
            float d2 = sqi + c.w - 2.0f * t;
            if (d2 < bd[8]) {                       // strict: ties keep lower index
                int j = base + m;
                // branchless sorted insert, all indices compile-time (stays in VGPRs)
#pragma unroll
                for (int p = 8; p >= 1; --p) {
                    bool  up = d2 < bd[p - 1];
                    float nd = up ? bd[p - 1] : (d2 < bd[p] ? d2 : bd[p]);
                    int   ni = up ? bi[p - 1] : (d2 < bd[p] ? j  : bi[p]);
                    bd[p] = nd; bi[p] = ni;
                }
                if (d2 < bd[0]) { bd[0] = d2; bi[0] = j; }
            }
        }
    }
    __syncthreads();
    float* md    = (float*)tile;           // 256*9 floats = 9 KB
    int*   mi    = (int*)(md + 256 * 9);   // 9 KB
    int*   heads = mi + 256 * 9;           // 1 KB
#pragma unroll
    for (int p = 0; p < 9; ++p) { md[tid * 9 + p] = bd[p]; mi[tid * 9 + p] = bi[p]; }
    heads[tid] = 0;
    __syncthreads();
    if (seg == 0) {
        int hbase = ql * 8;                // rows hbase..hbase+7 hold this query's 8 lists
#pragma unroll 1
        for (int pick = 0; pick < 9; ++pick) {
            float bestd = INFINITY; int besti = 0x7fffffff; int bests = 0;
            for (int s = 0; s < 8; ++s) {
                int hh = heads[hbase + s];
                if (hh < 9) {
                    int row = (hbase + s) * 9 + hh;
                    float dd = md[row]; int ii = mi[row];
                    if (dd < bestd || (dd == bestd && ii < besti)) {
                        bestd = dd; besti = ii; bests = s;
                    }
                }
            }
            heads[hbase + bests] = heads[hbase + bests] + 1;
            if (pick > 0) nbr[q * 8 + (pick - 1)] = besti;   // drop pick 0 (self)
        }
    }
}

// ---------------------------------------------------------------------------
// CSR build: indegree count -> exclusive scan (+norm) -> fill
// ---------------------------------------------------------------------------
__global__ void count_kernel(const int* __restrict__ nbr, int* __restrict__ indeg) {
    int e = blockIdx.x * blockDim.x + threadIdx.x;
    if (e < NEDGE) atomicAdd(&indeg[nbr[e]], 1);
}

__global__ __launch_bounds__(256) void scan_kernel(const int* __restrict__ indeg,
                                                   int* __restrict__ offs,
                                                   float* __restrict__ norm) {
    __shared__ int ssum[256];
    int t = threadIdx.x;
    const int CH = 63;                      // 256*63 = 16128 >= 16000
    int base = t * CH;
    int s = 0;
    for (int c = 0; c < CH; ++c) {
        int idx = base + c;
        if (idx < N_NODES) s += indeg[idx];
    }
    ssum[t] = s;
    __syncthreads();
    for (int d = 1; d < 256; d <<= 1) {
        int v = (t >= d) ? ssum[t - d] : 0;
        __syncthreads();
        ssum[t] += v;
        __syncthreads();
    }
    int run = ssum[t] - s;                  // exclusive prefix of this chunk
    for (int c = 0; c < CH; ++c) {
        int idx = base + c;
        if (idx < N_NODES) {
            int dg = indeg[idx];
            offs[idx] = run;
            run += dg;
            norm[idx] = rsqrtf((float)(1 + dg));   // deg = 1 + indegree
        }
    }
    if (t == 255) offs[N_NODES] = ssum[255];
}

__global__ void fill_kernel(const int* __restrict__ nbr, const int* __restrict__ offs,
                            int* __restrict__ cursor, int* __restrict__ adj) {
    int e = blockIdx.x * blockDim.x + threadIdx.x;
    if (e < NEDGE) {
        int d   = nbr[e];
        int src = e >> 3;
        int pos = atomicAdd(&cursor[d], 1);
        adj[offs[d] + pos] = src;
    }
}

// ---------------------------------------------------------------------------
// f32 GEMM: C[M x 256] = A[M x K] @ B[K x 256], optional per-row scale and
// per-col bias.  64x64 tile, BK=16, 256 threads, 4x4 micro-tile per thread.
// ---------------------------------------------------------------------------
__global__ __launch_bounds__(256) void gemm_kernel(const float* __restrict__ A,
                                                   const float* __restrict__ B,
                                                   float* __restrict__ C,
                                                   int K,
                                                   const float* __restrict__ rowscale,
                                                   const float* __restrict__ bias) {
    __shared__ float As[16][68];   // padded: staging writes 2-way max
    __shared__ float Bs[16][64];
    int tid = threadIdx.x;
    int rowBase = blockIdx.x * 64;
    int colBase = blockIdx.y * 64;
    int rg = tid >> 4;             // 0..15
    int cg = tid & 15;             // 0..15

    int ar = tid >> 2;             // 0..63 (A stage row)
    int ac = (tid & 3) * 4;        // 0,4,8,12 (A stage col4)
    int bk = tid >> 4;             // 0..15 (B stage row)
    int bn = (tid & 15) * 4;       // B stage col4

    float4 acc0 = {0,0,0,0}, acc1 = {0,0,0,0}, acc2 = {0,0,0,0}, acc3 = {0,0,0,0};

    for (int kb = 0; kb < K; kb += 16) {
        float4 av = *(const float4*)(A + (size_t)(rowBase + ar) * K + kb + ac);
        float4 bv = *(const float4*)(B + (size_t)(kb + bk) * HID + colBase + bn);
        __syncthreads();
        As[ac + 0][ar] = av.x; As[ac + 1][ar] = av.y;
        As[ac + 2][ar] = av.z; As[ac + 3][ar] = av.w;
        *(float4*)&Bs[bk][bn] = bv;
        __syncthreads();
#pragma unroll
        for (int k = 0; k < 16; ++k) {
            float4 a = *(const float4*)&As[k][rg * 4];
            float4 b = *(const float4*)&Bs[k][cg * 4];
            acc0.x = fmaf(a.x, b.x, acc0.x); acc0.y = fmaf(a.x, b.y, acc0.y);
            acc0.z = fmaf(a.x, b.z, acc0.z); acc0.w = fmaf(a.x, b.w, acc0.w);
            acc1.x = fmaf(a.y, b.x, acc1.x); acc1.y = fmaf(a.y, b.y, acc1.y);
            acc1.z = fmaf(a.y, b.z, acc1.z); acc1.w = fmaf(a.y, b.w, acc1.w);
            acc2.x = fmaf(a.z, b.x, acc2.x); acc2.y = fmaf(a.z, b.y, acc2.y);
            acc2.z = fmaf(a.z, b.z, acc2.z); acc2.w = fmaf(a.z, b.w, acc2.w);
            acc3.x = fmaf(a.w, b.x, acc3.x); acc3.y = fmaf(a.w, b.y, acc3.y);
            acc3.z = fmaf(a.w, b.z, acc3.z); acc3.w = fmaf(a.w, b.w, acc3.w);
        }
        __syncthreads();
    }

    int row = rowBase + rg * 4;
    int col = colBase + cg * 4;
    float s0 = 1.f, s1 = 1.f, s2 = 1.f, s3 = 1.f;
    if (rowscale) { s0 = rowscale[row]; s1 = rowscale[row + 1];
                    s2 = rowscale[row + 2]; s3 = rowscale[row + 3]; }
    float4 bb = {0,0,0,0};
    if (bias) bb = *(const float4*)(bias + col);

    float4 v;
    v.x = acc0.x * s0 + bb.x; v.y = acc0.y * s0 + bb.y;
    v.z = acc0.z * s0 + bb.z; v.w = acc0.w * s0 + bb.w;
    *(float4*)(C + (size_t)(row + 0) * HID + col) = v;
    v.x = acc1.x * s1 + bb.x; v.y = acc1.y * s1 + bb.y;
    v.z = acc1.z * s1 + bb.z; v.w = acc1.w * s1 + bb.w;
    *(float4*)(C + (size_t)(row + 1) * HID + col) = v;
    v.x = acc2.x * s2 + bb.x; v.y = acc2.y * s2 + bb.y;
    v.z = acc2.z * s2 + bb.z; v.w = acc2.w * s2 + bb.w;
    *(float4*)(C + (size_t)(row + 2) * HID + col) = v;
    v.x = acc3.x * s3 + bb.x; v.y = acc3.y * s3 + bb.y;
    v.z = acc3.z * s3 + bb.z; v.w = acc3.w * s3 + bb.w;
    *(float4*)(C + (size_t)(row + 3) * HID + col) = v;
}

// ---------------------------------------------------------------------------
// Aggregation: h[j] = relu(norm[j]*(u[j] + sum_{i->j} u[i]) + b), u = (h@W)*norm
// One wave per node, float4 per lane. u (16 MB) is L2-resident.
// ---------------------------------------------------------------------------
__global__ __launch_bounds__(256) void agg_kernel(const float* __restrict__ u,
                                                  const float* __restrict__ norm,
                                                  const float* __restrict__ bias,
                                                  const int* __restrict__ offs,
                                                  const int* __restrict__ adj,
                                                  float* __restrict__ hout) {
    int node = blockIdx.x * 4 + (threadIdx.x >> 6);
    int lane = threadIdx.x & 63;
    const float4* up = (const float4*)u;
    float4 acc = up[(size_t)node * 64 + lane];            // self term
    int e0 = offs[node], e1 = offs[node + 1];
    for (int e = e0; e < e1; ++e) {
        int s = adj[e];
        float4 v = up[(size_t)s * 64 + lane];
        acc.x += v.x; acc.y += v.y; acc.z += v.z; acc.w += v.w;
    }
    float nm = norm[node];
    float4 bb = ((const float4*)bias)[lane];
    float4 r;
    r.x = fmaxf(fmaf(nm, acc.x, bb.x), 0.0f);
    r.y = fmaxf(fmaf(nm, acc.y, bb.y), 0.0f);
    r.z = fmaxf(fmaf(nm, acc.z, bb.z), 0.0f);
    r.w = fmaxf(fmaf(nm, acc.w, bb.w), 0.0f);
    ((float4*)hout)[(size_t)node * 64 + lane] = r;
}

// ---------------------------------------------------------------------------
// Mean pool (partial sums + atomics) and 2-layer MLP head
// ---------------------------------------------------------------------------
__global__ __launch_bounds__(256) void pool_kernel(const float* __restrict__ h,
                                                   float* __restrict__ gsum) {
    int t = threadIdx.x;
    float acc = 0.f;
    int start = blockIdx.x * 250;
    for (int i = 0; i < 250; ++i) acc += h[(size_t)(start + i) * HID + t];
    atomicAdd(&gsum[t], acc);
}

__global__ __launch_bounds__(128) void head_kernel(const float* __restrict__ gsum,
                                                   const float* __restrict__ Wp1,
                                                   const float* __restrict__ bp1,
                                                   const float* __restrict__ Wp2,
                                                   const float* __restrict__ bp2,
                                                   float* __restrict__ out) {
    __shared__ float gl[256];
    __shared__ float hid[128];
    int t = threadIdx.x;
    const float inv = 1.0f / 16000.0f;
    gl[t]       = gsum[t]       * inv;
    gl[t + 128] = gsum[t + 128] * inv;
    __syncthreads();
    float a = bp1[t];
    for (int k = 0; k < 256; ++k) a = fmaf(gl[k], Wp1[k * 128 + t], a);
    hid[t] = fmaxf(a, 0.0f);
    __syncthreads();
    float o = bp2[t];
    for (int k = 0; k < 128; ++k) o = fmaf(hid[k], Wp2[k * 128 + t], o);
    out[t] = o;
}

// ---------------------------------------------------------------------------
extern "C" void kernel_launch(void* const* d_in, const int* in_sizes, int n_in,
                              void* d_out, int out_size, void* d_ws, size_t ws_size,
                              hipStream_t stream) {
    const float* x      = (const float*)d_in[0];
    const float* coords = (const float*)d_in[1];
    const float* We     = (const float*)d_in[2];
    const float* be     = (const float*)d_in[3];
    const float* gnn_W  = (const float*)d_in[4];
    const float* gnn_b  = (const float*)d_in[5];
    const float* Wp1    = (const float*)d_in[6];
    const float* bp1    = (const float*)d_in[7];
    const float* Wp2    = (const float*)d_in[8];
    const float* bp2    = (const float*)d_in[9];
    float* out = (float*)d_out;

    char* ws = (char*)d_ws;
    float* h     = (float*)(ws + 0);          // 16,384,000 B
    float* u     = (float*)(ws + 16384000);   // 16,384,000 B
    int*   nbr   = (int*)  (ws + 32768000);   // 512,000 B
    int*   adj   = (int*)  (ws + 33280000);   // 512,000 B
    int*   indeg = (int*)  (ws + 33792000);   // 64,000 B
    int*   offs  = (int*)  (ws + 33856000);   // 64,004 B (padded to 64,256)
    int*   cursor= (int*)  (ws + 33920256);   // 64,000 B
    float* norm  = (float*)(ws + 33984256);   // 64,000 B
    float* gsum  = (float*)(ws + 34048256);   // 1,024 B

    hipMemsetAsync(indeg,  0, N_NODES * 4, stream);
    hipMemsetAsync(cursor, 0, N_NODES * 4, stream);
    hipMemsetAsync(gsum,   0, HID * 4, stream);

    knn_kernel<<<N_NODES / 32, 256, 0, stream>>>(coords, nbr);
    count_kernel<<<(NEDGE + 255) / 256, 256, 0, stream>>>(nbr, indeg);
    scan_kernel<<<1, 256, 0, stream>>>(indeg, offs, norm);
    fill_kernel<<<(NEDGE + 255) / 256, 256, 0, stream>>>(nbr, offs, cursor, adj);

    dim3 g1(N_NODES / 64, HID / 64);
    gemm_kernel<<<g1, 256, 0, stream>>>(x, We, h, F_IN, nullptr, be);
    for (int l = 0; l < LAYERS; ++l) {
        gemm_kernel<<<g1, 256, 0, stream>>>(h, gnn_W + (size_t)l * HID * HID, u,
                                            HID, norm, nullptr);
        agg_kernel<<<N_NODES / 4, 256, 0, stream>>>(u, norm, gnn_b + (size_t)l * HID,
                                                    offs, adj, h);
    }
    pool_kernel<<<64, 256, 0, stream>>>(h, gsum);
    head_kernel<<<1, 128, 0, stream>>>(gsum, Wp1, bp1, Wp2, bp2, out);
}

// Round 2
// 664.340 us; speedup vs baseline: 1.1645x; 1.1645x over previous
//
#include <hip/hip_runtime.h>
#include <math.h>

#define N_NODES 16000
#define F_IN    16
#define HID     256
#define OUTD    128
#define KNN     8
#define LAYERS  3
#define NEDGE   (N_NODES * KNN)

#define NPAD    16384
#define PARTS   4
#define PART_SZ (NPAD / PARTS)   // 4096
#define KT      1024             // candidates per LDS tile

// ---------------------------------------------------------------------------
// Pack candidates: cand[i] = (-2x, -2y, -2z, |c|^2); INF-padded to NPAD.
// Shifted distance d' = d2 - |q|^2 = qx*(-2x)+qy*(-2y)+qz*(-2z)+|c|^2:
// 3 chained fmas, per-query-monotone, so ordering (and (d,idx) ties) match.
// ---------------------------------------------------------------------------
__global__ __launch_bounds__(256) void prep_kernel(const float* __restrict__ coords,
                                                   float4* __restrict__ cand) {
    int i = blockIdx.x * 256 + threadIdx.x;
    if (i >= NPAD) return;
    if (i < N_NODES) {
        float x = coords[3 * i], y = coords[3 * i + 1], z = coords[3 * i + 2];
        cand[i] = make_float4(-2.f * x, -2.f * y, -2.f * z, x * x + y * y + z * z);
    } else {
        cand[i] = make_float4(0.f, 0.f, 0.f, INFINITY);
    }
}

// branchless sorted-insert into 9-deep (asc) list; no-op when d2 >= bd[8];
// strict < keeps earlier (lower) index on ties. All indices compile-time.
#define INS9(bd, bi, d2, j)                                          \
    {                                                                \
        _Pragma("unroll")                                            \
        for (int p = 8; p >= 1; --p) {                               \
            bool  up = (d2) < bd[p - 1];                             \
            bool  in = (d2) < bd[p];                                 \
            float nd = up ? bd[p - 1] : (in ? (d2) : bd[p]);         \
            int   ni = up ? bi[p - 1] : (in ? (j)  : bi[p]);         \
            bd[p] = nd; bi[p] = ni;                                  \
        }                                                            \
        if ((d2) < bd[0]) { bd[0] = (d2); bi[0] = (j); }             \
    }

// ---------------------------------------------------------------------------
// kNN partial pass: block = (query-group of 64, part of 4096 candidates).
// 8 segments/query, 2 queries/thread, unroll-4 candidates per iteration.
// Ends with an in-LDS 8-list merge -> top-9 per (query, part).
// ---------------------------------------------------------------------------
__global__ __launch_bounds__(256, 4) void knn_part_kernel(const float* __restrict__ coords,
                                                          const float4* __restrict__ cand,
                                                          float* __restrict__ pd,
                                                          int* __restrict__ pi) {
    __shared__ float4 smemv[2304];            // 36,864 B: tile then merge scratch
    float4* tile = smemv;
    int tid   = threadIdx.x;
    int seg   = tid & 7;
    int qslot = tid >> 3;                     // 0..31
    int qbase = blockIdx.x * 64;
    int part  = blockIdx.y;

    int q0 = qbase + qslot;
    int q1 = q0 + 32;
    float qx0 = coords[q0 * 3], qy0 = coords[q0 * 3 + 1], qz0 = coords[q0 * 3 + 2];
    float qx1 = coords[q1 * 3], qy1 = coords[q1 * 3 + 1], qz1 = coords[q1 * 3 + 2];

    float bd0[9], bd1[9]; int bi0[9], bi1[9];
#pragma unroll
    for (int p = 0; p < 9; ++p) {
        bd0[p] = INFINITY; bi0[p] = 0x7fffffff;
        bd1[p] = INFINITY; bi1[p] = 0x7fffffff;
    }

    int pbase = part * PART_SZ;
    for (int t = 0; t < PART_SZ / KT; ++t) {
        __syncthreads();
        for (int l = tid; l < KT; l += 256) tile[l] = cand[pbase + t * KT + l];
        __syncthreads();
        int gb = pbase + t * KT;
        for (int m = seg; m < KT; m += 32) {
            float4 c0 = tile[m];
            float4 c1 = tile[m + 8];
            float4 c2 = tile[m + 16];
            float4 c3 = tile[m + 24];
            float d00 = fmaf(qx0, c0.x, fmaf(qy0, c0.y, fmaf(qz0, c0.z, c0.w)));
            float d01 = fmaf(qx0, c1.x, fmaf(qy0, c1.y, fmaf(qz0, c1.z, c1.w)));
            float d02 = fmaf(qx0, c2.x, fmaf(qy0, c2.y, fmaf(qz0, c2.z, c2.w)));
            float d03 = fmaf(qx0, c3.x, fmaf(qy0, c3.y, fmaf(qz0, c3.z, c3.w)));
            float d10 = fmaf(qx1, c0.x, fmaf(qy1, c0.y, fmaf(qz1, c0.z, c0.w)));
            float d11 = fmaf(qx1, c1.x, fmaf(qy1, c1.y, fmaf(qz1, c1.z, c1.w)));
            float d12 = fmaf(qx1, c2.x, fmaf(qy1, c2.y, fmaf(qz1, c2.z, c2.w)));
            float d13 = fmaf(qx1, c3.x, fmaf(qy1, c3.y, fmaf(qz1, c3.z, c3.w)));
            int j0 = gb + m, j1 = j0 + 8, j2 = j0 + 16, j3 = j0 + 24;
            if (fminf(fminf(d00, d01), fminf(d02, d03)) < bd0[8]) {
                INS9(bd0, bi0, d00, j0); INS9(bd0, bi0, d01, j1);
                INS9(bd0, bi0, d02, j2); INS9(bd0, bi0, d03, j3);
            }
            if (fminf(fminf(d10, d11), fminf(d12, d13)) < bd1[8]) {
                INS9(bd1, bi1, d10, j0); INS9(bd1, bi1, d11, j1);
                INS9(bd1, bi1, d12, j2); INS9(bd1, bi1, d13, j3);
            }
        }
    }

    // dump lists: row r = qidx_in_block*8 + seg (512 rows x 9)
    __syncthreads();
    float* md = (float*)smemv;               // 4608 floats
    int*   mi = (int*)smemv + 4608;          // 4608 ints
#pragma unroll
    for (int p = 0; p < 9; ++p) {
        md[(qslot * 8 + seg) * 9 + p]        = bd0[p];
        mi[(qslot * 8 + seg) * 9 + p]        = bi0[p];
        md[((32 + qslot) * 8 + seg) * 9 + p] = bd1[p];
        mi[((32 + qslot) * 8 + seg) * 9 + p] = bi1[p];
    }
    __syncthreads();

    if (tid < 64) {                           // thread t merges query qbase+t
        int q = qbase + tid;
        int hs[8];
#pragma unroll
        for (int s = 0; s < 8; ++s) hs[s] = 0;
#pragma unroll 1
        for (int pick = 0; pick < 9; ++pick) {
            float bestd = INFINITY; int besti = 0x7fffffff; int bs = 0;
#pragma unroll
            for (int s = 0; s < 8; ++s) {
                int hh = hs[s];
                int idx = (tid * 8 + s) * 9 + (hh < 9 ? hh : 8);
                float dd = md[idx]; int ii = mi[idx];
                bool ok = (hh < 9) && ((dd < bestd) || (dd == bestd && ii < besti));
                bestd = ok ? dd : bestd; besti = ok ? ii : besti; bs = ok ? s : bs;
            }
#pragma unroll
            for (int s = 0; s < 8; ++s) hs[s] += (s == bs) ? 1 : 0;
            pd[(q * PARTS + part) * 9 + pick] = bestd;
            pi[(q * PARTS + part) * 9 + pick] = besti;
        }
    }
}

// ---------------------------------------------------------------------------
// Final merge: per query, 4-way merge of sorted part lists; picks 1..8 -> nbr
// ---------------------------------------------------------------------------
__global__ __launch_bounds__(256) void knn_merge_kernel(const float* __restrict__ pd,
                                                        const int* __restrict__ pi,
                                                        int* __restrict__ nbr) {
    int q = blockIdx.x * 256 + threadIdx.x;
    if (q >= N_NODES) return;
    int hs[4];
#pragma unroll
    for (int p = 0; p < 4; ++p) hs[p] = 0;
#pragma unroll 1
    for (int pick = 0; pick < 9; ++pick) {
        float bestd = INFINITY; int besti = 0x7fffffff; int bp = 0;
#pragma unroll
        for (int p = 0; p < 4; ++p) {
            int hh = hs[p];
            int idx = (q * PARTS + p) * 9 + (hh < 9 ? hh : 8);
            float dd = pd[idx]; int ii = pi[idx];
            bool ok = (hh < 9) && ((dd < bestd) || (dd == bestd && ii < besti));
            bestd = ok ? dd : bestd; besti = ok ? ii : besti; bp = ok ? p : bp;
        }
#pragma unroll
        for (int p = 0; p < 4; ++p) hs[p] += (p == bp) ? 1 : 0;
        if (pick > 0) nbr[q * 8 + pick - 1] = besti;
    }
}

// ---------------------------------------------------------------------------
// CSR build: indegree count -> exclusive scan (+norm) -> fill
// ---------------------------------------------------------------------------
__global__ void count_kernel(const int* __restrict__ nbr, int* __restrict__ indeg) {
    int e = blockIdx.x * blockDim.x + threadIdx.x;
    if (e < NEDGE) atomicAdd(&indeg[nbr[e]], 1);
}

__global__ __launch_bounds__(256) void scan_kernel(const int* __restrict__ indeg,
                                                   int* __restrict__ offs,
                                                   float* __restrict__ norm) {
    __shared__ int ssum[256];
    int t = threadIdx.x;
    const int CH = 63;
    int base = t * CH;
    int s = 0;
    for (int c = 0; c < CH; ++c) {
        int idx = base + c;
        if (idx < N_NODES) s += indeg[idx];
    }
    ssum[t] = s;
    __syncthreads();
    for (int d = 1; d < 256; d <<= 1) {
        int v = (t >= d) ? ssum[t - d] : 0;
        __syncthreads();
        ssum[t] += v;
        __syncthreads();
    }
    int run = ssum[t] - s;
    for (int c = 0; c < CH; ++c) {
        int idx = base + c;
        if (idx < N_NODES) {
            int dg = indeg[idx];
            offs[idx] = run;
            run += dg;
            norm[idx] = rsqrtf((float)(1 + dg));
        }
    }
    if (t == 255) offs[N_NODES] = ssum[255];
}

__global__ void fill_kernel(const int* __restrict__ nbr, const int* __restrict__ offs,
                            int* __restrict__ cursor, int* __restrict__ adj) {
    int e = blockIdx.x * blockDim.x + threadIdx.x;
    if (e < NEDGE) {
        int d   = nbr[e];
        int src = e >> 3;
        int pos = atomicAdd(&cursor[d], 1);
        adj[offs[d] + pos] = src;
    }
}

// ---------------------------------------------------------------------------
// f32 GEMM: C[M x 256] = A[M x K] @ B[K x 256], optional per-row scale and
// per-col bias.  64x64 tile, BK=16, 256 threads, 4x4 micro-tile per thread.
// ---------------------------------------------------------------------------
__global__ __launch_bounds__(256) void gemm_kernel(const float* __restrict__ A,
                                                   const float* __restrict__ B,
                                                   float* __restrict__ C,
                                                   int K,
                                                   const float* __restrict__ rowscale,
                                                   const float* __restrict__ bias) {
    __shared__ float As[16][68];
    __shared__ float Bs[16][64];
    int tid = threadIdx.x;
    int rowBase = blockIdx.x * 64;
    int colBase = blockIdx.y * 64;
    int rg = tid >> 4;
    int cg = tid & 15;

    int ar = tid >> 2;
    int ac = (tid & 3) * 4;
    int bk = tid >> 4;
    int bn = (tid & 15) * 4;

    float4 acc0 = {0,0,0,0}, acc1 = {0,0,0,0}, acc2 = {0,0,0,0}, acc3 = {0,0,0,0};

    for (int kb = 0; kb < K; kb += 16) {
        float4 av = *(const float4*)(A + (size_t)(rowBase + ar) * K + kb + ac);
        float4 bv = *(const float4*)(B + (size_t)(kb + bk) * HID + colBase + bn);
        __syncthreads();
        As[ac + 0][ar] = av.x; As[ac + 1][ar] = av.y;
        As[ac + 2][ar] = av.z; As[ac + 3][ar] = av.w;
        *(float4*)&Bs[bk][bn] = bv;
        __syncthreads();
#pragma unroll
        for (int k = 0; k < 16; ++k) {
            float4 a = *(const float4*)&As[k][rg * 4];
            float4 b = *(const float4*)&Bs[k][cg * 4];
            acc0.x = fmaf(a.x, b.x, acc0.x); acc0.y = fmaf(a.x, b.y, acc0.y);
            acc0.z = fmaf(a.x, b.z, acc0.z); acc0.w = fmaf(a.x, b.w, acc0.w);
            acc1.x = fmaf(a.y, b.x, acc1.x); acc1.y = fmaf(a.y, b.y, acc1.y);
            acc1.z = fmaf(a.y, b.z, acc1.z); acc1.w = fmaf(a.y, b.w, acc1.w);
            acc2.x = fmaf(a.z, b.x, acc2.x); acc2.y = fmaf(a.z, b.y, acc2.y);
            acc2.z = fmaf(a.z, b.z, acc2.z); acc2.w = fmaf(a.z, b.w, acc2.w);
            acc3.x = fmaf(a.w, b.x, acc3.x); acc3.y = fmaf(a.w, b.y, acc3.y);
            acc3.z = fmaf(a.w, b.z, acc3.z); acc3.w = fmaf(a.w, b.w, acc3.w);
        }
        __syncthreads();
    }

    int row = rowBase + rg * 4;
    int col = colBase + cg * 4;
    float s0 = 1.f, s1 = 1.f, s2 = 1.f, s3 = 1.f;
    if (rowscale) { s0 = rowscale[row]; s1 = rowscale[row + 1];
                    s2 = rowscale[row + 2]; s3 = rowscale[row + 3]; }
    float4 bb = {0,0,0,0};
    if (bias) bb = *(const float4*)(bias + col);

    float4 v;
    v.x = acc0.x * s0 + bb.x; v.y = acc0.y * s0 + bb.y;
    v.z = acc0.z * s0 + bb.z; v.w = acc0.w * s0 + bb.w;
    *(float4*)(C + (size_t)(row + 0) * HID + col) = v;
    v.x = acc1.x * s1 + bb.x; v.y = acc1.y * s1 + bb.y;
    v.z = acc1.z * s1 + bb.z; v.w = acc1.w * s1 + bb.w;
    *(float4*)(C + (size_t)(row + 1) * HID + col) = v;
    v.x = acc2.x * s2 + bb.x; v.y = acc2.y * s2 + bb.y;
    v.z = acc2.z * s2 + bb.z; v.w = acc2.w * s2 + bb.w;
    *(float4*)(C + (size_t)(row + 2) * HID + col) = v;
    v.x = acc3.x * s3 + bb.x; v.y = acc3.y * s3 + bb.y;
    v.z = acc3.z * s3 + bb.z; v.w = acc3.w * s3 + bb.w;
    *(float4*)(C + (size_t)(row + 3) * HID + col) = v;
}

// ---------------------------------------------------------------------------
// Aggregation: h[j] = relu(norm[j]*(u[j] + sum_{i->j} u[i]) + b), u = (h@W)*norm
// ---------------------------------------------------------------------------
__global__ __launch_bounds__(256) void agg_kernel(const float* __restrict__ u,
                                                  const float* __restrict__ norm,
                                                  const float* __restrict__ bias,
                                                  const int* __restrict__ offs,
                                                  const int* __restrict__ adj,
                                                  float* __restrict__ hout) {
    int node = blockIdx.x * 4 + (threadIdx.x >> 6);
    int lane = threadIdx.x & 63;
    const float4* up = (const float4*)u;
    float4 acc = up[(size_t)node * 64 + lane];
    int e0 = offs[node], e1 = offs[node + 1];
    for (int e = e0; e < e1; ++e) {
        int s = adj[e];
        float4 v = up[(size_t)s * 64 + lane];
        acc.x += v.x; acc.y += v.y; acc.z += v.z; acc.w += v.w;
    }
    float nm = norm[node];
    float4 bb = ((const float4*)bias)[lane];
    float4 r;
    r.x = fmaxf(fmaf(nm, acc.x, bb.x), 0.0f);
    r.y = fmaxf(fmaf(nm, acc.y, bb.y), 0.0f);
    r.z = fmaxf(fmaf(nm, acc.z, bb.z), 0.0f);
    r.w = fmaxf(fmaf(nm, acc.w, bb.w), 0.0f);
    ((float4*)hout)[(size_t)node * 64 + lane] = r;
}

// ---------------------------------------------------------------------------
// Mean pool and 2-layer MLP head
// ---------------------------------------------------------------------------
__global__ __launch_bounds__(256) void pool_kernel(const float* __restrict__ h,
                                                   float* __restrict__ gsum) {
    int t = threadIdx.x;
    float acc = 0.f;
    int start = blockIdx.x * 250;
    for (int i = 0; i < 250; ++i) acc += h[(size_t)(start + i) * HID + t];
    atomicAdd(&gsum[t], acc);
}

__global__ __launch_bounds__(128) void head_kernel(const float* __restrict__ gsum,
                                                   const float* __restrict__ Wp1,
                                                   const float* __restrict__ bp1,
                                                   const float* __restrict__ Wp2,
                                                   const float* __restrict__ bp2,
                                                   float* __restrict__ out) {
    __shared__ float gl[256];
    __shared__ float hid[128];
    int t = threadIdx.x;
    const float inv = 1.0f / 16000.0f;
    gl[t]       = gsum[t]       * inv;
    gl[t + 128] = gsum[t + 128] * inv;
    __syncthreads();
    float a = bp1[t];
    for (int k = 0; k < 256; ++k) a = fmaf(gl[k], Wp1[k * 128 + t], a);
    hid[t] = fmaxf(a, 0.0f);
    __syncthreads();
    float o = bp2[t];
    for (int k = 0; k < 128; ++k) o = fmaf(hid[k], Wp2[k * 128 + t], o);
    out[t] = o;
}

// ---------------------------------------------------------------------------
extern "C" void kernel_launch(void* const* d_in, const int* in_sizes, int n_in,
                              void* d_out, int out_size, void* d_ws, size_t ws_size,
                              hipStream_t stream) {
    const float* x      = (const float*)d_in[0];
    const float* coords = (const float*)d_in[1];
    const float* We     = (const float*)d_in[2];
    const float* be     = (const float*)d_in[3];
    const float* gnn_W  = (const float*)d_in[4];
    const float* gnn_b  = (const float*)d_in[5];
    const float* Wp1    = (const float*)d_in[6];
    const float* bp1    = (const float*)d_in[7];
    const float* Wp2    = (const float*)d_in[8];
    const float* bp2    = (const float*)d_in[9];
    float* out = (float*)d_out;

    char* ws = (char*)d_ws;
    float* h     = (float*)(ws + 0);          // 16,384,000 B
    float* u     = (float*)(ws + 16384000);   // 16,384,000 B
    int*   nbr   = (int*)  (ws + 32768000);   // 512,000 B
    int*   adj   = (int*)  (ws + 33280000);   // 512,000 B
    int*   indeg = (int*)  (ws + 33792000);   // 64,000 B
    int*   offs  = (int*)  (ws + 33856000);   // 64,004 B (padded)
    int*   cursor= (int*)  (ws + 33920256);   // 64,000 B
    float* norm  = (float*)(ws + 33984256);   // 64,000 B
    float* gsum  = (float*)(ws + 34048256);   // 1,024 B
    float4* cand = (float4*)(ws + 34049280);  // 262,144 B
    // partial kNN lists alias the (not-yet-live) u buffer
    float* pd    = (float*)u;                        // 16000*36*4 = 2,304,000 B
    int*   pi    = (int*)(ws + 16384000 + 2304000);  // 2,304,000 B

    hipMemsetAsync(indeg,  0, N_NODES * 4, stream);
    hipMemsetAsync(cursor, 0, N_NODES * 4, stream);
    hipMemsetAsync(gsum,   0, HID * 4, stream);

    prep_kernel<<<NPAD / 256, 256, 0, stream>>>(coords, cand);
    knn_part_kernel<<<dim3(N_NODES / 64, PARTS), 256, 0, stream>>>(coords, cand, pd, pi);
    knn_merge_kernel<<<(N_NODES + 255) / 256, 256, 0, stream>>>(pd, pi, nbr);

    count_kernel<<<(NEDGE + 255) / 256, 256, 0, stream>>>(nbr, indeg);
    scan_kernel<<<1, 256, 0, stream>>>(indeg, offs, norm);
    fill_kernel<<<(NEDGE + 255) / 256, 256, 0, stream>>>(nbr, offs, cursor, adj);

    dim3 g1(N_NODES / 64, HID / 64);
    gemm_kernel<<<g1, 256, 0, stream>>>(x, We, h, F_IN, nullptr, be);
    for (int l = 0; l < LAYERS; ++l) {
        gemm_kernel<<<g1, 256, 0, stream>>>(h, gnn_W + (size_t)l * HID * HID, u,
                                            HID, norm, nullptr);
        agg_kernel<<<N_NODES / 4, 256, 0, stream>>>(u, norm, gnn_b + (size_t)l * HID,
                                                    offs, adj, h);
    }
    pool_kernel<<<64, 256, 0, stream>>>(h, gsum);
    head_kernel<<<1, 128, 0, stream>>>(gsum, Wp1, bp1, Wp2, bp2, out);
}

// Round 4
// 478.560 us; speedup vs baseline: 1.6166x; 1.3882x over previous
//
#include <hip/hip_runtime.h>
#include <math.h>

#define N_NODES 16000
#define F_IN    16
#define HID     256
#define OUTD    128
#define KNN     8
#define LAYERS  3
#define NEDGE   (N_NODES * KNN)

#define NPAD    16384
#define PARTS   4
#define PART_SZ (NPAD / PARTS)   // 4096
#define SEGS    16
#define NMIN    (PARTS * SEGS)   // 64 per-seg minima per query
#define KT      1024             // candidates per LDS tile (16 KB)
#define CAP     64               // collected-candidate cap per query

// ---------------------------------------------------------------------------
// cand[i] = (-2x, -2y, -2z, |c|^2); INF-padded. Shifted distance
// d' = fma(qx,-2x, fma(qy,-2y, fma(qz,-2z, |c|^2))) is per-query monotone,
// so ordering and (d, idx) tie-breaks match the reference's d2 top_k.
// ---------------------------------------------------------------------------
__global__ __launch_bounds__(256) void prep_kernel(const float* __restrict__ coords,
                                                   float4* __restrict__ cand) {
    int i = blockIdx.x * 256 + threadIdx.x;
    if (i >= NPAD) return;
    if (i < N_NODES) {
        float x = coords[3 * i], y = coords[3 * i + 1], z = coords[3 * i + 2];
        cand[i] = make_float4(-2.f * x, -2.f * y, -2.f * z, x * x + y * y + z * z);
    } else {
        cand[i] = make_float4(0.f, 0.f, 0.f, INFINITY);
    }
}

#define DIST(qx, qy, qz, c) fmaf(qx, c.x, fmaf(qy, c.y, fmaf(qz, c.z, c.w)))

// ---------------------------------------------------------------------------
// Phase 1: per (query, part, seg) minimum. Branchless, selection-free.
// Block = 64 queries x one part. Thread = 4 queries x one seg (256 cands).
// ---------------------------------------------------------------------------
__global__ __launch_bounds__(256) void knn_min_kernel(const float* __restrict__ coords,
                                                      const float4* __restrict__ cand,
                                                      float* __restrict__ minv) {
    __shared__ float4 tile[KT];
    int tid  = threadIdx.x;
    int seg  = tid & 15;
    int qg   = tid >> 4;                  // 0..15
    int qbase = blockIdx.x * 64;
    int part = blockIdx.y;

    int q0 = qbase + qg, q1 = q0 + 16, q2 = q0 + 32, q3 = q0 + 48;
    float qx0 = coords[q0*3], qy0 = coords[q0*3+1], qz0 = coords[q0*3+2];
    float qx1 = coords[q1*3], qy1 = coords[q1*3+1], qz1 = coords[q1*3+2];
    float qx2 = coords[q2*3], qy2 = coords[q2*3+1], qz2 = coords[q2*3+2];
    float qx3 = coords[q3*3], qy3 = coords[q3*3+1], qz3 = coords[q3*3+2];

    float m0 = INFINITY, m1 = INFINITY, m2 = INFINITY, m3 = INFINITY;

    int pbase = part * PART_SZ;
    for (int t = 0; t < PART_SZ / KT; ++t) {
        __syncthreads();
        for (int l = tid; l < KT; l += 256) tile[l] = cand[pbase + t * KT + l];
        __syncthreads();
#pragma unroll 4
        for (int g = 0; g < KT / 64; ++g) {
            float4 c0 = tile[seg + g * 64];
            float4 c1 = tile[seg + g * 64 + 16];
            float4 c2 = tile[seg + g * 64 + 32];
            float4 c3 = tile[seg + g * 64 + 48];
            m0 = fminf(m0, fminf(fminf(DIST(qx0,qy0,qz0,c0), DIST(qx0,qy0,qz0,c1)),
                                 fminf(DIST(qx0,qy0,qz0,c2), DIST(qx0,qy0,qz0,c3))));
            m1 = fminf(m1, fminf(fminf(DIST(qx1,qy1,qz1,c0), DIST(qx1,qy1,qz1,c1)),
                                 fminf(DIST(qx1,qy1,qz1,c2), DIST(qx1,qy1,qz1,c3))));
            m2 = fminf(m2, fminf(fminf(DIST(qx2,qy2,qz2,c0), DIST(qx2,qy2,qz2,c1)),
                                 fminf(DIST(qx2,qy2,qz2,c2), DIST(qx2,qy2,qz2,c3))));
            m3 = fminf(m3, fminf(fminf(DIST(qx3,qy3,qz3,c0), DIST(qx3,qy3,qz3,c1)),
                                 fminf(DIST(qx3,qy3,qz3,c2), DIST(qx3,qy3,qz3,c3))));
        }
    }
    minv[(q0 * PARTS + part) * SEGS + seg] = m0;
    minv[(q1 * PARTS + part) * SEGS + seg] = m1;
    minv[(q2 * PARTS + part) * SEGS + seg] = m2;
    minv[(q3 * PARTS + part) * SEGS + seg] = m3;
}

// ---------------------------------------------------------------------------
// Phase 2: merge the 64 seg-minima into 16 disjoint-list minima (4 segs each),
// tau[q] = 9th smallest of the 16. Each list min is a distinct candidate's
// distance, so the 9th smallest of this 16-subset >= true d9: valid bound.
// Strict-< insertion keeps duplicates, so multiset order statistic is exact.
// ---------------------------------------------------------------------------
__global__ __launch_bounds__(256) void tau_kernel(const float* __restrict__ minv,
                                                  float* __restrict__ tau) {
    int q = blockIdx.x * 256 + threadIdx.x;
    if (q >= N_NODES) return;
    float b[9];
#pragma unroll
    for (int p = 0; p < 9; ++p) b[p] = INFINITY;
    const float4* mv = (const float4*)(minv + q * NMIN);
#pragma unroll
    for (int c = 0; c < 16; ++c) {
        float4 m4 = mv[c];
        float v = fminf(fminf(m4.x, m4.y), fminf(m4.z, m4.w));
#pragma unroll
        for (int p = 8; p >= 1; --p) {
            bool  up = v < b[p - 1];
            float nd = up ? b[p - 1] : (v < b[p] ? v : b[p]);
            b[p] = nd;
        }
        if (v < b[0]) b[0] = v;
    }
    tau[q] = b[8];
}

// ---------------------------------------------------------------------------
// Phase 3: collect all candidates with d <= tau[q]. One block owns all 16384
// candidates for its 64 queries -> block-LOCAL LDS counters (no cross-block
// atomics). Identical fma expression as phase 1 -> bit-identical d -> the
// bound is exact and >=9 entries are always collected.
// ---------------------------------------------------------------------------
__global__ __launch_bounds__(256) void knn_collect_kernel(const float* __restrict__ coords,
                                                          const float4* __restrict__ cand,
                                                          const float* __restrict__ tau,
                                                          int* __restrict__ cnt,
                                                          float2* __restrict__ cl) {
    __shared__ float4 tile[KT];
    __shared__ int scnt[64];
    int tid  = threadIdx.x;
    int seg  = tid & 15;
    int qg   = tid >> 4;
    int qbase = blockIdx.x * 64;

    int q0 = qbase + qg, q1 = q0 + 16, q2 = q0 + 32, q3 = q0 + 48;
    float qx0 = coords[q0*3], qy0 = coords[q0*3+1], qz0 = coords[q0*3+2];
    float qx1 = coords[q1*3], qy1 = coords[q1*3+1], qz1 = coords[q1*3+2];
    float qx2 = coords[q2*3], qy2 = coords[q2*3+1], qz2 = coords[q2*3+2];
    float qx3 = coords[q3*3], qy3 = coords[q3*3+1], qz3 = coords[q3*3+2];
    float t0 = tau[q0], t1 = tau[q1], t2 = tau[q2], t3 = tau[q3];

    if (tid < 64) scnt[tid] = 0;

#define APPEND(d, qq, j)                                             \
    if ((d) <= t##qq) {                                              \
        int pos = atomicAdd(&scnt[qg + 16 * qq], 1);                 \
        if (pos < CAP) cl[(size_t)q##qq * CAP + pos] =               \
            make_float2((d), __int_as_float(j));                     \
    }

    for (int t = 0; t < NPAD / KT; ++t) {
        __syncthreads();
        for (int l = tid; l < KT; l += 256) tile[l] = cand[t * KT + l];
        __syncthreads();
        int gb = t * KT;
        for (int g = 0; g < KT / 64; ++g) {
            float4 c0 = tile[seg + g * 64];
            float4 c1 = tile[seg + g * 64 + 16];
            float4 c2 = tile[seg + g * 64 + 32];
            float4 c3 = tile[seg + g * 64 + 48];
            int j0 = gb + seg + g * 64, j1 = j0 + 16, j2 = j0 + 32, j3 = j0 + 48;
            float d;
            d = DIST(qx0,qy0,qz0,c0); APPEND(d, 0, j0);
            d = DIST(qx0,qy0,qz0,c1); APPEND(d, 0, j1);
            d = DIST(qx0,qy0,qz0,c2); APPEND(d, 0, j2);
            d = DIST(qx0,qy0,qz0,c3); APPEND(d, 0, j3);
            d = DIST(qx1,qy1,qz1,c0); APPEND(d, 1, j0);
            d = DIST(qx1,qy1,qz1,c1); APPEND(d, 1, j1);
            d = DIST(qx1,qy1,qz1,c2); APPEND(d, 1, j2);
            d = DIST(qx1,qy1,qz1,c3); APPEND(d, 1, j3);
            d = DIST(qx2,qy2,qz2,c0); APPEND(d, 2, j0);
            d = DIST(qx2,qy2,qz2,c1); APPEND(d, 2, j1);
            d = DIST(qx2,qy2,qz2,c2); APPEND(d, 2, j2);
            d = DIST(qx2,qy2,qz2,c3); APPEND(d, 2, j3);
            d = DIST(qx3,qy3,qz3,c0); APPEND(d, 3, j0);
            d = DIST(qx3,qy3,qz3,c1); APPEND(d, 3, j1);
            d = DIST(qx3,qy3,qz3,c2); APPEND(d, 3, j2);
            d = DIST(qx3,qy3,qz3,c3); APPEND(d, 3, j3);
        }
    }
#undef APPEND
    __syncthreads();
    if (tid < 64) cnt[qbase + tid] = scnt[tid];
}

// ---------------------------------------------------------------------------
// Phase 4: exact lexicographic (d, idx) top-9 over the collected set (order-
// invariant -> deterministic; matches top_k tie-breaking). Full-rescan
// fallback if a query overflowed CAP (exactness guarantee, ~never fires).
// ---------------------------------------------------------------------------
#define INS9L(bd, bi, d, j)                                                   \
    {                                                                         \
        _Pragma("unroll")                                                     \
        for (int p = 8; p >= 1; --p) {                                        \
            bool up = (d) < bd[p-1] || ((d) == bd[p-1] && (j) < bi[p-1]);     \
            bool in = (d) < bd[p]   || ((d) == bd[p]   && (j) < bi[p]);       \
            float nd = up ? bd[p-1] : (in ? (d) : bd[p]);                     \
            int   ni = up ? bi[p-1] : (in ? (j) : bi[p]);                     \
            bd[p] = nd; bi[p] = ni;                                           \
        }                                                                     \
        if ((d) < bd[0] || ((d) == bd[0] && (j) < bi[0])) {                   \
            bd[0] = (d); bi[0] = (j);                                         \
        }                                                                     \
    }

__global__ __launch_bounds__(256) void knn_select_kernel(const float* __restrict__ coords,
                                                         const float4* __restrict__ cand,
                                                         const float2* __restrict__ cl,
                                                         const int* __restrict__ cnt,
                                                         int* __restrict__ nbr) {
    int q = blockIdx.x * 256 + threadIdx.x;
    if (q >= N_NODES) return;
    float bd[9]; int bi[9];
#pragma unroll
    for (int p = 0; p < 9; ++p) { bd[p] = INFINITY; bi[p] = 0x7fffffff; }
    int n = cnt[q];
    if (n <= CAP) {
        for (int i = 0; i < n; ++i) {
            float2 e = cl[(size_t)q * CAP + i];
            float d = e.x; int j = __float_as_int(e.y);
            INS9L(bd, bi, d, j);
        }
    } else {  // overflow fallback: exact full rescan
        float qx = coords[q*3], qy = coords[q*3+1], qz = coords[q*3+2];
        for (int j = 0; j < NPAD; ++j) {
            float4 c = cand[j];
            float d = DIST(qx, qy, qz, c);
            if (d < bd[8] || (d == bd[8] && j < bi[8])) INS9L(bd, bi, d, j);
        }
    }
#pragma unroll
    for (int p = 1; p < 9; ++p) nbr[q * 8 + p - 1] = bi[p];
}

// ---------------------------------------------------------------------------
// CSR build: indegree count -> exclusive scan (+norm) -> fill
// ---------------------------------------------------------------------------
__global__ void count_kernel(const int* __restrict__ nbr, int* __restrict__ indeg) {
    int e = blockIdx.x * blockDim.x + threadIdx.x;
    if (e < NEDGE) atomicAdd(&indeg[nbr[e]], 1);
}

__global__ __launch_bounds__(256) void scan_kernel(const int* __restrict__ indeg,
                                                   int* __restrict__ offs,
                                                   float* __restrict__ norm) {
    __shared__ int ssum[256];
    int t = threadIdx.x;
    const int CH = 63;
    int base = t * CH;
    int s = 0;
    for (int c = 0; c < CH; ++c) {
        int idx = base + c;
        if (idx < N_NODES) s += indeg[idx];
    }
    ssum[t] = s;
    __syncthreads();
    for (int d = 1; d < 256; d <<= 1) {
        int v = (t >= d) ? ssum[t - d] : 0;
        __syncthreads();
        ssum[t] += v;
        __syncthreads();
    }
    int run = ssum[t] - s;
    for (int c = 0; c < CH; ++c) {
        int idx = base + c;
        if (idx < N_NODES) {
            int dg = indeg[idx];
            offs[idx] = run;
            run += dg;
            norm[idx] = rsqrtf((float)(1 + dg));
        }
    }
    if (t == 255) offs[N_NODES] = ssum[255];
}

__global__ void fill_kernel(const int* __restrict__ nbr, const int* __restrict__ offs,
                            int* __restrict__ cursor, int* __restrict__ adj) {
    int e = blockIdx.x * blockDim.x + threadIdx.x;
    if (e < NEDGE) {
        int d   = nbr[e];
        int src = e >> 3;
        int pos = atomicAdd(&cursor[d], 1);
        adj[offs[d] + pos] = src;
    }
}

// ---------------------------------------------------------------------------
// f32 GEMM: C[M x 256] = A[M x K] @ B[K x 256], optional per-row scale and
// per-col bias.  64x64 tile, BK=16, 256 threads, 4x4 micro-tile per thread.
// ---------------------------------------------------------------------------
__global__ __launch_bounds__(256) void gemm_kernel(const float* __restrict__ A,
                                                   const float* __restrict__ B,
                                                   float* __restrict__ C,
                                                   int K,
                                                   const float* __restrict__ rowscale,
                                                   const float* __restrict__ bias) {
    __shared__ float As[16][68];
    __shared__ float Bs[16][64];
    int tid = threadIdx.x;
    int rowBase = blockIdx.x * 64;
    int colBase = blockIdx.y * 64;
    int rg = tid >> 4;
    int cg = tid & 15;

    int ar = tid >> 2;
    int ac = (tid & 3) * 4;
    int bk = tid >> 4;
    int bn = (tid & 15) * 4;

    float4 acc0 = {0,0,0,0}, acc1 = {0,0,0,0}, acc2 = {0,0,0,0}, acc3 = {0,0,0,0};

    for (int kb = 0; kb < K; kb += 16) {
        float4 av = *(const float4*)(A + (size_t)(rowBase + ar) * K + kb + ac);
        float4 bv = *(const float4*)(B + (size_t)(kb + bk) * HID + colBase + bn);
        __syncthreads();
        As[ac + 0][ar] = av.x; As[ac + 1][ar] = av.y;
        As[ac + 2][ar] = av.z; As[ac + 3][ar] = av.w;
        *(float4*)&Bs[bk][bn] = bv;
        __syncthreads();
#pragma unroll
        for (int k = 0; k < 16; ++k) {
            float4 a = *(const float4*)&As[k][rg * 4];
            float4 b = *(const float4*)&Bs[k][cg * 4];
            acc0.x = fmaf(a.x, b.x, acc0.x); acc0.y = fmaf(a.x, b.y, acc0.y);
            acc0.z = fmaf(a.x, b.z, acc0.z); acc0.w = fmaf(a.x, b.w, acc0.w);
            acc1.x = fmaf(a.y, b.x, acc1.x); acc1.y = fmaf(a.y, b.y, acc1.y);
            acc1.z = fmaf(a.y, b.z, acc1.z); acc1.w = fmaf(a.y, b.w, acc1.w);
            acc2.x = fmaf(a.z, b.x, acc2.x); acc2.y = fmaf(a.z, b.y, acc2.y);
            acc2.z = fmaf(a.z, b.z, acc2.z); acc2.w = fmaf(a.z, b.w, acc2.w);
            acc3.x = fmaf(a.w, b.x, acc3.x); acc3.y = fmaf(a.w, b.y, acc3.y);
            acc3.z = fmaf(a.w, b.z, acc3.z); acc3.w = fmaf(a.w, b.w, acc3.w);
        }
        __syncthreads();
    }

    int row = rowBase + rg * 4;
    int col = colBase + cg * 4;
    float s0 = 1.f, s1 = 1.f, s2 = 1.f, s3 = 1.f;
    if (rowscale) { s0 = rowscale[row]; s1 = rowscale[row + 1];
                    s2 = rowscale[row + 2]; s3 = rowscale[row + 3]; }
    float4 bb = {0,0,0,0};
    if (bias) bb = *(const float4*)(bias + col);

    float4 v;
    v.x = acc0.x * s0 + bb.x; v.y = acc0.y * s0 + bb.y;
    v.z = acc0.z * s0 + bb.z; v.w = acc0.w * s0 + bb.w;
    *(float4*)(C + (size_t)(row + 0) * HID + col) = v;
    v.x = acc1.x * s1 + bb.x; v.y = acc1.y * s1 + bb.y;
    v.z = acc1.z * s1 + bb.z; v.w = acc1.w * s1 + bb.w;
    *(float4*)(C + (size_t)(row + 1) * HID + col) = v;
    v.x = acc2.x * s2 + bb.x; v.y = acc2.y * s2 + bb.y;
    v.z = acc2.z * s2 + bb.z; v.w = acc2.w * s2 + bb.w;
    *(float4*)(C + (size_t)(row + 2) * HID + col) = v;
    v.x = acc3.x * s3 + bb.x; v.y = acc3.y * s3 + bb.y;
    v.z = acc3.z * s3 + bb.z; v.w = acc3.w * s3 + bb.w;
    *(float4*)(C + (size_t)(row + 3) * HID + col) = v;
}

// ---------------------------------------------------------------------------
// Aggregation: h[j] = relu(norm[j]*(u[j] + sum_{i->j} u[i]) + b), u = (h@W)*norm
// ---------------------------------------------------------------------------
__global__ __launch_bounds__(256) void agg_kernel(const float* __restrict__ u,
                                                  const float* __restrict__ norm,
                                                  const float* __restrict__ bias,
                                                  const int* __restrict__ offs,
                                                  const int* __restrict__ adj,
                                                  float* __restrict__ hout) {
    int node = blockIdx.x * 4 + (threadIdx.x >> 6);
    int lane = threadIdx.x & 63;
    const float4* up = (const float4*)u;
    float4 acc = up[(size_t)node * 64 + lane];
    int e0 = offs[node], e1 = offs[node + 1];
    for (int e = e0; e < e1; ++e) {
        int s = adj[e];
        float4 v = up[(size_t)s * 64 + lane];
        acc.x += v.x; acc.y += v.y; acc.z += v.z; acc.w += v.w;
    }
    float nm = norm[node];
    float4 bb = ((const float4*)bias)[lane];
    float4 r;
    r.x = fmaxf(fmaf(nm, acc.x, bb.x), 0.0f);
    r.y = fmaxf(fmaf(nm, acc.y, bb.y), 0.0f);
    r.z = fmaxf(fmaf(nm, acc.z, bb.z), 0.0f);
    r.w = fmaxf(fmaf(nm, acc.w, bb.w), 0.0f);
    ((float4*)hout)[(size_t)node * 64 + lane] = r;
}

// ---------------------------------------------------------------------------
// Mean pool and 2-layer MLP head
// ---------------------------------------------------------------------------
__global__ __launch_bounds__(256) void pool_kernel(const float* __restrict__ h,
                                                   float* __restrict__ gsum) {
    int t = threadIdx.x;
    float acc = 0.f;
    int start = blockIdx.x * 250;
    for (int i = 0; i < 250; ++i) acc += h[(size_t)(start + i) * HID + t];
    atomicAdd(&gsum[t], acc);
}

__global__ __launch_bounds__(128) void head_kernel(const float* __restrict__ gsum,
                                                   const float* __restrict__ Wp1,
                                                   const float* __restrict__ bp1,
                                                   const float* __restrict__ Wp2,
                                                   const float* __restrict__ bp2,
                                                   float* __restrict__ out) {
    __shared__ float gl[256];
    __shared__ float hid[128];
    int t = threadIdx.x;
    const float inv = 1.0f / 16000.0f;
    gl[t]       = gsum[t]       * inv;
    gl[t + 128] = gsum[t + 128] * inv;
    __syncthreads();
    float a = bp1[t];
    for (int k = 0; k < 256; ++k) a = fmaf(gl[k], Wp1[k * 128 + t], a);
    hid[t] = fmaxf(a, 0.0f);
    __syncthreads();
    float o = bp2[t];
    for (int k = 0; k < 128; ++k) o = fmaf(hid[k], Wp2[k * 128 + t], o);
    out[t] = o;
}

// ---------------------------------------------------------------------------
extern "C" void kernel_launch(void* const* d_in, const int* in_sizes, int n_in,
                              void* d_out, int out_size, void* d_ws, size_t ws_size,
                              hipStream_t stream) {
    const float* x      = (const float*)d_in[0];
    const float* coords = (const float*)d_in[1];
    const float* We     = (const float*)d_in[2];
    const float* be     = (const float*)d_in[3];
    const float* gnn_W  = (const float*)d_in[4];
    const float* gnn_b  = (const float*)d_in[5];
    const float* Wp1    = (const float*)d_in[6];
    const float* bp1    = (const float*)d_in[7];
    const float* Wp2    = (const float*)d_in[8];
    const float* bp2    = (const float*)d_in[9];
    float* out = (float*)d_out;

    char* ws = (char*)d_ws;
    float* h     = (float*)(ws + 0);          // 16,384,000 B
    float* u     = (float*)(ws + 16384000);   // 16,384,000 B
    int*   nbr   = (int*)  (ws + 32768000);   // 512,000 B
    int*   adj   = (int*)  (ws + 33280000);   // 512,000 B
    int*   indeg = (int*)  (ws + 33792000);   // 64,000 B
    int*   offs  = (int*)  (ws + 33856000);   // 64,004 B (padded)
    int*   cursor= (int*)  (ws + 33920256);   // 64,000 B
    float* norm  = (float*)(ws + 33984256);   // 64,000 B
    float* gsum  = (float*)(ws + 34048256);   // 1,024 B
    float4* cand = (float4*)(ws + 34049280);  // 262,144 B
    // kNN scratch aliases the (not-yet-live) u buffer
    float*  minv = (float*)u;                       // 16000*64*4 = 4,096,000 B
    float*  tau  = (float*)((char*)u + 4096000);    //    64,000 B
    int*    cnt  = (int*)  ((char*)u + 4160000);    //    64,000 B (written by collect)
    float2* cl   = (float2*)((char*)u + 4224000);   // 16000*64*8 = 8,192,000 B

    hipMemsetAsync(indeg,  0, N_NODES * 4, stream);
    hipMemsetAsync(cursor, 0, N_NODES * 4, stream);
    hipMemsetAsync(gsum,   0, HID * 4, stream);

    prep_kernel<<<NPAD / 256, 256, 0, stream>>>(coords, cand);
    knn_min_kernel<<<dim3(N_NODES / 64, PARTS), 256, 0, stream>>>(coords, cand, minv);
    tau_kernel<<<(N_NODES + 255) / 256, 256, 0, stream>>>(minv, tau);
    knn_collect_kernel<<<N_NODES / 64, 256, 0, stream>>>(coords, cand, tau, cnt, cl);
    knn_select_kernel<<<(N_NODES + 255) / 256, 256, 0, stream>>>(coords, cand, cl, cnt, nbr);

    count_kernel<<<(NEDGE + 255) / 256, 256, 0, stream>>>(nbr, indeg);
    scan_kernel<<<1, 256, 0, stream>>>(indeg, offs, norm);
    fill_kernel<<<(NEDGE + 255) / 256, 256, 0, stream>>>(nbr, offs, cursor, adj);

    dim3 g1(N_NODES / 64, HID / 64);
    gemm_kernel<<<g1, 256, 0, stream>>>(x, We, h, F_IN, nullptr, be);
    for (int l = 0; l < LAYERS; ++l) {
        gemm_kernel<<<g1, 256, 0, stream>>>(h, gnn_W + (size_t)l * HID * HID, u,
                                            HID, norm, nullptr);
        agg_kernel<<<N_NODES / 4, 256, 0, stream>>>(u, norm, gnn_b + (size_t)l * HID,
                                                    offs, adj, h);
    }
    pool_kernel<<<64, 256, 0, stream>>>(h, gsum);
    head_kernel<<<1, 128, 0, stream>>>(gsum, Wp1, bp1, Wp2, bp2, out);
}

// Round 5
// 380.927 us; speedup vs baseline: 2.0309x; 1.2563x over previous
//
#include <hip/hip_runtime.h>
#include <math.h>

#define N_NODES 16000
#define F_IN    16
#define HID     256
#define OUTD    128
#define KNN     8
#define LAYERS  3
#define NEDGE   (N_NODES * KNN)

#define NPAD    16384
#define PARTS   4
#define PART_SZ (NPAD / PARTS)   // 4096
#define SEGS    16
#define NMIN    (PARTS * SEGS)   // 64 per-seg minima per query
#define KT      1024             // candidates per LDS tile (16 KB)
#define CAPP    32               // collected-candidate cap per (query, part)

// ---------------------------------------------------------------------------
// cand[i] = (-2x, -2y, -2z, |c|^2); INF-padded. Shifted distance
// d' = fma(qx,-2x, fma(qy,-2y, fma(qz,-2z, |c|^2))) is per-query monotone,
// so ordering and (d, idx) tie-breaks match the reference's d2 top_k.
// ---------------------------------------------------------------------------
__global__ __launch_bounds__(256) void prep_kernel(const float* __restrict__ coords,
                                                   float4* __restrict__ cand) {
    int i = blockIdx.x * 256 + threadIdx.x;
    if (i >= NPAD) return;
    if (i < N_NODES) {
        float x = coords[3 * i], y = coords[3 * i + 1], z = coords[3 * i + 2];
        cand[i] = make_float4(-2.f * x, -2.f * y, -2.f * z, x * x + y * y + z * z);
    } else {
        cand[i] = make_float4(0.f, 0.f, 0.f, INFINITY);
    }
}

#define DIST(qx, qy, qz, c) fmaf(qx, c.x, fmaf(qy, c.y, fmaf(qz, c.z, c.w)))

// ---------------------------------------------------------------------------
// Phase 1: per (query, part, seg) minimum. Branchless, selection-free.
// Block = 64 queries x one part. Thread = 4 queries x one seg (256 cands).
// ---------------------------------------------------------------------------
__global__ __launch_bounds__(256) void knn_min_kernel(const float* __restrict__ coords,
                                                      const float4* __restrict__ cand,
                                                      float* __restrict__ minv) {
    __shared__ float4 tile[KT];
    int tid  = threadIdx.x;
    int seg  = tid & 15;
    int qg   = tid >> 4;                  // 0..15
    int qbase = blockIdx.x * 64;
    int part = blockIdx.y;

    int q0 = qbase + qg, q1 = q0 + 16, q2 = q0 + 32, q3 = q0 + 48;
    float qx0 = coords[q0*3], qy0 = coords[q0*3+1], qz0 = coords[q0*3+2];
    float qx1 = coords[q1*3], qy1 = coords[q1*3+1], qz1 = coords[q1*3+2];
    float qx2 = coords[q2*3], qy2 = coords[q2*3+1], qz2 = coords[q2*3+2];
    float qx3 = coords[q3*3], qy3 = coords[q3*3+1], qz3 = coords[q3*3+2];

    float m0 = INFINITY, m1 = INFINITY, m2 = INFINITY, m3 = INFINITY;

    int pbase = part * PART_SZ;
    for (int t = 0; t < PART_SZ / KT; ++t) {
        __syncthreads();
        for (int l = tid; l < KT; l += 256) tile[l] = cand[pbase + t * KT + l];
        __syncthreads();
#pragma unroll 4
        for (int g = 0; g < KT / 64; ++g) {
            float4 c0 = tile[seg + g * 64];
            float4 c1 = tile[seg + g * 64 + 16];
            float4 c2 = tile[seg + g * 64 + 32];
            float4 c3 = tile[seg + g * 64 + 48];
            m0 = fminf(m0, fminf(fminf(DIST(qx0,qy0,qz0,c0), DIST(qx0,qy0,qz0,c1)),
                                 fminf(DIST(qx0,qy0,qz0,c2), DIST(qx0,qy0,qz0,c3))));
            m1 = fminf(m1, fminf(fminf(DIST(qx1,qy1,qz1,c0), DIST(qx1,qy1,qz1,c1)),
                                 fminf(DIST(qx1,qy1,qz1,c2), DIST(qx1,qy1,qz1,c3))));
            m2 = fminf(m2, fminf(fminf(DIST(qx2,qy2,qz2,c0), DIST(qx2,qy2,qz2,c1)),
                                 fminf(DIST(qx2,qy2,qz2,c2), DIST(qx2,qy2,qz2,c3))));
            m3 = fminf(m3, fminf(fminf(DIST(qx3,qy3,qz3,c0), DIST(qx3,qy3,qz3,c1)),
                                 fminf(DIST(qx3,qy3,qz3,c2), DIST(qx3,qy3,qz3,c3))));
        }
    }
    minv[(q0 * PARTS + part) * SEGS + seg] = m0;
    minv[(q1 * PARTS + part) * SEGS + seg] = m1;
    minv[(q2 * PARTS + part) * SEGS + seg] = m2;
    minv[(q3 * PARTS + part) * SEGS + seg] = m3;
}

// ---------------------------------------------------------------------------
// Phase 2: merge the 64 seg-minima into 16 disjoint-list minima (4 segs each),
// tau[q] = 9th smallest of the 16. Each list min is a distinct candidate's
// distance, so the 9th smallest of this 16-subset >= true d9: valid bound.
// ---------------------------------------------------------------------------
__global__ __launch_bounds__(256) void tau_kernel(const float* __restrict__ minv,
                                                  float* __restrict__ tau) {
    int q = blockIdx.x * 256 + threadIdx.x;
    if (q >= N_NODES) return;
    float b[9];
#pragma unroll
    for (int p = 0; p < 9; ++p) b[p] = INFINITY;
    const float4* mv = (const float4*)(minv + q * NMIN);
#pragma unroll
    for (int c = 0; c < 16; ++c) {
        float4 m4 = mv[c];
        float v = fminf(fminf(m4.x, m4.y), fminf(m4.z, m4.w));
#pragma unroll
        for (int p = 8; p >= 1; --p) {
            bool  up = v < b[p - 1];
            float nd = up ? b[p - 1] : (v < b[p] ? v : b[p]);
            b[p] = nd;
        }
        if (v < b[0]) b[0] = v;
    }
    tau[q] = b[8];
}

// ---------------------------------------------------------------------------
// Phase 3: collect all candidates with d <= tau[q], partitioned over PARTS
// (grid 250 x 4 for occupancy). Counters are block-LOCAL LDS (no cross-block
// atomics); each (query, part) owns a disjoint CAPP segment of cl. Identical
// fma expression as phase 1 -> bit-identical d -> bound is exact.
// ---------------------------------------------------------------------------
__global__ __launch_bounds__(256) void knn_collect_kernel(const float* __restrict__ coords,
                                                          const float4* __restrict__ cand,
                                                          const float* __restrict__ tau,
                                                          int* __restrict__ cnt,
                                                          float2* __restrict__ cl) {
    __shared__ float4 tile[KT];
    __shared__ int scnt[64];
    int tid  = threadIdx.x;
    int seg  = tid & 15;
    int qg   = tid >> 4;
    int qbase = blockIdx.x * 64;
    int part  = blockIdx.y;

    int q0 = qbase + qg, q1 = q0 + 16, q2 = q0 + 32, q3 = q0 + 48;
    float qx0 = coords[q0*3], qy0 = coords[q0*3+1], qz0 = coords[q0*3+2];
    float qx1 = coords[q1*3], qy1 = coords[q1*3+1], qz1 = coords[q1*3+2];
    float qx2 = coords[q2*3], qy2 = coords[q2*3+1], qz2 = coords[q2*3+2];
    float qx3 = coords[q3*3], qy3 = coords[q3*3+1], qz3 = coords[q3*3+2];
    float t0 = tau[q0], t1 = tau[q1], t2 = tau[q2], t3 = tau[q3];

    if (tid < 64) scnt[tid] = 0;

#define APPEND(d, qq, j)                                                   \
    if ((d) <= t##qq) {                                                    \
        int pos = atomicAdd(&scnt[qg + 16 * qq], 1);                       \
        if (pos < CAPP) cl[((size_t)q##qq * PARTS + part) * CAPP + pos] =  \
            make_float2((d), __int_as_float(j));                           \
    }

    int pbase = part * PART_SZ;
    for (int t = 0; t < PART_SZ / KT; ++t) {
        __syncthreads();
        for (int l = tid; l < KT; l += 256) tile[l] = cand[pbase + t * KT + l];
        __syncthreads();
        int gb = pbase + t * KT;
        for (int g = 0; g < KT / 64; ++g) {
            float4 c0 = tile[seg + g * 64];
            float4 c1 = tile[seg + g * 64 + 16];
            float4 c2 = tile[seg + g * 64 + 32];
            float4 c3 = tile[seg + g * 64 + 48];
            int j0 = gb + seg + g * 64, j1 = j0 + 16, j2 = j0 + 32, j3 = j0 + 48;
            float d;
            d = DIST(qx0,qy0,qz0,c0); APPEND(d, 0, j0);
            d = DIST(qx0,qy0,qz0,c1); APPEND(d, 0, j1);
            d = DIST(qx0,qy0,qz0,c2); APPEND(d, 0, j2);
            d = DIST(qx0,qy0,qz0,c3); APPEND(d, 0, j3);
            d = DIST(qx1,qy1,qz1,c0); APPEND(d, 1, j0);
            d = DIST(qx1,qy1,qz1,c1); APPEND(d, 1, j1);
            d = DIST(qx1,qy1,qz1,c2); APPEND(d, 1, j2);
            d = DIST(qx1,qy1,qz1,c3); APPEND(d, 1, j3);
            d = DIST(qx2,qy2,qz2,c0); APPEND(d, 2, j0);
            d = DIST(qx2,qy2,qz2,c1); APPEND(d, 2, j1);
            d = DIST(qx2,qy2,qz2,c2); APPEND(d, 2, j2);
            d = DIST(qx2,qy2,qz2,c3); APPEND(d, 2, j3);
            d = DIST(qx3,qy3,qz3,c0); APPEND(d, 3, j0);
            d = DIST(qx3,qy3,qz3,c1); APPEND(d, 3, j1);
            d = DIST(qx3,qy3,qz3,c2); APPEND(d, 3, j2);
            d = DIST(qx3,qy3,qz3,c3); APPEND(d, 3, j3);
        }
    }
#undef APPEND
    __syncthreads();
    if (tid < 64) cnt[(size_t)(qbase + tid) * PARTS + part] = scnt[tid];
}

// ---------------------------------------------------------------------------
// Phase 4: exact lexicographic (d, idx) top-9 over the union of the 4 part
// segments (disjoint, order-invariant -> deterministic; matches top_k
// tie-breaking). Full-rescan fallback if any part overflowed CAPP.
// ---------------------------------------------------------------------------
#define INS9L(bd, bi, d, j)                                                   \
    {                                                                         \
        _Pragma("unroll")                                                     \
        for (int p = 8; p >= 1; --p) {                                        \
            bool up = (d) < bd[p-1] || ((d) == bd[p-1] && (j) < bi[p-1]);     \
            bool in = (d) < bd[p]   || ((d) == bd[p]   && (j) < bi[p]);       \
            float nd = up ? bd[p-1] : (in ? (d) : bd[p]);                     \
            int   ni = up ? bi[p-1] : (in ? (j) : bi[p]);                     \
            bd[p] = nd; bi[p] = ni;                                           \
        }                                                                     \
        if ((d) < bd[0] || ((d) == bd[0] && (j) < bi[0])) {                   \
            bd[0] = (d); bi[0] = (j);                                         \
        }                                                                     \
    }

__global__ __launch_bounds__(256) void knn_select_kernel(const float* __restrict__ coords,
                                                         const float4* __restrict__ cand,
                                                         const float2* __restrict__ cl,
                                                         const int* __restrict__ cnt,
                                                         int* __restrict__ nbr) {
    int q = blockIdx.x * 256 + threadIdx.x;
    if (q >= N_NODES) return;
    float bd[9]; int bi[9];
#pragma unroll
    for (int p = 0; p < 9; ++p) { bd[p] = INFINITY; bi[p] = 0x7fffffff; }
    int n0 = cnt[(size_t)q * PARTS + 0];
    int n1 = cnt[(size_t)q * PARTS + 1];
    int n2 = cnt[(size_t)q * PARTS + 2];
    int n3 = cnt[(size_t)q * PARTS + 3];
    if (n0 <= CAPP && n1 <= CAPP && n2 <= CAPP && n3 <= CAPP) {
#pragma unroll
        for (int p = 0; p < PARTS; ++p) {
            int n = (p == 0) ? n0 : (p == 1) ? n1 : (p == 2) ? n2 : n3;
            const float2* seg = cl + ((size_t)q * PARTS + p) * CAPP;
            for (int i = 0; i < n; ++i) {
                float2 e = seg[i];
                float d = e.x; int j = __float_as_int(e.y);
                INS9L(bd, bi, d, j);
            }
        }
    } else {  // overflow fallback: exact full rescan (~never fires)
        float qx = coords[q*3], qy = coords[q*3+1], qz = coords[q*3+2];
        for (int j = 0; j < NPAD; ++j) {
            float4 c = cand[j];
            float d = DIST(qx, qy, qz, c);
            if (d < bd[8] || (d == bd[8] && j < bi[8])) INS9L(bd, bi, d, j);
        }
    }
#pragma unroll
    for (int p = 1; p < 9; ++p) nbr[q * 8 + p - 1] = bi[p];
}

// ---------------------------------------------------------------------------
// CSR build: indegree count -> exclusive scan (+norm) -> fill
// ---------------------------------------------------------------------------
__global__ void count_kernel(const int* __restrict__ nbr, int* __restrict__ indeg) {
    int e = blockIdx.x * blockDim.x + threadIdx.x;
    if (e < NEDGE) atomicAdd(&indeg[nbr[e]], 1);
}

__global__ __launch_bounds__(256) void scan_kernel(const int* __restrict__ indeg,
                                                   int* __restrict__ offs,
                                                   float* __restrict__ norm) {
    __shared__ int ssum[256];
    int t = threadIdx.x;
    const int CH = 63;
    int base = t * CH;
    int s = 0;
    for (int c = 0; c < CH; ++c) {
        int idx = base + c;
        if (idx < N_NODES) s += indeg[idx];
    }
    ssum[t] = s;
    __syncthreads();
    for (int d = 1; d < 256; d <<= 1) {
        int v = (t >= d) ? ssum[t - d] : 0;
        __syncthreads();
        ssum[t] += v;
        __syncthreads();
    }
    int run = ssum[t] - s;
    for (int c = 0; c < CH; ++c) {
        int idx = base + c;
        if (idx < N_NODES) {
            int dg = indeg[idx];
            offs[idx] = run;
            run += dg;
            norm[idx] = rsqrtf((float)(1 + dg));
        }
    }
    if (t == 255) offs[N_NODES] = ssum[255];
}

__global__ void fill_kernel(const int* __restrict__ nbr, const int* __restrict__ offs,
                            int* __restrict__ cursor, int* __restrict__ adj) {
    int e = blockIdx.x * blockDim.x + threadIdx.x;
    if (e < NEDGE) {
        int d   = nbr[e];
        int src = e >> 3;
        int pos = atomicAdd(&cursor[d], 1);
        adj[offs[d] + pos] = src;
    }
}

// ---------------------------------------------------------------------------
// f32 GEMM: C[M x 256] = A[M x K] @ B[K x 256], optional per-row scale and
// per-col bias.  64x64 tile, BK=16, 256 threads, 4x4 micro-tile per thread.
// ---------------------------------------------------------------------------
__global__ __launch_bounds__(256) void gemm_kernel(const float* __restrict__ A,
                                                   const float* __restrict__ B,
                                                   float* __restrict__ C,
                                                   int K,
                                                   const float* __restrict__ rowscale,
                                                   const float* __restrict__ bias) {
    __shared__ float As[16][68];
    __shared__ float Bs[16][64];
    int tid = threadIdx.x;
    int rowBase = blockIdx.x * 64;
    int colBase = blockIdx.y * 64;
    int rg = tid >> 4;
    int cg = tid & 15;

    int ar = tid >> 2;
    int ac = (tid & 3) * 4;
    int bk = tid >> 4;
    int bn = (tid & 15) * 4;

    float4 acc0 = {0,0,0,0}, acc1 = {0,0,0,0}, acc2 = {0,0,0,0}, acc3 = {0,0,0,0};

    for (int kb = 0; kb < K; kb += 16) {
        float4 av = *(const float4*)(A + (size_t)(rowBase + ar) * K + kb + ac);
        float4 bv = *(const float4*)(B + (size_t)(kb + bk) * HID + colBase + bn);
        __syncthreads();
        As[ac + 0][ar] = av.x; As[ac + 1][ar] = av.y;
        As[ac + 2][ar] = av.z; As[ac + 3][ar] = av.w;
        *(float4*)&Bs[bk][bn] = bv;
        __syncthreads();
#pragma unroll
        for (int k = 0; k < 16; ++k) {
            float4 a = *(const float4*)&As[k][rg * 4];
            float4 b = *(const float4*)&Bs[k][cg * 4];
            acc0.x = fmaf(a.x, b.x, acc0.x); acc0.y = fmaf(a.x, b.y, acc0.y);
            acc0.z = fmaf(a.x, b.z, acc0.z); acc0.w = fmaf(a.x, b.w, acc0.w);
            acc1.x = fmaf(a.y, b.x, acc1.x); acc1.y = fmaf(a.y, b.y, acc1.y);
            acc1.z = fmaf(a.y, b.z, acc1.z); acc1.w = fmaf(a.y, b.w, acc1.w);
            acc2.x = fmaf(a.z, b.x, acc2.x); acc2.y = fmaf(a.z, b.y, acc2.y);
            acc2.z = fmaf(a.z, b.z, acc2.z); acc2.w = fmaf(a.z, b.w, acc2.w);
            acc3.x = fmaf(a.w, b.x, acc3.x); acc3.y = fmaf(a.w, b.y, acc3.y);
            acc3.z = fmaf(a.w, b.z, acc3.z); acc3.w = fmaf(a.w, b.w, acc3.w);
        }
        __syncthreads();
    }

    int row = rowBase + rg * 4;
    int col = colBase + cg * 4;
    float s0 = 1.f, s1 = 1.f, s2 = 1.f, s3 = 1.f;
    if (rowscale) { s0 = rowscale[row]; s1 = rowscale[row + 1];
                    s2 = rowscale[row + 2]; s3 = rowscale[row + 3]; }
    float4 bb = {0,0,0,0};
    if (bias) bb = *(const float4*)(bias + col);

    float4 v;
    v.x = acc0.x * s0 + bb.x; v.y = acc0.y * s0 + bb.y;
    v.z = acc0.z * s0 + bb.z; v.w = acc0.w * s0 + bb.w;
    *(float4*)(C + (size_t)(row + 0) * HID + col) = v;
    v.x = acc1.x * s1 + bb.x; v.y = acc1.y * s1 + bb.y;
    v.z = acc1.z * s1 + bb.z; v.w = acc1.w * s1 + bb.w;
    *(float4*)(C + (size_t)(row + 1) * HID + col) = v;
    v.x = acc2.x * s2 + bb.x; v.y = acc2.y * s2 + bb.y;
    v.z = acc2.z * s2 + bb.z; v.w = acc2.w * s2 + bb.w;
    *(float4*)(C + (size_t)(row + 2) * HID + col) = v;
    v.x = acc3.x * s3 + bb.x; v.y = acc3.y * s3 + bb.y;
    v.z = acc3.z * s3 + bb.z; v.w = acc3.w * s3 + bb.w;
    *(float4*)(C + (size_t)(row + 3) * HID + col) = v;
}

// ---------------------------------------------------------------------------
// Aggregation: h[j] = relu(norm[j]*(u[j] + sum_{i->j} u[i]) + b), u = (h@W)*norm
// ---------------------------------------------------------------------------
__global__ __launch_bounds__(256) void agg_kernel(const float* __restrict__ u,
                                                  const float* __restrict__ norm,
                                                  const float* __restrict__ bias,
                                                  const int* __restrict__ offs,
                                                  const int* __restrict__ adj,
                                                  float* __restrict__ hout) {
    int node = blockIdx.x * 4 + (threadIdx.x >> 6);
    int lane = threadIdx.x & 63;
    const float4* up = (const float4*)u;
    float4 acc = up[(size_t)node * 64 + lane];
    int e0 = offs[node], e1 = offs[node + 1];
    for (int e = e0; e < e1; ++e) {
        int s = adj[e];
        float4 v = up[(size_t)s * 64 + lane];
        acc.x += v.x; acc.y += v.y; acc.z += v.z; acc.w += v.w;
    }
    float nm = norm[node];
    float4 bb = ((const float4*)bias)[lane];
    float4 r;
    r.x = fmaxf(fmaf(nm, acc.x, bb.x), 0.0f);
    r.y = fmaxf(fmaf(nm, acc.y, bb.y), 0.0f);
    r.z = fmaxf(fmaf(nm, acc.z, bb.z), 0.0f);
    r.w = fmaxf(fmaf(nm, acc.w, bb.w), 0.0f);
    ((float4*)hout)[(size_t)node * 64 + lane] = r;
}

// ---------------------------------------------------------------------------
// Mean pool and 2-layer MLP head
// ---------------------------------------------------------------------------
__global__ __launch_bounds__(256) void pool_kernel(const float* __restrict__ h,
                                                   float* __restrict__ gsum) {
    int t = threadIdx.x;
    float acc = 0.f;
    int start = blockIdx.x * 250;
    for (int i = 0; i < 250; ++i) acc += h[(size_t)(start + i) * HID + t];
    atomicAdd(&gsum[t], acc);
}

__global__ __launch_bounds__(128) void head_kernel(const float* __restrict__ gsum,
                                                   const float* __restrict__ Wp1,
                                                   const float* __restrict__ bp1,
                                                   const float* __restrict__ Wp2,
                                                   const float* __restrict__ bp2,
                                                   float* __restrict__ out) {
    __shared__ float gl[256];
    __shared__ float hid[128];
    int t = threadIdx.x;
    const float inv = 1.0f / 16000.0f;
    gl[t]       = gsum[t]       * inv;
    gl[t + 128] = gsum[t + 128] * inv;
    __syncthreads();
    float a = bp1[t];
    for (int k = 0; k < 256; ++k) a = fmaf(gl[k], Wp1[k * 128 + t], a);
    hid[t] = fmaxf(a, 0.0f);
    __syncthreads();
    float o = bp2[t];
    for (int k = 0; k < 128; ++k) o = fmaf(hid[k], Wp2[k * 128 + t], o);
    out[t] = o;
}

// ---------------------------------------------------------------------------
extern "C" void kernel_launch(void* const* d_in, const int* in_sizes, int n_in,
                              void* d_out, int out_size, void* d_ws, size_t ws_size,
                              hipStream_t stream) {
    const float* x      = (const float*)d_in[0];
    const float* coords = (const float*)d_in[1];
    const float* We     = (const float*)d_in[2];
    const float* be     = (const float*)d_in[3];
    const float* gnn_W  = (const float*)d_in[4];
    const float* gnn_b  = (const float*)d_in[5];
    const float* Wp1    = (const float*)d_in[6];
    const float* bp1    = (const float*)d_in[7];
    const float* Wp2    = (const float*)d_in[8];
    const float* bp2    = (const float*)d_in[9];
    float* out = (float*)d_out;

    char* ws = (char*)d_ws;
    float* h     = (float*)(ws + 0);          // 16,384,000 B
    float* u     = (float*)(ws + 16384000);   // 16,384,000 B
    int*   nbr   = (int*)  (ws + 32768000);   // 512,000 B
    int*   adj   = (int*)  (ws + 33280000);   // 512,000 B
    int*   indeg = (int*)  (ws + 33792000);   // 64,000 B
    int*   offs  = (int*)  (ws + 33856000);   // 64,004 B (padded)
    int*   cursor= (int*)  (ws + 33920256);   // 64,000 B
    float* norm  = (float*)(ws + 33984256);   // 64,000 B
    float* gsum  = (float*)(ws + 34048256);   // 1,024 B
    float4* cand = (float4*)(ws + 34049280);  // 262,144 B
    // kNN scratch aliases not-yet-live h and u buffers:
    // cl = 16000*4*32*8 = 16,384,000 B -> exactly the h region
    float2* cl   = (float2*)h;
    float*  minv = (float*)u;                       // 4,096,000 B
    float*  tau  = (float*)((char*)u + 4096000);    //    64,000 B
    int*    cnt  = (int*)  ((char*)u + 4160000);    //   256,000 B

    hipMemsetAsync(indeg,  0, N_NODES * 4, stream);
    hipMemsetAsync(cursor, 0, N_NODES * 4, stream);
    hipMemsetAsync(gsum,   0, HID * 4, stream);

    prep_kernel<<<NPAD / 256, 256, 0, stream>>>(coords, cand);
    knn_min_kernel<<<dim3(N_NODES / 64, PARTS), 256, 0, stream>>>(coords, cand, minv);
    tau_kernel<<<(N_NODES + 255) / 256, 256, 0, stream>>>(minv, tau);
    knn_collect_kernel<<<dim3(N_NODES / 64, PARTS), 256, 0, stream>>>(coords, cand, tau, cnt, cl);
    knn_select_kernel<<<(N_NODES + 255) / 256, 256, 0, stream>>>(coords, cand, cl, cnt, nbr);

    count_kernel<<<(NEDGE + 255) / 256, 256, 0, stream>>>(nbr, indeg);
    scan_kernel<<<1, 256, 0, stream>>>(indeg, offs, norm);
    fill_kernel<<<(NEDGE + 255) / 256, 256, 0, stream>>>(nbr, offs, cursor, adj);

    dim3 g1(N_NODES / 64, HID / 64);
    gemm_kernel<<<g1, 256, 0, stream>>>(x, We, h, F_IN, nullptr, be);
    for (int l = 0; l < LAYERS; ++l) {
        gemm_kernel<<<g1, 256, 0, stream>>>(h, gnn_W + (size_t)l * HID * HID, u,
                                            HID, norm, nullptr);
        agg_kernel<<<N_NODES / 4, 256, 0, stream>>>(u, norm, gnn_b + (size_t)l * HID,
                                                    offs, adj, h);
    }
    pool_kernel<<<64, 256, 0, stream>>>(h, gsum);
    head_kernel<<<1, 128, 0, stream>>>(gsum, Wp1, bp1, Wp2, bp2, out);
}

// Round 6
// 331.699 us; speedup vs baseline: 2.3323x; 1.1484x over previous
//
#include <hip/hip_runtime.h>
#include <math.h>

#define N_NODES 16000
#define F_IN    16
#define HID     256
#define OUTD    128
#define KNN     8
#define LAYERS  3
#define NEDGE   (N_NODES * KNN)

#define NPAD    16384
#define PARTS   4
#define PART_SZ (NPAD / PARTS)   // 4096
#define SEGS    32               // segs per part (8 queries/thread)
#define NMIN    (PARTS * SEGS)   // 128 per-seg minima per query
#define KT      1024             // candidates per LDS tile (16 KB)
#define CAPP    32               // collected-candidate cap per (query, part)

typedef __attribute__((ext_vector_type(8))) short  s8v;   // 8 bf16
typedef __attribute__((ext_vector_type(4))) float  f4v;

__device__ __forceinline__ unsigned short f2bf(float x) {
    unsigned u = __float_as_uint(x);
    unsigned r = u + 0x7fffu + ((u >> 16) & 1u);   // RNE
    return (unsigned short)(r >> 16);
}
__device__ __forceinline__ float bf2f(unsigned short b) {
    return __uint_as_float(((unsigned)b) << 16);
}

// ---------------------------------------------------------------------------
// cand[i] = (-2x, -2y, -2z, |c|^2); INF-padded. Shifted distance
// d' = fma(qx,-2x, fma(qy,-2y, fma(qz,-2z, |c|^2))) is per-query monotone.
// ---------------------------------------------------------------------------
__global__ __launch_bounds__(256) void prep_kernel(const float* __restrict__ coords,
                                                   float4* __restrict__ cand) {
    int i = blockIdx.x * 256 + threadIdx.x;
    if (i >= NPAD) return;
    if (i < N_NODES) {
        float x = coords[3 * i], y = coords[3 * i + 1], z = coords[3 * i + 2];
        cand[i] = make_float4(-2.f * x, -2.f * y, -2.f * z, x * x + y * y + z * z);
    } else {
        cand[i] = make_float4(0.f, 0.f, 0.f, INFINITY);
    }
}

#define DIST(qx, qy, qz, c) fmaf(qx, c.x, fmaf(qy, c.y, fmaf(qz, c.z, c.w)))

// ---------------------------------------------------------------------------
// Phase 1: per (query, part, seg) minimum. 8 queries/thread: each LDS b128
// feeds 8 distance evals (halves LDS wave-instructions vs 4q/thread).
// ---------------------------------------------------------------------------
__global__ __launch_bounds__(256) void knn_min_kernel(const float* __restrict__ coords,
                                                      const float4* __restrict__ cand,
                                                      float* __restrict__ minv) {
    __shared__ float4 tile[KT];
    int tid  = threadIdx.x;
    int seg  = tid & 31;                  // 0..31
    int qg   = tid >> 5;                  // 0..7
    int qbase = blockIdx.x * 64;
    int part = blockIdx.y;

    float qx[8], qy[8], qz[8], m[8];
#pragma unroll
    for (int i = 0; i < 8; ++i) {
        int q = qbase + i * 8 + qg;
        qx[i] = coords[q * 3]; qy[i] = coords[q * 3 + 1]; qz[i] = coords[q * 3 + 2];
        m[i] = INFINITY;
    }

    int pbase = part * PART_SZ;
    for (int t = 0; t < PART_SZ / KT; ++t) {
        __syncthreads();
        for (int l = tid; l < KT; l += 256) tile[l] = cand[pbase + t * KT + l];
        __syncthreads();
#pragma unroll 2
        for (int g = 0; g < KT / 128; ++g) {
            float4 c0 = tile[g * 128 + seg];
            float4 c1 = tile[g * 128 + seg + 32];
            float4 c2 = tile[g * 128 + seg + 64];
            float4 c3 = tile[g * 128 + seg + 96];
#pragma unroll
            for (int i = 0; i < 8; ++i) {
                float d0 = DIST(qx[i], qy[i], qz[i], c0);
                float d1 = DIST(qx[i], qy[i], qz[i], c1);
                float d2 = DIST(qx[i], qy[i], qz[i], c2);
                float d3 = DIST(qx[i], qy[i], qz[i], c3);
                m[i] = fminf(m[i], fminf(fminf(d0, d1), fminf(d2, d3)));
            }
        }
    }
#pragma unroll
    for (int i = 0; i < 8; ++i) {
        int q = qbase + i * 8 + qg;
        minv[(q * PARTS + part) * SEGS + seg] = m[i];
    }
}

// ---------------------------------------------------------------------------
// Phase 2: merge 128 seg-minima into 16 disjoint-list minima (8 segs each),
// tau[q] = 9th smallest of the 16 (distances of 16 distinct candidates, so
// the 9th smallest of this subset >= true d9: valid collection bound).
// ---------------------------------------------------------------------------
__global__ __launch_bounds__(256) void tau_kernel(const float* __restrict__ minv,
                                                  float* __restrict__ tau) {
    int q = blockIdx.x * 256 + threadIdx.x;
    if (q >= N_NODES) return;
    float b[9];
#pragma unroll
    for (int p = 0; p < 9; ++p) b[p] = INFINITY;
    const float4* mv = (const float4*)(minv + (size_t)q * NMIN);
#pragma unroll
    for (int c = 0; c < 16; ++c) {
        float4 a0 = mv[c * 2], a1 = mv[c * 2 + 1];
        float v = fminf(fminf(fminf(a0.x, a0.y), fminf(a0.z, a0.w)),
                        fminf(fminf(a1.x, a1.y), fminf(a1.z, a1.w)));
#pragma unroll
        for (int p = 8; p >= 1; --p) {
            bool  up = v < b[p - 1];
            float nd = up ? b[p - 1] : (v < b[p] ? v : b[p]);
            b[p] = nd;
        }
        if (v < b[0]) b[0] = v;
    }
    tau[q] = b[8];
}

// ---------------------------------------------------------------------------
// Phase 3: collect all candidates with d <= tau[q] (8 queries/thread).
// Block-LOCAL LDS counters; identical fma as phase 1 -> bit-identical d.
// ---------------------------------------------------------------------------
__global__ __launch_bounds__(256) void knn_collect_kernel(const float* __restrict__ coords,
                                                          const float4* __restrict__ cand,
                                                          const float* __restrict__ tau,
                                                          int* __restrict__ cnt,
                                                          float2* __restrict__ cl) {
    __shared__ float4 tile[KT];
    __shared__ int scnt[64];
    int tid  = threadIdx.x;
    int seg  = tid & 31;
    int qg   = tid >> 5;
    int qbase = blockIdx.x * 64;
    int part  = blockIdx.y;

    float qx[8], qy[8], qz[8], tt[8];
#pragma unroll
    for (int i = 0; i < 8; ++i) {
        int q = qbase + i * 8 + qg;
        qx[i] = coords[q * 3]; qy[i] = coords[q * 3 + 1]; qz[i] = coords[q * 3 + 2];
        tt[i] = tau[q];
    }
    if (tid < 64) scnt[tid] = 0;

    int pbase = part * PART_SZ;
    for (int t = 0; t < PART_SZ / KT; ++t) {
        __syncthreads();
        for (int l = tid; l < KT; l += 256) tile[l] = cand[pbase + t * KT + l];
        __syncthreads();
        int gb = pbase + t * KT;
        for (int g = 0; g < KT / 128; ++g) {
            float4 c0 = tile[g * 128 + seg];
            float4 c1 = tile[g * 128 + seg + 32];
            float4 c2 = tile[g * 128 + seg + 64];
            float4 c3 = tile[g * 128 + seg + 96];
            int jb = gb + g * 128 + seg;
#pragma unroll
            for (int i = 0; i < 8; ++i) {
                int qi = qbase + i * 8 + qg;
                float d0 = DIST(qx[i], qy[i], qz[i], c0);
                float d1 = DIST(qx[i], qy[i], qz[i], c1);
                float d2 = DIST(qx[i], qy[i], qz[i], c2);
                float d3 = DIST(qx[i], qy[i], qz[i], c3);
                if (d0 <= tt[i]) {
                    int pos = atomicAdd(&scnt[i * 8 + qg], 1);
                    if (pos < CAPP) cl[((size_t)qi * PARTS + part) * CAPP + pos] =
                        make_float2(d0, __int_as_float(jb));
                }
                if (d1 <= tt[i]) {
                    int pos = atomicAdd(&scnt[i * 8 + qg], 1);
                    if (pos < CAPP) cl[((size_t)qi * PARTS + part) * CAPP + pos] =
                        make_float2(d1, __int_as_float(jb + 32));
                }
                if (d2 <= tt[i]) {
                    int pos = atomicAdd(&scnt[i * 8 + qg], 1);
                    if (pos < CAPP) cl[((size_t)qi * PARTS + part) * CAPP + pos] =
                        make_float2(d2, __int_as_float(jb + 64));
                }
                if (d3 <= tt[i]) {
                    int pos = atomicAdd(&scnt[i * 8 + qg], 1);
                    if (pos < CAPP) cl[((size_t)qi * PARTS + part) * CAPP + pos] =
                        make_float2(d3, __int_as_float(jb + 96));
                }
            }
        }
    }
    __syncthreads();
    if (tid < 64) cnt[(size_t)(qbase + tid) * PARTS + part] = scnt[tid];
}

// ---------------------------------------------------------------------------
// Phase 4: exact lexicographic (d, idx) top-9 over the 4 part segments.
// ---------------------------------------------------------------------------
#define INS9L(bd, bi, d, j)                                                   \
    {                                                                         \
        _Pragma("unroll")                                                     \
        for (int p = 8; p >= 1; --p) {                                        \
            bool up = (d) < bd[p-1] || ((d) == bd[p-1] && (j) < bi[p-1]);     \
            bool in = (d) < bd[p]   || ((d) == bd[p]   && (j) < bi[p]);       \
            float nd = up ? bd[p-1] : (in ? (d) : bd[p]);                     \
            int   ni = up ? bi[p-1] : (in ? (j) : bi[p]);                     \
            bd[p] = nd; bi[p] = ni;                                           \
        }                                                                     \
        if ((d) < bd[0] || ((d) == bd[0] && (j) < bi[0])) {                   \
            bd[0] = (d); bi[0] = (j);                                         \
        }                                                                     \
    }

__global__ __launch_bounds__(256) void knn_select_kernel(const float* __restrict__ coords,
                                                         const float4* __restrict__ cand,
                                                         const float2* __restrict__ cl,
                                                         const int* __restrict__ cnt,
                                                         int* __restrict__ nbr) {
    int q = blockIdx.x * 256 + threadIdx.x;
    if (q >= N_NODES) return;
    float bd[9]; int bi[9];
#pragma unroll
    for (int p = 0; p < 9; ++p) { bd[p] = INFINITY; bi[p] = 0x7fffffff; }
    int n0 = cnt[(size_t)q * PARTS + 0];
    int n1 = cnt[(size_t)q * PARTS + 1];
    int n2 = cnt[(size_t)q * PARTS + 2];
    int n3 = cnt[(size_t)q * PARTS + 3];
    if (n0 <= CAPP && n1 <= CAPP && n2 <= CAPP && n3 <= CAPP) {
#pragma unroll
        for (int p = 0; p < PARTS; ++p) {
            int n = (p == 0) ? n0 : (p == 1) ? n1 : (p == 2) ? n2 : n3;
            const float2* segp = cl + ((size_t)q * PARTS + p) * CAPP;
            for (int i = 0; i < n; ++i) {
                float2 e = segp[i];
                float d = e.x; int j = __float_as_int(e.y);
                INS9L(bd, bi, d, j);
            }
        }
    } else {  // overflow fallback: exact full rescan (~never fires)
        float qx = coords[q*3], qy = coords[q*3+1], qz = coords[q*3+2];
        for (int j = 0; j < NPAD; ++j) {
            float4 c = cand[j];
            float d = DIST(qx, qy, qz, c);
            if (d < bd[8] || (d == bd[8] && j < bi[8])) INS9L(bd, bi, d, j);
        }
    }
#pragma unroll
    for (int p = 1; p < 9; ++p) nbr[q * 8 + p - 1] = bi[p];
}

// ---------------------------------------------------------------------------
// CSR build
// ---------------------------------------------------------------------------
__global__ void count_kernel(const int* __restrict__ nbr, int* __restrict__ indeg) {
    int e = blockIdx.x * blockDim.x + threadIdx.x;
    if (e < NEDGE) atomicAdd(&indeg[nbr[e]], 1);
}

__global__ __launch_bounds__(256) void scan_kernel(const int* __restrict__ indeg,
                                                   int* __restrict__ offs,
                                                   float* __restrict__ norm) {
    __shared__ int ssum[256];
    int t = threadIdx.x;
    const int CH = 63;
    int base = t * CH;
    int s = 0;
    for (int c = 0; c < CH; ++c) {
        int idx = base + c;
        if (idx < N_NODES) s += indeg[idx];
    }
    ssum[t] = s;
    __syncthreads();
    for (int d = 1; d < 256; d <<= 1) {
        int v = (t >= d) ? ssum[t - d] : 0;
        __syncthreads();
        ssum[t] += v;
        __syncthreads();
    }
    int run = ssum[t] - s;
    for (int c = 0; c < CH; ++c) {
        int idx = base + c;
        if (idx < N_NODES) {
            int dg = indeg[idx];
            offs[idx] = run;
            run += dg;
            norm[idx] = rsqrtf((float)(1 + dg));
        }
    }
    if (t == 255) offs[N_NODES] = ssum[255];
}

__global__ void fill_kernel(const int* __restrict__ nbr, const int* __restrict__ offs,
                            int* __restrict__ cursor, int* __restrict__ adj) {
    int e = blockIdx.x * blockDim.x + threadIdx.x;
    if (e < NEDGE) {
        int d   = nbr[e];
        int src = e >> 3;
        int pos = atomicAdd(&cursor[d], 1);
        adj[offs[d] + pos] = src;
    }
}

// ---------------------------------------------------------------------------
// Encoder GEMM (f32, K=16): C[M x 256] = A[M x 16] @ B[16 x 256] + bias.
// ---------------------------------------------------------------------------
__global__ __launch_bounds__(256) void gemm_kernel(const float* __restrict__ A,
                                                   const float* __restrict__ B,
                                                   float* __restrict__ C,
                                                   int K,
                                                   const float* __restrict__ rowscale,
                                                   const float* __restrict__ bias) {
    __shared__ float As[16][68];
    __shared__ float Bs[16][64];
    int tid = threadIdx.x;
    int rowBase = blockIdx.x * 64;
    int colBase = blockIdx.y * 64;
    int rg = tid >> 4;
    int cg = tid & 15;

    int ar = tid >> 2;
    int ac = (tid & 3) * 4;
    int bk = tid >> 4;
    int bn = (tid & 15) * 4;

    float4 acc0 = {0,0,0,0}, acc1 = {0,0,0,0}, acc2 = {0,0,0,0}, acc3 = {0,0,0,0};

    for (int kb = 0; kb < K; kb += 16) {
        float4 av = *(const float4*)(A + (size_t)(rowBase + ar) * K + kb + ac);
        float4 bv = *(const float4*)(B + (size_t)(kb + bk) * HID + colBase + bn);
        __syncthreads();
        As[ac + 0][ar] = av.x; As[ac + 1][ar] = av.y;
        As[ac + 2][ar] = av.z; As[ac + 3][ar] = av.w;
        *(float4*)&Bs[bk][bn] = bv;
        __syncthreads();
#pragma unroll
        for (int k = 0; k < 16; ++k) {
            float4 a = *(const float4*)&As[k][rg * 4];
            float4 b = *(const float4*)&Bs[k][cg * 4];
            acc0.x = fmaf(a.x, b.x, acc0.x); acc0.y = fmaf(a.x, b.y, acc0.y);
            acc0.z = fmaf(a.x, b.z, acc0.z); acc0.w = fmaf(a.x, b.w, acc0.w);
            acc1.x = fmaf(a.y, b.x, acc1.x); acc1.y = fmaf(a.y, b.y, acc1.y);
            acc1.z = fmaf(a.y, b.z, acc1.z); acc1.w = fmaf(a.y, b.w, acc1.w);
            acc2.x = fmaf(a.z, b.x, acc2.x); acc2.y = fmaf(a.z, b.y, acc2.y);
            acc2.z = fmaf(a.z, b.z, acc2.z); acc2.w = fmaf(a.z, b.w, acc2.w);
            acc3.x = fmaf(a.w, b.x, acc3.x); acc3.y = fmaf(a.w, b.y, acc3.y);
            acc3.z = fmaf(a.w, b.z, acc3.z); acc3.w = fmaf(a.w, b.w, acc3.w);
        }
        __syncthreads();
    }

    int row = rowBase + rg * 4;
    int col = colBase + cg * 4;
    float s0 = 1.f, s1 = 1.f, s2 = 1.f, s3 = 1.f;
    if (rowscale) { s0 = rowscale[row]; s1 = rowscale[row + 1];
                    s2 = rowscale[row + 2]; s3 = rowscale[row + 3]; }
    float4 bb = {0,0,0,0};
    if (bias) bb = *(const float4*)(bias + col);

    float4 v;
    v.x = acc0.x * s0 + bb.x; v.y = acc0.y * s0 + bb.y;
    v.z = acc0.z * s0 + bb.z; v.w = acc0.w * s0 + bb.w;
    *(float4*)(C + (size_t)(row + 0) * HID + col) = v;
    v.x = acc1.x * s1 + bb.x; v.y = acc1.y * s1 + bb.y;
    v.z = acc1.z * s1 + bb.z; v.w = acc1.w * s1 + bb.w;
    *(float4*)(C + (size_t)(row + 1) * HID + col) = v;
    v.x = acc2.x * s2 + bb.x; v.y = acc2.y * s2 + bb.y;
    v.z = acc2.z * s2 + bb.z; v.w = acc2.w * s2 + bb.w;
    *(float4*)(C + (size_t)(row + 2) * HID + col) = v;
    v.x = acc3.x * s3 + bb.x; v.y = acc3.y * s3 + bb.y;
    v.z = acc3.z * s3 + bb.z; v.w = acc3.w * s3 + bb.w;
    *(float4*)(C + (size_t)(row + 3) * HID + col) = v;
}

// ---------------------------------------------------------------------------
// W transpose + split: WThi[j][k] = bf16(W[k][j]), WTlo = bf16(residual).
// ---------------------------------------------------------------------------
__global__ __launch_bounds__(256) void wsplit_kernel(const float* __restrict__ W,
                                                     unsigned short* __restrict__ WThi,
                                                     unsigned short* __restrict__ WTlo) {
    int idx = blockIdx.x * 256 + threadIdx.x;     // 65536 = 256*256
    int k = idx >> 8, j = idx & 255;
    float x = W[idx];                             // W[k][j]
    unsigned short hb = f2bf(x);
    float hf = bf2f(hb);
    WThi[j * 256 + k] = hb;
    WTlo[j * 256 + k] = f2bf(x - hf);
}

// ---------------------------------------------------------------------------
// Split-bf16 MFMA GEMM: u[M x 256] = (h[M x 256] @ W) * norm[row].
// u ~= h_hi @ (Whi + Wlo)  (3 MFMA per tile: hh, hl, lh), f32 accumulate.
// Block: 256 thr = 4 waves; tile 64 rows x 128 cols; K-step 32.
// Fragment layout (gfx950 mfma_f32_16x16x32_bf16, doc-verified):
//   A[i][k]: i = lane&15, k = (lane>>4)*8 + e
//   B[k][j]: j = lane&15, k = (lane>>4)*8 + e   (read from transposed WT)
//   D[i][j]: j = lane&15, i = (lane>>4)*4 + r
// ---------------------------------------------------------------------------
__global__ __launch_bounds__(256) void mfma_gemm_kernel(const float* __restrict__ A,
                                                        const unsigned short* __restrict__ WThi,
                                                        const unsigned short* __restrict__ WTlo,
                                                        float* __restrict__ C,
                                                        const float* __restrict__ rowscale) {
    __shared__ unsigned short Ahi[64][40], Alo[64][40];
    __shared__ unsigned short Bhi[128][40], Blo[128][40];
    int tid = threadIdx.x;
    int rowBase = blockIdx.x * 64;
    int colBase = blockIdx.y * 128;
    int wave = tid >> 6;
    int lane = tid & 63;
    int fr = lane & 15;          // fragment row/col within 16
    int fg = lane >> 4;          // k-group 0..3

    // staging indices
    int asr = tid >> 2;          // 0..63 : A row
    int ask = (tid & 3) * 8;     // 0,8,16,24 : A k-offset
    int bsj = tid >> 1;          // 0..127 : B col (WT row)
    int bsk = (tid & 1) * 16;    // 0,16 : B k-offset (16 ushorts)

    f4v acc[8];
#pragma unroll
    for (int c = 0; c < 8; ++c) acc[c] = (f4v){0.f, 0.f, 0.f, 0.f};

    for (int kb = 0; kb < HID; kb += 32) {
        // global reads
        const float4* ap = (const float4*)(A + (size_t)(rowBase + asr) * HID + kb + ask);
        float4 a0 = ap[0], a1 = ap[1];
        const uint4* bhp = (const uint4*)(WThi + (size_t)(colBase + bsj) * HID + kb + bsk);
        const uint4* blp = (const uint4*)(WTlo + (size_t)(colBase + bsj) * HID + kb + bsk);
        uint4 bh0 = bhp[0], bh1 = bhp[1];
        uint4 bl0 = blp[0], bl1 = blp[1];

        __syncthreads();
        // A convert + write
        {
            float xv[8] = {a0.x, a0.y, a0.z, a0.w, a1.x, a1.y, a1.z, a1.w};
            s8v hv, lv;
#pragma unroll
            for (int e = 0; e < 8; ++e) {
                unsigned short hb = f2bf(xv[e]);
                float hf = bf2f(hb);
                hv[e] = (short)hb;
                lv[e] = (short)f2bf(xv[e] - hf);
            }
            *(s8v*)&Ahi[asr][ask] = hv;
            *(s8v*)&Alo[asr][ask] = lv;
        }
        // B write (already bf16)
        *(uint4*)&Bhi[bsj][bsk]      = bh0;
        *(uint4*)&Bhi[bsj][bsk + 8]  = bh1;
        *(uint4*)&Blo[bsj][bsk]      = bl0;
        *(uint4*)&Blo[bsj][bsk + 8]  = bl1;
        __syncthreads();

        s8v afh = *(s8v*)&Ahi[wave * 16 + fr][fg * 8];
        s8v afl = *(s8v*)&Alo[wave * 16 + fr][fg * 8];
#pragma unroll
        for (int c = 0; c < 8; ++c) {
            s8v bfh = *(s8v*)&Bhi[c * 16 + fr][fg * 8];
            s8v bfl = *(s8v*)&Blo[c * 16 + fr][fg * 8];
            acc[c] = __builtin_amdgcn_mfma_f32_16x16x32_bf16(afh, bfh, acc[c], 0, 0, 0);
            acc[c] = __builtin_amdgcn_mfma_f32_16x16x32_bf16(afh, bfl, acc[c], 0, 0, 0);
            acc[c] = __builtin_amdgcn_mfma_f32_16x16x32_bf16(afl, bfh, acc[c], 0, 0, 0);
        }
    }

    // epilogue: D[i][j]: i = fg*4 + r, j = fr
    float sc[4];
#pragma unroll
    for (int r = 0; r < 4; ++r) sc[r] = rowscale[rowBase + wave * 16 + fg * 4 + r];
#pragma unroll
    for (int c = 0; c < 8; ++c) {
        int col = colBase + c * 16 + fr;
#pragma unroll
        for (int r = 0; r < 4; ++r) {
            int row = rowBase + wave * 16 + fg * 4 + r;
            C[(size_t)row * HID + col] = acc[c][r] * sc[r];
        }
    }
}

// ---------------------------------------------------------------------------
// Aggregation: h[j] = relu(norm[j]*(u[j] + sum_{i->j} u[i]) + b)
// ---------------------------------------------------------------------------
__global__ __launch_bounds__(256) void agg_kernel(const float* __restrict__ u,
                                                  const float* __restrict__ norm,
                                                  const float* __restrict__ bias,
                                                  const int* __restrict__ offs,
                                                  const int* __restrict__ adj,
                                                  float* __restrict__ hout) {
    int node = blockIdx.x * 4 + (threadIdx.x >> 6);
    int lane = threadIdx.x & 63;
    const float4* up = (const float4*)u;
    float4 acc = up[(size_t)node * 64 + lane];
    int e0 = offs[node], e1 = offs[node + 1];
    for (int e = e0; e < e1; ++e) {
        int s = adj[e];
        float4 v = up[(size_t)s * 64 + lane];
        acc.x += v.x; acc.y += v.y; acc.z += v.z; acc.w += v.w;
    }
    float nm = norm[node];
    float4 bb = ((const float4*)bias)[lane];
    float4 r;
    r.x = fmaxf(fmaf(nm, acc.x, bb.x), 0.0f);
    r.y = fmaxf(fmaf(nm, acc.y, bb.y), 0.0f);
    r.z = fmaxf(fmaf(nm, acc.z, bb.z), 0.0f);
    r.w = fmaxf(fmaf(nm, acc.w, bb.w), 0.0f);
    ((float4*)hout)[(size_t)node * 64 + lane] = r;
}

// ---------------------------------------------------------------------------
// Mean pool and 2-layer MLP head (f32)
// ---------------------------------------------------------------------------
__global__ __launch_bounds__(256) void pool_kernel(const float* __restrict__ h,
                                                   float* __restrict__ gsum) {
    int t = threadIdx.x;
    float acc = 0.f;
    int start = blockIdx.x * 250;
    for (int i = 0; i < 250; ++i) acc += h[(size_t)(start + i) * HID + t];
    atomicAdd(&gsum[t], acc);
}

__global__ __launch_bounds__(128) void head_kernel(const float* __restrict__ gsum,
                                                   const float* __restrict__ Wp1,
                                                   const float* __restrict__ bp1,
                                                   const float* __restrict__ Wp2,
                                                   const float* __restrict__ bp2,
                                                   float* __restrict__ out) {
    __shared__ float gl[256];
    __shared__ float hid[128];
    int t = threadIdx.x;
    const float inv = 1.0f / 16000.0f;
    gl[t]       = gsum[t]       * inv;
    gl[t + 128] = gsum[t + 128] * inv;
    __syncthreads();
    float a = bp1[t];
    for (int k = 0; k < 256; ++k) a = fmaf(gl[k], Wp1[k * 128 + t], a);
    hid[t] = fmaxf(a, 0.0f);
    __syncthreads();
    float o = bp2[t];
    for (int k = 0; k < 128; ++k) o = fmaf(hid[k], Wp2[k * 128 + t], o);
    out[t] = o;
}

// ---------------------------------------------------------------------------
extern "C" void kernel_launch(void* const* d_in, const int* in_sizes, int n_in,
                              void* d_out, int out_size, void* d_ws, size_t ws_size,
                              hipStream_t stream) {
    const float* x      = (const float*)d_in[0];
    const float* coords = (const float*)d_in[1];
    const float* We     = (const float*)d_in[2];
    const float* be     = (const float*)d_in[3];
    const float* gnn_W  = (const float*)d_in[4];
    const float* gnn_b  = (const float*)d_in[5];
    const float* Wp1    = (const float*)d_in[6];
    const float* bp1    = (const float*)d_in[7];
    const float* Wp2    = (const float*)d_in[8];
    const float* bp2    = (const float*)d_in[9];
    float* out = (float*)d_out;

    char* ws = (char*)d_ws;
    float* h     = (float*)(ws + 0);          // 16,384,000 B
    float* u     = (float*)(ws + 16384000);   // 16,384,000 B
    int*   nbr   = (int*)  (ws + 32768000);   // 512,000 B
    int*   adj   = (int*)  (ws + 33280000);   // 512,000 B
    int*   indeg = (int*)  (ws + 33792000);   // 64,000 B
    int*   offs  = (int*)  (ws + 33856000);   // 64,004 B (padded)
    int*   cursor= (int*)  (ws + 33920256);   // 64,000 B
    float* norm  = (float*)(ws + 33984256);   // 64,000 B
    float* gsum  = (float*)(ws + 34048256);   // 1,024 B
    float4* cand = (float4*)(ws + 34049280);  // 262,144 B (kNN; reused as WT)
    // kNN scratch aliases the not-yet-live h and u buffers:
    float2* cl   = (float2*)h;                       // 16000*4*32*8 = 16,384,000 B
    float*  minv = (float*)u;                        // 16000*128*4 = 8,192,000 B
    float*  tau  = (float*)((char*)u + 8192000);     //    64,000 B
    int*    cnt  = (int*)  ((char*)u + 8256000);     //   256,000 B
    // per-layer transposed/split weights reuse the dead cand region (262,144 B)
    unsigned short* WThi = (unsigned short*)cand;    // 131,072 B
    unsigned short* WTlo = WThi + 65536;             // 131,072 B

    hipMemsetAsync(indeg,  0, N_NODES * 4, stream);
    hipMemsetAsync(cursor, 0, N_NODES * 4, stream);
    hipMemsetAsync(gsum,   0, HID * 4, stream);

    prep_kernel<<<NPAD / 256, 256, 0, stream>>>(coords, cand);
    knn_min_kernel<<<dim3(N_NODES / 64, PARTS), 256, 0, stream>>>(coords, cand, minv);
    tau_kernel<<<(N_NODES + 255) / 256, 256, 0, stream>>>(minv, tau);
    knn_collect_kernel<<<dim3(N_NODES / 64, PARTS), 256, 0, stream>>>(coords, cand, tau, cnt, cl);
    knn_select_kernel<<<(N_NODES + 255) / 256, 256, 0, stream>>>(coords, cand, cl, cnt, nbr);

    count_kernel<<<(NEDGE + 255) / 256, 256, 0, stream>>>(nbr, indeg);
    scan_kernel<<<1, 256, 0, stream>>>(indeg, offs, norm);
    fill_kernel<<<(NEDGE + 255) / 256, 256, 0, stream>>>(nbr, offs, cursor, adj);

    dim3 g1(N_NODES / 64, HID / 64);
    gemm_kernel<<<g1, 256, 0, stream>>>(x, We, h, F_IN, nullptr, be);
    for (int l = 0; l < LAYERS; ++l) {
        wsplit_kernel<<<256, 256, 0, stream>>>(gnn_W + (size_t)l * HID * HID, WThi, WTlo);
        mfma_gemm_kernel<<<dim3(N_NODES / 64, 2), 256, 0, stream>>>(h, WThi, WTlo, u, norm);
        agg_kernel<<<N_NODES / 4, 256, 0, stream>>>(u, norm, gnn_b + (size_t)l * HID,
                                                    offs, adj, h);
    }
    pool_kernel<<<64, 256, 0, stream>>>(h, gsum);
    head_kernel<<<1, 128, 0, stream>>>(gsum, Wp1, bp1, Wp2, bp2, out);
}

// Round 8
// 307.084 us; speedup vs baseline: 2.5193x; 1.0802x over previous
//
#include <hip/hip_runtime.h>
#include <math.h>

#define N_NODES 16000
#define F_IN    16
#define HID     256
#define OUTD    128
#define KNN     8
#define LAYERS  3
#define NEDGE   (N_NODES * KNN)

#define NPAD    16384
#define PARTS   4
#define PART_SZ (NPAD / PARTS)   // 4096
#define SEGS    32               // segs per part (8 queries/thread)
#define NMIN    (PARTS * SEGS)   // 128 per-seg minima per query
#define KT      1024             // candidates per LDS tile (16 KB)
#define CAPP    32               // collected-candidate cap per (query, part)

typedef __attribute__((ext_vector_type(8))) short  s8v;   // 8 bf16
typedef __attribute__((ext_vector_type(4))) float  f4v;

__device__ __forceinline__ unsigned short f2bf(float x) {
    unsigned u = __float_as_uint(x);
    unsigned r = u + 0x7fffu + ((u >> 16) & 1u);   // RNE
    return (unsigned short)(r >> 16);
}
__device__ __forceinline__ float bf2f(unsigned short b) {
    return __uint_as_float(((unsigned)b) << 16);
}

// ---------------------------------------------------------------------------
// cand[i] = (-2x, -2y, -2z, |c|^2); INF-padded. Shifted distance
// d' = fma(qx,-2x, fma(qy,-2y, fma(qz,-2z, |c|^2))) is per-query monotone.
// ---------------------------------------------------------------------------
__global__ __launch_bounds__(256) void prep_kernel(const float* __restrict__ coords,
                                                   float4* __restrict__ cand) {
    int i = blockIdx.x * 256 + threadIdx.x;
    if (i >= NPAD) return;
    if (i < N_NODES) {
        float x = coords[3 * i], y = coords[3 * i + 1], z = coords[3 * i + 2];
        cand[i] = make_float4(-2.f * x, -2.f * y, -2.f * z, x * x + y * y + z * z);
    } else {
        cand[i] = make_float4(0.f, 0.f, 0.f, INFINITY);
    }
}

#define DIST(qx, qy, qz, c) fmaf(qx, c.x, fmaf(qy, c.y, fmaf(qz, c.z, c.w)))

// ---------------------------------------------------------------------------
// Phase 1: per (query, part, seg) minimum. 8 queries/thread, branchless.
// ---------------------------------------------------------------------------
__global__ __launch_bounds__(256) void knn_min_kernel(const float* __restrict__ coords,
                                                      const float4* __restrict__ cand,
                                                      float* __restrict__ minv) {
    __shared__ float4 tile[KT];
    int tid  = threadIdx.x;
    int seg  = tid & 31;
    int qg   = tid >> 5;
    int qbase = blockIdx.x * 64;
    int part = blockIdx.y;

    float qx[8], qy[8], qz[8], m[8];
#pragma unroll
    for (int i = 0; i < 8; ++i) {
        int q = qbase + i * 8 + qg;
        qx[i] = coords[q * 3]; qy[i] = coords[q * 3 + 1]; qz[i] = coords[q * 3 + 2];
        m[i] = INFINITY;
    }

    int pbase = part * PART_SZ;
    for (int t = 0; t < PART_SZ / KT; ++t) {
        __syncthreads();
        for (int l = tid; l < KT; l += 256) tile[l] = cand[pbase + t * KT + l];
        __syncthreads();
#pragma unroll 2
        for (int g = 0; g < KT / 128; ++g) {
            float4 c0 = tile[g * 128 + seg];
            float4 c1 = tile[g * 128 + seg + 32];
            float4 c2 = tile[g * 128 + seg + 64];
            float4 c3 = tile[g * 128 + seg + 96];
#pragma unroll
            for (int i = 0; i < 8; ++i) {
                float d0 = DIST(qx[i], qy[i], qz[i], c0);
                float d1 = DIST(qx[i], qy[i], qz[i], c1);
                float d2 = DIST(qx[i], qy[i], qz[i], c2);
                float d3 = DIST(qx[i], qy[i], qz[i], c3);
                m[i] = fminf(m[i], fminf(fminf(d0, d1), fminf(d2, d3)));
            }
        }
    }
#pragma unroll
    for (int i = 0; i < 8; ++i) {
        int q = qbase + i * 8 + qg;
        minv[(q * PARTS + part) * SEGS + seg] = m[i];
    }
}

// ---------------------------------------------------------------------------
// Phase 2: tau[q] = 9th smallest of 16 merged-list minima (valid bound).
// ---------------------------------------------------------------------------
__global__ __launch_bounds__(256) void tau_kernel(const float* __restrict__ minv,
                                                  float* __restrict__ tau) {
    int q = blockIdx.x * 256 + threadIdx.x;
    if (q >= N_NODES) return;
    float b[9];
#pragma unroll
    for (int p = 0; p < 9; ++p) b[p] = INFINITY;
    const float4* mv = (const float4*)(minv + (size_t)q * NMIN);
#pragma unroll
    for (int c = 0; c < 16; ++c) {
        float4 a0 = mv[c * 2], a1 = mv[c * 2 + 1];
        float v = fminf(fminf(fminf(a0.x, a0.y), fminf(a0.z, a0.w)),
                        fminf(fminf(a1.x, a1.y), fminf(a1.z, a1.w)));
#pragma unroll
        for (int p = 8; p >= 1; --p) {
            bool  up = v < b[p - 1];
            float nd = up ? b[p - 1] : (v < b[p] ? v : b[p]);
            b[p] = nd;
        }
        if (v < b[0]) b[0] = v;
    }
    tau[q] = b[8];
}

// ---------------------------------------------------------------------------
// Phase 3: collect candidates with d <= tau[q]. min4-GATE: one compare per
// (group, query); the 4 per-distance appends only run in the rare region.
// Identical fma expression as phase 1 -> bit-identical d -> bound exact.
// ---------------------------------------------------------------------------
__global__ __launch_bounds__(256) void knn_collect_kernel(const float* __restrict__ coords,
                                                          const float4* __restrict__ cand,
                                                          const float* __restrict__ tau,
                                                          int* __restrict__ cnt,
                                                          float2* __restrict__ cl) {
    __shared__ float4 tile[KT];
    __shared__ int scnt[64];
    int tid  = threadIdx.x;
    int seg  = tid & 31;
    int qg   = tid >> 5;
    int qbase = blockIdx.x * 64;
    int part  = blockIdx.y;

    float qx[8], qy[8], qz[8], tt[8];
#pragma unroll
    for (int i = 0; i < 8; ++i) {
        int q = qbase + i * 8 + qg;
        qx[i] = coords[q * 3]; qy[i] = coords[q * 3 + 1]; qz[i] = coords[q * 3 + 2];
        tt[i] = tau[q];
    }
    if (tid < 64) scnt[tid] = 0;

    int pbase = part * PART_SZ;
    for (int t = 0; t < PART_SZ / KT; ++t) {
        __syncthreads();
        for (int l = tid; l < KT; l += 256) tile[l] = cand[pbase + t * KT + l];
        __syncthreads();
        int gb = pbase + t * KT;
        for (int g = 0; g < KT / 128; ++g) {
            float4 c0 = tile[g * 128 + seg];
            float4 c1 = tile[g * 128 + seg + 32];
            float4 c2 = tile[g * 128 + seg + 64];
            float4 c3 = tile[g * 128 + seg + 96];
            int jb = gb + g * 128 + seg;
#pragma unroll
            for (int i = 0; i < 8; ++i) {
                float d0 = DIST(qx[i], qy[i], qz[i], c0);
                float d1 = DIST(qx[i], qy[i], qz[i], c1);
                float d2 = DIST(qx[i], qy[i], qz[i], c2);
                float d3 = DIST(qx[i], qy[i], qz[i], c3);
                float m4 = fminf(fminf(d0, d1), fminf(d2, d3));
                if (m4 <= tt[i]) {
                    int qi = qbase + i * 8 + qg;
                    int cb = (int)(((size_t)qi * PARTS + part) * CAPP);
                    if (d0 <= tt[i]) {
                        int pos = atomicAdd(&scnt[i * 8 + qg], 1);
                        if (pos < CAPP) cl[cb + pos] = make_float2(d0, __int_as_float(jb));
                    }
                    if (d1 <= tt[i]) {
                        int pos = atomicAdd(&scnt[i * 8 + qg], 1);
                        if (pos < CAPP) cl[cb + pos] = make_float2(d1, __int_as_float(jb + 32));
                    }
                    if (d2 <= tt[i]) {
                        int pos = atomicAdd(&scnt[i * 8 + qg], 1);
                        if (pos < CAPP) cl[cb + pos] = make_float2(d2, __int_as_float(jb + 64));
                    }
                    if (d3 <= tt[i]) {
                        int pos = atomicAdd(&scnt[i * 8 + qg], 1);
                        if (pos < CAPP) cl[cb + pos] = make_float2(d3, __int_as_float(jb + 96));
                    }
                }
            }
        }
    }
    __syncthreads();
    if (tid < 64) cnt[(size_t)(qbase + tid) * PARTS + part] = scnt[tid];
}

// ---------------------------------------------------------------------------
// Phase 4: exact lexicographic (d, idx) top-9 over the 4 part segments.
// ---------------------------------------------------------------------------
#define INS9L(bd, bi, d, j)                                                   \
    {                                                                         \
        _Pragma("unroll")                                                     \
        for (int p = 8; p >= 1; --p) {                                        \
            bool up = (d) < bd[p-1] || ((d) == bd[p-1] && (j) < bi[p-1]);     \
            bool in = (d) < bd[p]   || ((d) == bd[p]   && (j) < bi[p]);       \
            float nd = up ? bd[p-1] : (in ? (d) : bd[p]);                     \
            int   ni = up ? bi[p-1] : (in ? (j) : bi[p]);                     \
            bd[p] = nd; bi[p] = ni;                                           \
        }                                                                     \
        if ((d) < bd[0] || ((d) == bd[0] && (j) < bi[0])) {                   \
            bd[0] = (d); bi[0] = (j);                                         \
        }                                                                     \
    }

__global__ __launch_bounds__(256) void knn_select_kernel(const float* __restrict__ coords,
                                                         const float4* __restrict__ cand,
                                                         const float2* __restrict__ cl,
                                                         const int* __restrict__ cnt,
                                                         int* __restrict__ nbr) {
    int q = blockIdx.x * 256 + threadIdx.x;
    if (q >= N_NODES) return;
    float bd[9]; int bi[9];
#pragma unroll
    for (int p = 0; p < 9; ++p) { bd[p] = INFINITY; bi[p] = 0x7fffffff; }
    int n0 = cnt[(size_t)q * PARTS + 0];
    int n1 = cnt[(size_t)q * PARTS + 1];
    int n2 = cnt[(size_t)q * PARTS + 2];
    int n3 = cnt[(size_t)q * PARTS + 3];
    if (n0 <= CAPP && n1 <= CAPP && n2 <= CAPP && n3 <= CAPP) {
#pragma unroll
        for (int p = 0; p < PARTS; ++p) {
            int n = (p == 0) ? n0 : (p == 1) ? n1 : (p == 2) ? n2 : n3;
            const float2* segp = cl + ((size_t)q * PARTS + p) * CAPP;
            for (int i = 0; i < n; ++i) {
                float2 e = segp[i];
                float d = e.x; int j = __float_as_int(e.y);
                INS9L(bd, bi, d, j);
            }
        }
    } else {
        float qx = coords[q*3], qy = coords[q*3+1], qz = coords[q*3+2];
        for (int j = 0; j < NPAD; ++j) {
            float4 c = cand[j];
            float d = DIST(qx, qy, qz, c);
            if (d < bd[8] || (d == bd[8] && j < bi[8])) INS9L(bd, bi, d, j);
        }
    }
#pragma unroll
    for (int p = 1; p < 9; ++p) nbr[q * 8 + p - 1] = bi[p];
}

// ---------------------------------------------------------------------------
// CSR build
// ---------------------------------------------------------------------------
__global__ void count_kernel(const int* __restrict__ nbr, int* __restrict__ indeg) {
    int e = blockIdx.x * blockDim.x + threadIdx.x;
    if (e < NEDGE) atomicAdd(&indeg[nbr[e]], 1);
}

__global__ __launch_bounds__(256) void scan_kernel(const int* __restrict__ indeg,
                                                   int* __restrict__ offs,
                                                   float* __restrict__ norm) {
    __shared__ int ssum[256];
    int t = threadIdx.x;
    const int CH = 63;
    int base = t * CH;
    int s = 0;
    for (int c = 0; c < CH; ++c) {
        int idx = base + c;
        if (idx < N_NODES) s += indeg[idx];
    }
    ssum[t] = s;
    __syncthreads();
    for (int d = 1; d < 256; d <<= 1) {
        int v = (t >= d) ? ssum[t - d] : 0;
        __syncthreads();
        ssum[t] += v;
        __syncthreads();
    }
    int run = ssum[t] - s;
    for (int c = 0; c < CH; ++c) {
        int idx = base + c;
        if (idx < N_NODES) {
            int dg = indeg[idx];
            offs[idx] = run;
            run += dg;
            norm[idx] = rsqrtf((float)(1 + dg));
        }
    }
    if (t == 255) offs[N_NODES] = ssum[255];
}

__global__ void fill_kernel(const int* __restrict__ nbr, const int* __restrict__ offs,
                            int* __restrict__ cursor, int* __restrict__ adj) {
    int e = blockIdx.x * blockDim.x + threadIdx.x;
    if (e < NEDGE) {
        int d   = nbr[e];
        int src = e >> 3;
        int pos = atomicAdd(&cursor[d], 1);
        adj[offs[d] + pos] = src;
    }
}

// ---------------------------------------------------------------------------
// Encoder GEMM (f32, K=16): h[M x 256] = x[M x 16] @ We + be.
// ---------------------------------------------------------------------------
__global__ __launch_bounds__(256) void gemm_kernel(const float* __restrict__ A,
                                                   const float* __restrict__ B,
                                                   float* __restrict__ C,
                                                   int K,
                                                   const float* __restrict__ rowscale,
                                                   const float* __restrict__ bias) {
    __shared__ float As[16][68];
    __shared__ float Bs[16][64];
    int tid = threadIdx.x;
    int rowBase = blockIdx.x * 64;
    int colBase = blockIdx.y * 64;
    int rg = tid >> 4;
    int cg = tid & 15;

    int ar = tid >> 2;
    int ac = (tid & 3) * 4;
    int bk = tid >> 4;
    int bn = (tid & 15) * 4;

    float4 acc0 = {0,0,0,0}, acc1 = {0,0,0,0}, acc2 = {0,0,0,0}, acc3 = {0,0,0,0};

    for (int kb = 0; kb < K; kb += 16) {
        float4 av = *(const float4*)(A + (size_t)(rowBase + ar) * K + kb + ac);
        float4 bv = *(const float4*)(B + (size_t)(kb + bk) * HID + colBase + bn);
        __syncthreads();
        As[ac + 0][ar] = av.x; As[ac + 1][ar] = av.y;
        As[ac + 2][ar] = av.z; As[ac + 3][ar] = av.w;
        *(float4*)&Bs[bk][bn] = bv;
        __syncthreads();
#pragma unroll
        for (int k = 0; k < 16; ++k) {
            float4 a = *(const float4*)&As[k][rg * 4];
            float4 b = *(const float4*)&Bs[k][cg * 4];
            acc0.x = fmaf(a.x, b.x, acc0.x); acc0.y = fmaf(a.x, b.y, acc0.y);
            acc0.z = fmaf(a.x, b.z, acc0.z); acc0.w = fmaf(a.x, b.w, acc0.w);
            acc1.x = fmaf(a.y, b.x, acc1.x); acc1.y = fmaf(a.y, b.y, acc1.y);
            acc1.z = fmaf(a.y, b.z, acc1.z); acc1.w = fmaf(a.y, b.w, acc1.w);
            acc2.x = fmaf(a.z, b.x, acc2.x); acc2.y = fmaf(a.z, b.y, acc2.y);
            acc2.z = fmaf(a.z, b.z, acc2.z); acc2.w = fmaf(a.z, b.w, acc2.w);
            acc3.x = fmaf(a.w, b.x, acc3.x); acc3.y = fmaf(a.w, b.y, acc3.y);
            acc3.z = fmaf(a.w, b.z, acc3.z); acc3.w = fmaf(a.w, b.w, acc3.w);
        }
        __syncthreads();
    }

    int row = rowBase + rg * 4;
    int col = colBase + cg * 4;
    float s0 = 1.f, s1 = 1.f, s2 = 1.f, s3 = 1.f;
    if (rowscale) { s0 = rowscale[row]; s1 = rowscale[row + 1];
                    s2 = rowscale[row + 2]; s3 = rowscale[row + 3]; }
    float4 bb = {0,0,0,0};
    if (bias) bb = *(const float4*)(bias + col);

    float4 v;
    v.x = acc0.x * s0 + bb.x; v.y = acc0.y * s0 + bb.y;
    v.z = acc0.z * s0 + bb.z; v.w = acc0.w * s0 + bb.w;
    *(float4*)(C + (size_t)(row + 0) * HID + col) = v;
    v.x = acc1.x * s1 + bb.x; v.y = acc1.y * s1 + bb.y;
    v.z = acc1.z * s1 + bb.z; v.w = acc1.w * s1 + bb.w;
    *(float4*)(C + (size_t)(row + 1) * HID + col) = v;
    v.x = acc2.x * s2 + bb.x; v.y = acc2.y * s2 + bb.y;
    v.z = acc2.z * s2 + bb.z; v.w = acc2.w * s2 + bb.w;
    *(float4*)(C + (size_t)(row + 2) * HID + col) = v;
    v.x = acc3.x * s3 + bb.x; v.y = acc3.y * s3 + bb.y;
    v.z = acc3.z * s3 + bb.z; v.w = acc3.w * s3 + bb.w;
    *(float4*)(C + (size_t)(row + 3) * HID + col) = v;
}

// ---------------------------------------------------------------------------
// W transpose + split for ALL layers: WThi[l][j][k] = bf16(W[l][k][j]),
// WTlo = bf16(residual). One dispatch.
// ---------------------------------------------------------------------------
__global__ __launch_bounds__(256) void wsplit_kernel(const float* __restrict__ W,
                                                     unsigned short* __restrict__ WThi,
                                                     unsigned short* __restrict__ WTlo) {
    int idx = blockIdx.x * 256 + threadIdx.x;
    int l = idx >> 16;
    int r = idx & 65535;
    int k = r >> 8, j = r & 255;
    float x = W[idx];
    unsigned short hb = f2bf(x);
    float hf = bf2f(hb);
    size_t o = (size_t)l * 65536 + j * 256 + k;
    WThi[o] = hb;
    WTlo[o] = f2bf(x - hf);
}

// ---------------------------------------------------------------------------
// Split-bf16 MFMA GEMM: u16[M x 256] = bf16((h[M x 256] @ W) * norm[row]).
// acc = hh + hl + lh in f32 (a_lo*b_lo ~ 2^-18, dropped).
// Fragment layout (gfx950 mfma_f32_16x16x32_bf16, doc-verified):
//   A[i][k]: i = lane&15, k = (lane>>4)*8 + e ; B likewise from transposed WT;
//   D[i][j]: j = lane&15, i = (lane>>4)*4 + r.
// ---------------------------------------------------------------------------
__global__ __launch_bounds__(256) void mfma_gemm_kernel(const float* __restrict__ A,
                                                        const unsigned short* __restrict__ WThi,
                                                        const unsigned short* __restrict__ WTlo,
                                                        unsigned short* __restrict__ C,
                                                        const float* __restrict__ rowscale) {
    __shared__ unsigned short Ahi[64][40], Alo[64][40];
    __shared__ unsigned short Bhi[128][40], Blo[128][40];
    int tid = threadIdx.x;
    int rowBase = blockIdx.x * 64;
    int colBase = blockIdx.y * 128;
    int wave = tid >> 6;
    int lane = tid & 63;
    int fr = lane & 15;
    int fg = lane >> 4;

    int asr = tid >> 2;
    int ask = (tid & 3) * 8;
    int bsj = tid >> 1;
    int bsk = (tid & 1) * 16;

    f4v acc[8];
#pragma unroll
    for (int c = 0; c < 8; ++c) acc[c] = (f4v){0.f, 0.f, 0.f, 0.f};

    for (int kb = 0; kb < HID; kb += 32) {
        const float4* ap = (const float4*)(A + (size_t)(rowBase + asr) * HID + kb + ask);
        float4 a0 = ap[0], a1 = ap[1];
        const uint4* bhp = (const uint4*)(WThi + (size_t)(colBase + bsj) * HID + kb + bsk);
        const uint4* blp = (const uint4*)(WTlo + (size_t)(colBase + bsj) * HID + kb + bsk);
        uint4 bh0 = bhp[0], bh1 = bhp[1];
        uint4 bl0 = blp[0], bl1 = blp[1];

        __syncthreads();
        {
            float xv[8] = {a0.x, a0.y, a0.z, a0.w, a1.x, a1.y, a1.z, a1.w};
            s8v hv, lv;
#pragma unroll
            for (int e = 0; e < 8; ++e) {
                unsigned short hb = f2bf(xv[e]);
                float hf = bf2f(hb);
                hv[e] = (short)hb;
                lv[e] = (short)f2bf(xv[e] - hf);
            }
            *(s8v*)&Ahi[asr][ask] = hv;
            *(s8v*)&Alo[asr][ask] = lv;
        }
        *(uint4*)&Bhi[bsj][bsk]      = bh0;
        *(uint4*)&Bhi[bsj][bsk + 8]  = bh1;
        *(uint4*)&Blo[bsj][bsk]      = bl0;
        *(uint4*)&Blo[bsj][bsk + 8]  = bl1;
        __syncthreads();

        s8v afh = *(s8v*)&Ahi[wave * 16 + fr][fg * 8];
        s8v afl = *(s8v*)&Alo[wave * 16 + fr][fg * 8];
#pragma unroll
        for (int c = 0; c < 8; ++c) {
            s8v bfh = *(s8v*)&Bhi[c * 16 + fr][fg * 8];
            s8v bfl = *(s8v*)&Blo[c * 16 + fr][fg * 8];
            acc[c] = __builtin_amdgcn_mfma_f32_16x16x32_bf16(afh, bfh, acc[c], 0, 0, 0);
            acc[c] = __builtin_amdgcn_mfma_f32_16x16x32_bf16(afh, bfl, acc[c], 0, 0, 0);
            acc[c] = __builtin_amdgcn_mfma_f32_16x16x32_bf16(afl, bfh, acc[c], 0, 0, 0);
        }
    }

    float sc[4];
#pragma unroll
    for (int r = 0; r < 4; ++r) sc[r] = rowscale[rowBase + wave * 16 + fg * 4 + r];
#pragma unroll
    for (int c = 0; c < 8; ++c) {
        int col = colBase + c * 16 + fr;
#pragma unroll
        for (int r = 0; r < 4; ++r) {
            int row = rowBase + wave * 16 + fg * 4 + r;
            C[(size_t)row * HID + col] = f2bf(acc[c][r] * sc[r]);
        }
    }
}

// ---------------------------------------------------------------------------
// Aggregation: h[j] = relu(norm[j]*(u[j] + sum_{i->j} u[i]) + b); u is bf16.
// ---------------------------------------------------------------------------
__global__ __launch_bounds__(256) void agg_kernel(const unsigned short* __restrict__ u,
                                                  const float* __restrict__ norm,
                                                  const float* __restrict__ bias,
                                                  const int* __restrict__ offs,
                                                  const int* __restrict__ adj,
                                                  float* __restrict__ hout) {
    int node = blockIdx.x * 4 + (threadIdx.x >> 6);
    int lane = threadIdx.x & 63;
    const ushort4* up = (const ushort4*)u;
    ushort4 sv = up[(size_t)node * 64 + lane];
    float ax = bf2f(sv.x), ay = bf2f(sv.y), az = bf2f(sv.z), aw = bf2f(sv.w);
    int e0 = offs[node], e1 = offs[node + 1];
    for (int e = e0; e < e1; ++e) {
        int s = adj[e];
        ushort4 v = up[(size_t)s * 64 + lane];
        ax += bf2f(v.x); ay += bf2f(v.y); az += bf2f(v.z); aw += bf2f(v.w);
    }
    float nm = norm[node];
    float4 bb = ((const float4*)bias)[lane];
    float4 r;
    r.x = fmaxf(fmaf(nm, ax, bb.x), 0.0f);
    r.y = fmaxf(fmaf(nm, ay, bb.y), 0.0f);
    r.z = fmaxf(fmaf(nm, az, bb.z), 0.0f);
    r.w = fmaxf(fmaf(nm, aw, bb.w), 0.0f);
    ((float4*)hout)[(size_t)node * 64 + lane] = r;
}

// ---------------------------------------------------------------------------
// Mean pool and 2-layer MLP head (f32)
// ---------------------------------------------------------------------------
__global__ __launch_bounds__(256) void pool_kernel(const float* __restrict__ h,
                                                   float* __restrict__ gsum) {
    int t = threadIdx.x;
    float acc = 0.f;
    int start = blockIdx.x * 250;
    for (int i = 0; i < 250; ++i) acc += h[(size_t)(start + i) * HID + t];
    atomicAdd(&gsum[t], acc);
}

__global__ __launch_bounds__(128) void head_kernel(const float* __restrict__ gsum,
                                                   const float* __restrict__ Wp1,
                                                   const float* __restrict__ bp1,
                                                   const float* __restrict__ Wp2,
                                                   const float* __restrict__ bp2,
                                                   float* __restrict__ out) {
    __shared__ float gl[256];
    __shared__ float hid[128];
    int t = threadIdx.x;
    const float inv = 1.0f / 16000.0f;
    gl[t]       = gsum[t]       * inv;
    gl[t + 128] = gsum[t + 128] * inv;
    __syncthreads();
    float a = bp1[t];
    for (int k = 0; k < 256; ++k) a = fmaf(gl[k], Wp1[k * 128 + t], a);
    hid[t] = fmaxf(a, 0.0f);
    __syncthreads();
    float o = bp2[t];
    for (int k = 0; k < 128; ++k) o = fmaf(hid[k], Wp2[k * 128 + t], o);
    out[t] = o;
}

// ---------------------------------------------------------------------------
extern "C" void kernel_launch(void* const* d_in, const int* in_sizes, int n_in,
                              void* d_out, int out_size, void* d_ws, size_t ws_size,
                              hipStream_t stream) {
    const float* x      = (const float*)d_in[0];
    const float* coords = (const float*)d_in[1];
    const float* We     = (const float*)d_in[2];
    const float* be     = (const float*)d_in[3];
    const float* gnn_W  = (const float*)d_in[4];
    const float* gnn_b  = (const float*)d_in[5];
    const float* Wp1    = (const float*)d_in[6];
    const float* bp1    = (const float*)d_in[7];
    const float* Wp2    = (const float*)d_in[8];
    const float* bp2    = (const float*)d_in[9];
    float* out = (float*)d_out;

    char* ws = (char*)d_ws;
    // ws layout (high-water 34,311,424 B, same as proven round-6 layout).
    // NOTE: no backslash at end of comments (line-continuation eats next line!)
    float* h     = (float*)(ws + 0);          // 16,384,000 B (f32)
    char*  ureg  = ws + 16384000;             // 16,384,000 B multi-use region
    int*   nbr   = (int*)  (ws + 32768000);   // 512,000 B
    int*   adj   = (int*)  (ws + 33280000);   // 512,000 B
    int*   indeg = (int*)  (ws + 33792000);   // 64,000 B (memset region start)
    int*   cursor= (int*)  (ws + 33856000);   // 64,000 B (memset)
    float* gsum  = (float*)(ws + 33920000);   // 1,024 B  (memset region end)
    int*   offs  = (int*)  (ws + 33921024);   // 64,004 B
    float* norm  = (float*)(ws + 33985152);   // 64,000 B
    float4* cand = (float4*)(ws + 34049280);  // 262,144 B

    // ureg during kNN: minv, tau, cnt.  During GNN: u16, WThi, WTlo.
    unsigned short* u16 = (unsigned short*)ureg;              // 8,192,000 B
    float*  minv = (float*)ureg;                              // 8,192,000 B
    float*  tau  = (float*)(ureg + 8192000);                  // 64,000 B
    int*    cnt  = (int*)  (ureg + 8256000);                  // 256,000 B
    unsigned short* WThi = (unsigned short*)(ureg + 8512000); // 393,216 B
    unsigned short* WTlo = (unsigned short*)(ureg + 8905216); // 393,216 B
    float2* cl   = (float2*)h;                                // 16,384,000 B (kNN phase)

    (void)hipMemsetAsync(ws + 33792000, 0, 129024, stream);   // indeg+cursor+gsum

    prep_kernel<<<NPAD / 256, 256, 0, stream>>>(coords, cand);
    knn_min_kernel<<<dim3(N_NODES / 64, PARTS), 256, 0, stream>>>(coords, cand, minv);
    tau_kernel<<<(N_NODES + 255) / 256, 256, 0, stream>>>(minv, tau);
    knn_collect_kernel<<<dim3(N_NODES / 64, PARTS), 256, 0, stream>>>(coords, cand, tau, cnt, cl);
    knn_select_kernel<<<(N_NODES + 255) / 256, 256, 0, stream>>>(coords, cand, cl, cnt, nbr);

    count_kernel<<<(NEDGE + 255) / 256, 256, 0, stream>>>(nbr, indeg);
    scan_kernel<<<1, 256, 0, stream>>>(indeg, offs, norm);
    fill_kernel<<<(NEDGE + 255) / 256, 256, 0, stream>>>(nbr, offs, cursor, adj);

    wsplit_kernel<<<LAYERS * 256, 256, 0, stream>>>(gnn_W, WThi, WTlo);

    dim3 g1(N_NODES / 64, HID / 64);
    gemm_kernel<<<g1, 256, 0, stream>>>(x, We, h, F_IN, nullptr, be);
    for (int l = 0; l < LAYERS; ++l) {
        mfma_gemm_kernel<<<dim3(N_NODES / 64, 2), 256, 0, stream>>>(
            h, WThi + (size_t)l * 65536, WTlo + (size_t)l * 65536, u16, norm);
        agg_kernel<<<N_NODES / 4, 256, 0, stream>>>(u16, norm, gnn_b + (size_t)l * HID,
                                                    offs, adj, h);
    }
    pool_kernel<<<64, 256, 0, stream>>>(h, gsum);
    head_kernel<<<1, 128, 0, stream>>>(gsum, Wp1, bp1, Wp2, bp2, out);
}

// Round 9
// 294.931 us; speedup vs baseline: 2.6231x; 1.0412x over previous
//
#include <hip/hip_runtime.h>
#include <math.h>

#define N_NODES 16000
#define F_IN    16
#define HID     256
#define OUTD    128
#define KNN     8
#define LAYERS  3
#define NEDGE   (N_NODES * KNN)

#define NPAD    16384
#define PARTS   4
#define PART_SZ (NPAD / PARTS)   // 4096
#define SEGS    32               // segs per part (8 queries/thread)
#define NMIN    (PARTS * SEGS)   // 128 per-seg minima per query
#define CAPP    32               // collected-candidate cap per (query, part)

typedef __attribute__((ext_vector_type(8))) short  s8v;   // 8 bf16
typedef __attribute__((ext_vector_type(4))) float  f4v;

__device__ __forceinline__ unsigned short f2bf(float x) {
    unsigned u = __float_as_uint(x);
    unsigned r = u + 0x7fffu + ((u >> 16) & 1u);   // RNE
    return (unsigned short)(r >> 16);
}
__device__ __forceinline__ float bf2f(unsigned short b) {
    return __uint_as_float(((unsigned)b) << 16);
}

// ---------------------------------------------------------------------------
// cand[i] = (-2x, -2y, -2z, |c|^2); INF-padded. Shifted distance
// d' = fma(qx,-2x, fma(qy,-2y, fma(qz,-2z, |c|^2))) is per-query monotone.
// cand is 256 KB -> L2-resident; scans read it directly (no LDS staging).
// ---------------------------------------------------------------------------
__global__ __launch_bounds__(256) void prep_kernel(const float* __restrict__ coords,
                                                   float4* __restrict__ cand) {
    int i = blockIdx.x * 256 + threadIdx.x;
    if (i >= NPAD) return;
    if (i < N_NODES) {
        float x = coords[3 * i], y = coords[3 * i + 1], z = coords[3 * i + 2];
        cand[i] = make_float4(-2.f * x, -2.f * y, -2.f * z, x * x + y * y + z * z);
    } else {
        cand[i] = make_float4(0.f, 0.f, 0.f, INFINITY);
    }
}

#define DIST(qx, qy, qz, c) fmaf(qx, c.x, fmaf(qy, c.y, fmaf(qz, c.z, c.w)))

// ---------------------------------------------------------------------------
// Phase 1: per (query, part, seg) minimum. 8 queries/thread, branchless,
// direct L2 reads (wave: 4 x 512B contiguous + broadcast across half-waves).
// ---------------------------------------------------------------------------
__global__ __launch_bounds__(256) void knn_min_kernel(const float* __restrict__ coords,
                                                      const float4* __restrict__ cand,
                                                      float* __restrict__ minv) {
    int tid  = threadIdx.x;
    int seg  = tid & 31;
    int qg   = tid >> 5;
    int qbase = blockIdx.x * 64;
    int part = blockIdx.y;

    float qx[8], qy[8], qz[8], m[8];
#pragma unroll
    for (int i = 0; i < 8; ++i) {
        int q = qbase + i * 8 + qg;
        qx[i] = coords[q * 3]; qy[i] = coords[q * 3 + 1]; qz[i] = coords[q * 3 + 2];
        m[i] = INFINITY;
    }

    int pbase = part * PART_SZ;
#pragma unroll 2
    for (int c0 = 0; c0 < PART_SZ; c0 += 128) {
        float4 v0 = cand[pbase + c0 + seg];
        float4 v1 = cand[pbase + c0 + seg + 32];
        float4 v2 = cand[pbase + c0 + seg + 64];
        float4 v3 = cand[pbase + c0 + seg + 96];
#pragma unroll
        for (int i = 0; i < 8; ++i) {
            float d0 = DIST(qx[i], qy[i], qz[i], v0);
            float d1 = DIST(qx[i], qy[i], qz[i], v1);
            float d2 = DIST(qx[i], qy[i], qz[i], v2);
            float d3 = DIST(qx[i], qy[i], qz[i], v3);
            m[i] = fminf(m[i], fminf(fminf(d0, d1), fminf(d2, d3)));
        }
    }
#pragma unroll
    for (int i = 0; i < 8; ++i) {
        int q = qbase + i * 8 + qg;
        minv[(q * PARTS + part) * SEGS + seg] = m[i];
    }
}

// ---------------------------------------------------------------------------
// Phase 2: tau[q] = 9th smallest of 16 merged-list minima (each list = 8
// consecutive segs of one part -> 16 distinct candidates -> valid bound).
// ---------------------------------------------------------------------------
__global__ __launch_bounds__(256) void tau_kernel(const float* __restrict__ minv,
                                                  float* __restrict__ tau) {
    int q = blockIdx.x * 256 + threadIdx.x;
    if (q >= N_NODES) return;
    float b[9];
#pragma unroll
    for (int p = 0; p < 9; ++p) b[p] = INFINITY;
    const float4* mv = (const float4*)(minv + (size_t)q * NMIN);
#pragma unroll
    for (int c = 0; c < 16; ++c) {
        float4 a0 = mv[c * 2], a1 = mv[c * 2 + 1];
        float v = fminf(fminf(fminf(a0.x, a0.y), fminf(a0.z, a0.w)),
                        fminf(fminf(a1.x, a1.y), fminf(a1.z, a1.w)));
#pragma unroll
        for (int p = 8; p >= 1; --p) {
            bool  up = v < b[p - 1];
            float nd = up ? b[p - 1] : (v < b[p] ? v : b[p]);
            b[p] = nd;
        }
        if (v < b[0]) b[0] = v;
    }
    tau[q] = b[8];
}

// ---------------------------------------------------------------------------
// Phase 3: collect candidates with d <= tau[q]. min4-gate; direct L2 reads;
// block-local LDS counters. Identical fma as phase 1 -> bit-identical d.
// ---------------------------------------------------------------------------
__global__ __launch_bounds__(256) void knn_collect_kernel(const float* __restrict__ coords,
                                                          const float4* __restrict__ cand,
                                                          const float* __restrict__ tau,
                                                          int* __restrict__ cnt,
                                                          float2* __restrict__ cl) {
    __shared__ int scnt[64];
    int tid  = threadIdx.x;
    int seg  = tid & 31;
    int qg   = tid >> 5;
    int qbase = blockIdx.x * 64;
    int part  = blockIdx.y;

    float qx[8], qy[8], qz[8], tt[8];
#pragma unroll
    for (int i = 0; i < 8; ++i) {
        int q = qbase + i * 8 + qg;
        qx[i] = coords[q * 3]; qy[i] = coords[q * 3 + 1]; qz[i] = coords[q * 3 + 2];
        tt[i] = tau[q];
    }
    if (tid < 64) scnt[tid] = 0;
    __syncthreads();

    int pbase = part * PART_SZ;
    for (int c0 = 0; c0 < PART_SZ; c0 += 128) {
        float4 v0 = cand[pbase + c0 + seg];
        float4 v1 = cand[pbase + c0 + seg + 32];
        float4 v2 = cand[pbase + c0 + seg + 64];
        float4 v3 = cand[pbase + c0 + seg + 96];
        int jb = pbase + c0 + seg;
#pragma unroll
        for (int i = 0; i < 8; ++i) {
            float d0 = DIST(qx[i], qy[i], qz[i], v0);
            float d1 = DIST(qx[i], qy[i], qz[i], v1);
            float d2 = DIST(qx[i], qy[i], qz[i], v2);
            float d3 = DIST(qx[i], qy[i], qz[i], v3);
            float m4 = fminf(fminf(d0, d1), fminf(d2, d3));
            if (m4 <= tt[i]) {
                int qi = qbase + i * 8 + qg;
                int cb = (int)(((size_t)qi * PARTS + part) * CAPP);
                if (d0 <= tt[i]) {
                    int pos = atomicAdd(&scnt[i * 8 + qg], 1);
                    if (pos < CAPP) cl[cb + pos] = make_float2(d0, __int_as_float(jb));
                }
                if (d1 <= tt[i]) {
                    int pos = atomicAdd(&scnt[i * 8 + qg], 1);
                    if (pos < CAPP) cl[cb + pos] = make_float2(d1, __int_as_float(jb + 32));
                }
                if (d2 <= tt[i]) {
                    int pos = atomicAdd(&scnt[i * 8 + qg], 1);
                    if (pos < CAPP) cl[cb + pos] = make_float2(d2, __int_as_float(jb + 64));
                }
                if (d3 <= tt[i]) {
                    int pos = atomicAdd(&scnt[i * 8 + qg], 1);
                    if (pos < CAPP) cl[cb + pos] = make_float2(d3, __int_as_float(jb + 96));
                }
            }
        }
    }
    __syncthreads();
    if (tid < 64) cnt[(size_t)(qbase + tid) * PARTS + part] = scnt[tid];
}

// ---------------------------------------------------------------------------
// Phase 4: exact lexicographic (d, idx) top-9 over the 4 part segments.
// Fused: also counts indegree (was a separate kernel).
// ---------------------------------------------------------------------------
#define INS9L(bd, bi, d, j)                                                   \
    {                                                                         \
        _Pragma("unroll")                                                     \
        for (int p = 8; p >= 1; --p) {                                        \
            bool up = (d) < bd[p-1] || ((d) == bd[p-1] && (j) < bi[p-1]);     \
            bool in = (d) < bd[p]   || ((d) == bd[p]   && (j) < bi[p]);       \
            float nd = up ? bd[p-1] : (in ? (d) : bd[p]);                     \
            int   ni = up ? bi[p-1] : (in ? (j) : bi[p]);                     \
            bd[p] = nd; bi[p] = ni;                                           \
        }                                                                     \
        if ((d) < bd[0] || ((d) == bd[0] && (j) < bi[0])) {                   \
            bd[0] = (d); bi[0] = (j);                                         \
        }                                                                     \
    }

__global__ __launch_bounds__(256) void knn_select_kernel(const float* __restrict__ coords,
                                                         const float4* __restrict__ cand,
                                                         const float2* __restrict__ cl,
                                                         const int* __restrict__ cnt,
                                                         int* __restrict__ nbr,
                                                         int* __restrict__ indeg) {
    int q = blockIdx.x * 256 + threadIdx.x;
    if (q >= N_NODES) return;
    float bd[9]; int bi[9];
#pragma unroll
    for (int p = 0; p < 9; ++p) { bd[p] = INFINITY; bi[p] = 0x7fffffff; }
    int n0 = cnt[(size_t)q * PARTS + 0];
    int n1 = cnt[(size_t)q * PARTS + 1];
    int n2 = cnt[(size_t)q * PARTS + 2];
    int n3 = cnt[(size_t)q * PARTS + 3];
    if (n0 <= CAPP && n1 <= CAPP && n2 <= CAPP && n3 <= CAPP) {
#pragma unroll
        for (int p = 0; p < PARTS; ++p) {
            int n = (p == 0) ? n0 : (p == 1) ? n1 : (p == 2) ? n2 : n3;
            const float2* segp = cl + ((size_t)q * PARTS + p) * CAPP;
            for (int i = 0; i < n; ++i) {
                float2 e = segp[i];
                float d = e.x; int j = __float_as_int(e.y);
                INS9L(bd, bi, d, j);
            }
        }
    } else {
        float qx = coords[q*3], qy = coords[q*3+1], qz = coords[q*3+2];
        for (int j = 0; j < NPAD; ++j) {
            float4 c = cand[j];
            float d = DIST(qx, qy, qz, c);
            if (d < bd[8] || (d == bd[8] && j < bi[8])) INS9L(bd, bi, d, j);
        }
    }
#pragma unroll
    for (int p = 1; p < 9; ++p) {
        nbr[q * 8 + p - 1] = bi[p];
        atomicAdd(&indeg[bi[p]], 1);
    }
}

// ---------------------------------------------------------------------------
// CSR: exclusive scan (+norm) over indegree, then fill.
// ---------------------------------------------------------------------------
__global__ __launch_bounds__(1024) void scan_kernel(const int* __restrict__ indeg,
                                                    int* __restrict__ offs,
                                                    float* __restrict__ norm) {
    __shared__ int ssum[1024];
    int t = threadIdx.x;
    const int CH = 16;                       // 1024*16 = 16384 >= 16000
    int base = t * CH;
    int s = 0;
    for (int c = 0; c < CH; ++c) {
        int idx = base + c;
        if (idx < N_NODES) s += indeg[idx];
    }
    ssum[t] = s;
    __syncthreads();
    for (int d = 1; d < 1024; d <<= 1) {
        int v = (t >= d) ? ssum[t - d] : 0;
        __syncthreads();
        ssum[t] += v;
        __syncthreads();
    }
    int run = ssum[t] - s;
    for (int c = 0; c < CH; ++c) {
        int idx = base + c;
        if (idx < N_NODES) {
            int dg = indeg[idx];
            offs[idx] = run;
            run += dg;
            norm[idx] = rsqrtf((float)(1 + dg));
        }
    }
    if (t == 1023) offs[N_NODES] = ssum[1023];
}

__global__ void fill_kernel(const int* __restrict__ nbr, const int* __restrict__ offs,
                            int* __restrict__ cursor, int* __restrict__ adj) {
    int e = blockIdx.x * blockDim.x + threadIdx.x;
    if (e < NEDGE) {
        int d   = nbr[e];
        int src = e >> 3;
        int pos = atomicAdd(&cursor[d], 1);
        adj[offs[d] + pos] = src;
    }
}

// ---------------------------------------------------------------------------
// Encoder GEMM (f32, K=16): h[M x 256] = x[M x 16] @ We + be.
// ---------------------------------------------------------------------------
__global__ __launch_bounds__(256) void gemm_kernel(const float* __restrict__ A,
                                                   const float* __restrict__ B,
                                                   float* __restrict__ C,
                                                   int K,
                                                   const float* __restrict__ rowscale,
                                                   const float* __restrict__ bias) {
    __shared__ float As[16][68];
    __shared__ float Bs[16][64];
    int tid = threadIdx.x;
    int rowBase = blockIdx.x * 64;
    int colBase = blockIdx.y * 64;
    int rg = tid >> 4;
    int cg = tid & 15;

    int ar = tid >> 2;
    int ac = (tid & 3) * 4;
    int bk = tid >> 4;
    int bn = (tid & 15) * 4;

    float4 acc0 = {0,0,0,0}, acc1 = {0,0,0,0}, acc2 = {0,0,0,0}, acc3 = {0,0,0,0};

    for (int kb = 0; kb < K; kb += 16) {
        float4 av = *(const float4*)(A + (size_t)(rowBase + ar) * K + kb + ac);
        float4 bv = *(const float4*)(B + (size_t)(kb + bk) * HID + colBase + bn);
        __syncthreads();
        As[ac + 0][ar] = av.x; As[ac + 1][ar] = av.y;
        As[ac + 2][ar] = av.z; As[ac + 3][ar] = av.w;
        *(float4*)&Bs[bk][bn] = bv;
        __syncthreads();
#pragma unroll
        for (int k = 0; k < 16; ++k) {
            float4 a = *(const float4*)&As[k][rg * 4];
            float4 b = *(const float4*)&Bs[k][cg * 4];
            acc0.x = fmaf(a.x, b.x, acc0.x); acc0.y = fmaf(a.x, b.y, acc0.y);
            acc0.z = fmaf(a.x, b.z, acc0.z); acc0.w = fmaf(a.x, b.w, acc0.w);
            acc1.x = fmaf(a.y, b.x, acc1.x); acc1.y = fmaf(a.y, b.y, acc1.y);
            acc1.z = fmaf(a.y, b.z, acc1.z); acc1.w = fmaf(a.y, b.w, acc1.w);
            acc2.x = fmaf(a.z, b.x, acc2.x); acc2.y = fmaf(a.z, b.y, acc2.y);
            acc2.z = fmaf(a.z, b.z, acc2.z); acc2.w = fmaf(a.z, b.w, acc2.w);
            acc3.x = fmaf(a.w, b.x, acc3.x); acc3.y = fmaf(a.w, b.y, acc3.y);
            acc3.z = fmaf(a.w, b.z, acc3.z); acc3.w = fmaf(a.w, b.w, acc3.w);
        }
        __syncthreads();
    }

    int row = rowBase + rg * 4;
    int col = colBase + cg * 4;
    float s0 = 1.f, s1 = 1.f, s2 = 1.f, s3 = 1.f;
    if (rowscale) { s0 = rowscale[row]; s1 = rowscale[row + 1];
                    s2 = rowscale[row + 2]; s3 = rowscale[row + 3]; }
    float4 bb = {0,0,0,0};
    if (bias) bb = *(const float4*)(bias + col);

    float4 v;
    v.x = acc0.x * s0 + bb.x; v.y = acc0.y * s0 + bb.y;
    v.z = acc0.z * s0 + bb.z; v.w = acc0.w * s0 + bb.w;
    *(float4*)(C + (size_t)(row + 0) * HID + col) = v;
    v.x = acc1.x * s1 + bb.x; v.y = acc1.y * s1 + bb.y;
    v.z = acc1.z * s1 + bb.z; v.w = acc1.w * s1 + bb.w;
    *(float4*)(C + (size_t)(row + 1) * HID + col) = v;
    v.x = acc2.x * s2 + bb.x; v.y = acc2.y * s2 + bb.y;
    v.z = acc2.z * s2 + bb.z; v.w = acc2.w * s2 + bb.w;
    *(float4*)(C + (size_t)(row + 2) * HID + col) = v;
    v.x = acc3.x * s3 + bb.x; v.y = acc3.y * s3 + bb.y;
    v.z = acc3.z * s3 + bb.z; v.w = acc3.w * s3 + bb.w;
    *(float4*)(C + (size_t)(row + 3) * HID + col) = v;
}

// ---------------------------------------------------------------------------
// W transpose + split for ALL layers: WThi[l][j][k] = bf16(W[l][k][j]),
// WTlo = bf16(residual). One dispatch.
// ---------------------------------------------------------------------------
__global__ __launch_bounds__(256) void wsplit_kernel(const float* __restrict__ W,
                                                     unsigned short* __restrict__ WThi,
                                                     unsigned short* __restrict__ WTlo) {
    int idx = blockIdx.x * 256 + threadIdx.x;
    int l = idx >> 16;
    int r = idx & 65535;
    int k = r >> 8, j = r & 255;
    float x = W[idx];
    unsigned short hb = f2bf(x);
    float hf = bf2f(hb);
    size_t o = (size_t)l * 65536 + j * 256 + k;
    WThi[o] = hb;
    WTlo[o] = f2bf(x - hf);
}

// ---------------------------------------------------------------------------
// Split-bf16 MFMA GEMM: u16[M x 256] = bf16((h[M x 256] @ W) * norm[row]).
// acc = hh + hl + lh in f32 (a_lo*b_lo ~ 2^-18, dropped).
// ---------------------------------------------------------------------------
__global__ __launch_bounds__(256) void mfma_gemm_kernel(const float* __restrict__ A,
                                                        const unsigned short* __restrict__ WThi,
                                                        const unsigned short* __restrict__ WTlo,
                                                        unsigned short* __restrict__ C,
                                                        const float* __restrict__ rowscale) {
    __shared__ unsigned short Ahi[64][40], Alo[64][40];
    __shared__ unsigned short Bhi[128][40], Blo[128][40];
    int tid = threadIdx.x;
    int rowBase = blockIdx.x * 64;
    int colBase = blockIdx.y * 128;
    int wave = tid >> 6;
    int lane = tid & 63;
    int fr = lane & 15;
    int fg = lane >> 4;

    int asr = tid >> 2;
    int ask = (tid & 3) * 8;
    int bsj = tid >> 1;
    int bsk = (tid & 1) * 16;

    f4v acc[8];
#pragma unroll
    for (int c = 0; c < 8; ++c) acc[c] = (f4v){0.f, 0.f, 0.f, 0.f};

    for (int kb = 0; kb < HID; kb += 32) {
        const float4* ap = (const float4*)(A + (size_t)(rowBase + asr) * HID + kb + ask);
        float4 a0 = ap[0], a1 = ap[1];
        const uint4* bhp = (const uint4*)(WThi + (size_t)(colBase + bsj) * HID + kb + bsk);
        const uint4* blp = (const uint4*)(WTlo + (size_t)(colBase + bsj) * HID + kb + bsk);
        uint4 bh0 = bhp[0], bh1 = bhp[1];
        uint4 bl0 = blp[0], bl1 = blp[1];

        __syncthreads();
        {
            float xv[8] = {a0.x, a0.y, a0.z, a0.w, a1.x, a1.y, a1.z, a1.w};
            s8v hv, lv;
#pragma unroll
            for (int e = 0; e < 8; ++e) {
                unsigned short hb = f2bf(xv[e]);
                float hf = bf2f(hb);
                hv[e] = (short)hb;
                lv[e] = (short)f2bf(xv[e] - hf);
            }
            *(s8v*)&Ahi[asr][ask] = hv;
            *(s8v*)&Alo[asr][ask] = lv;
        }
        *(uint4*)&Bhi[bsj][bsk]      = bh0;
        *(uint4*)&Bhi[bsj][bsk + 8]  = bh1;
        *(uint4*)&Blo[bsj][bsk]      = bl0;
        *(uint4*)&Blo[bsj][bsk + 8]  = bl1;
        __syncthreads();

        s8v afh = *(s8v*)&Ahi[wave * 16 + fr][fg * 8];
        s8v afl = *(s8v*)&Alo[wave * 16 + fr][fg * 8];
#pragma unroll
        for (int c = 0; c < 8; ++c) {
            s8v bfh = *(s8v*)&Bhi[c * 16 + fr][fg * 8];
            s8v bfl = *(s8v*)&Blo[c * 16 + fr][fg * 8];
            acc[c] = __builtin_amdgcn_mfma_f32_16x16x32_bf16(afh, bfh, acc[c], 0, 0, 0);
            acc[c] = __builtin_amdgcn_mfma_f32_16x16x32_bf16(afh, bfl, acc[c], 0, 0, 0);
            acc[c] = __builtin_amdgcn_mfma_f32_16x16x32_bf16(afl, bfh, acc[c], 0, 0, 0);
        }
    }

    float sc[4];
#pragma unroll
    for (int r = 0; r < 4; ++r) sc[r] = rowscale[rowBase + wave * 16 + fg * 4 + r];
#pragma unroll
    for (int c = 0; c < 8; ++c) {
        int col = colBase + c * 16 + fr;
#pragma unroll
        for (int r = 0; r < 4; ++r) {
            int row = rowBase + wave * 16 + fg * 4 + r;
            C[(size_t)row * HID + col] = f2bf(acc[c][r] * sc[r]);
        }
    }
}

// ---------------------------------------------------------------------------
// Aggregation: h[j] = relu(norm[j]*(u[j] + sum_{i->j} u[i]) + b); u is bf16.
// ---------------------------------------------------------------------------
__global__ __launch_bounds__(256) void agg_kernel(const unsigned short* __restrict__ u,
                                                  const float* __restrict__ norm,
                                                  const float* __restrict__ bias,
                                                  const int* __restrict__ offs,
                                                  const int* __restrict__ adj,
                                                  float* __restrict__ hout) {
    int node = blockIdx.x * 4 + (threadIdx.x >> 6);
    int lane = threadIdx.x & 63;
    const ushort4* up = (const ushort4*)u;
    ushort4 sv = up[(size_t)node * 64 + lane];
    float ax = bf2f(sv.x), ay = bf2f(sv.y), az = bf2f(sv.z), aw = bf2f(sv.w);
    int e0 = offs[node], e1 = offs[node + 1];
    for (int e = e0; e < e1; ++e) {
        int s = adj[e];
        ushort4 v = up[(size_t)s * 64 + lane];
        ax += bf2f(v.x); ay += bf2f(v.y); az += bf2f(v.z); aw += bf2f(v.w);
    }
    float nm = norm[node];
    float4 bb = ((const float4*)bias)[lane];
    float4 r;
    r.x = fmaxf(fmaf(nm, ax, bb.x), 0.0f);
    r.y = fmaxf(fmaf(nm, ay, bb.y), 0.0f);
    r.z = fmaxf(fmaf(nm, az, bb.z), 0.0f);
    r.w = fmaxf(fmaf(nm, aw, bb.w), 0.0f);
    ((float4*)hout)[(size_t)node * 64 + lane] = r;
}

// ---------------------------------------------------------------------------
// Mean pool and 2-layer MLP head (f32)
// ---------------------------------------------------------------------------
__global__ __launch_bounds__(256) void pool_kernel(const float* __restrict__ h,
                                                   float* __restrict__ gsum) {
    int t = threadIdx.x;
    float acc = 0.f;
    int start = blockIdx.x * 250;
    for (int i = 0; i < 250; ++i) acc += h[(size_t)(start + i) * HID + t];
    atomicAdd(&gsum[t], acc);
}

__global__ __launch_bounds__(128) void head_kernel(const float* __restrict__ gsum,
                                                   const float* __restrict__ Wp1,
                                                   const float* __restrict__ bp1,
                                                   const float* __restrict__ Wp2,
                                                   const float* __restrict__ bp2,
                                                   float* __restrict__ out) {
    __shared__ float gl[256];
    __shared__ float hid[128];
    int t = threadIdx.x;
    const float inv = 1.0f / 16000.0f;
    gl[t]       = gsum[t]       * inv;
    gl[t + 128] = gsum[t + 128] * inv;
    __syncthreads();
    float a = bp1[t];
    for (int k = 0; k < 256; ++k) a = fmaf(gl[k], Wp1[k * 128 + t], a);
    hid[t] = fmaxf(a, 0.0f);
    __syncthreads();
    float o = bp2[t];
    for (int k = 0; k < 128; ++k) o = fmaf(hid[k], Wp2[k * 128 + t], o);
    out[t] = o;
}

// ---------------------------------------------------------------------------
extern "C" void kernel_launch(void* const* d_in, const int* in_sizes, int n_in,
                              void* d_out, int out_size, void* d_ws, size_t ws_size,
                              hipStream_t stream) {
    const float* x      = (const float*)d_in[0];
    const float* coords = (const float*)d_in[1];
    const float* We     = (const float*)d_in[2];
    const float* be     = (const float*)d_in[3];
    const float* gnn_W  = (const float*)d_in[4];
    const float* gnn_b  = (const float*)d_in[5];
    const float* Wp1    = (const float*)d_in[6];
    const float* bp1    = (const float*)d_in[7];
    const float* Wp2    = (const float*)d_in[8];
    const float* bp2    = (const float*)d_in[9];
    float* out = (float*)d_out;

    char* ws = (char*)d_ws;
    // ws layout, high-water 34,311,424 B (same as proven round-6/8 layout).
    // NOTE: never end a comment with a backslash (line continuation!).
    float* h     = (float*)(ws + 0);          // 16,384,000 B (f32)
    char*  ureg  = ws + 16384000;             // 16,384,000 B multi-use region
    int*   nbr   = (int*)  (ws + 32768000);   // 512,000 B
    int*   adj   = (int*)  (ws + 33280000);   // 512,000 B
    int*   indeg = (int*)  (ws + 33792000);   // 64,000 B (memset region start)
    int*   cursor= (int*)  (ws + 33856000);   // 64,000 B (memset)
    float* gsum  = (float*)(ws + 33920000);   // 1,024 B  (memset region end)
    int*   offs  = (int*)  (ws + 33921024);   // 64,004 B
    float* norm  = (float*)(ws + 33985152);   // 64,000 B
    float4* cand = (float4*)(ws + 34049280);  // 262,144 B

    // ureg during kNN: minv, tau, cnt.  During GNN: u16, WThi, WTlo.
    unsigned short* u16 = (unsigned short*)ureg;              // 8,192,000 B
    float*  minv = (float*)ureg;                              // 8,192,000 B
    float*  tau  = (float*)(ureg + 8192000);                  // 64,000 B
    int*    cnt  = (int*)  (ureg + 8256000);                  // 256,000 B
    unsigned short* WThi = (unsigned short*)(ureg + 8512000); // 393,216 B
    unsigned short* WTlo = (unsigned short*)(ureg + 8905216); // 393,216 B
    float2* cl   = (float2*)h;                                // 16,384,000 B (kNN phase)

    (void)hipMemsetAsync(ws + 33792000, 0, 129024, stream);   // indeg+cursor+gsum

    prep_kernel<<<NPAD / 256, 256, 0, stream>>>(coords, cand);
    knn_min_kernel<<<dim3(N_NODES / 64, PARTS), 256, 0, stream>>>(coords, cand, minv);
    tau_kernel<<<(N_NODES + 255) / 256, 256, 0, stream>>>(minv, tau);
    knn_collect_kernel<<<dim3(N_NODES / 64, PARTS), 256, 0, stream>>>(coords, cand, tau, cnt, cl);
    knn_select_kernel<<<(N_NODES + 255) / 256, 256, 0, stream>>>(coords, cand, cl, cnt, nbr, indeg);

    scan_kernel<<<1, 1024, 0, stream>>>(indeg, offs, norm);
    fill_kernel<<<(NEDGE + 255) / 256, 256, 0, stream>>>(nbr, offs, cursor, adj);

    wsplit_kernel<<<LAYERS * 256, 256, 0, stream>>>(gnn_W, WThi, WTlo);

    dim3 g1(N_NODES / 64, HID / 64);
    gemm_kernel<<<g1, 256, 0, stream>>>(x, We, h, F_IN, nullptr, be);
    for (int l = 0; l < LAYERS; ++l) {
        mfma_gemm_kernel<<<dim3(N_NODES / 64, 2), 256, 0, stream>>>(
            h, WThi + (size_t)l * 65536, WTlo + (size_t)l * 65536, u16, norm);
        agg_kernel<<<N_NODES / 4, 256, 0, stream>>>(u16, norm, gnn_b + (size_t)l * HID,
                                                    offs, adj, h);
    }
    pool_kernel<<<64, 256, 0, stream>>>(h, gsum);
    head_kernel<<<1, 128, 0, stream>>>(gsum, Wp1, bp1, Wp2, bp2, out);
}

// Round 10
// 287.425 us; speedup vs baseline: 2.6916x; 1.0261x over previous
//
#include <hip/hip_runtime.h>
#include <math.h>

#define N_NODES 16000
#define F_IN    16
#define HID     256
#define OUTD    128
#define KNN     8
#define LAYERS  3
#define NEDGE   (N_NODES * KNN)

#define NPAD    16384
#define PARTS   4
#define PART_SZ (NPAD / PARTS)   // 4096
#define SEGS    32               // segs per part (8 queries/thread)
#define NMIN    (PARTS * SEGS)   // 128 per-seg minima per query
#define CAPP    32               // collected-candidate cap per (query, part)
#define NZERO   32256            // ints to zero: indeg 16000 + cursor 16000 + gsum 256

typedef __attribute__((ext_vector_type(8))) short  s8v;   // 8 bf16
typedef __attribute__((ext_vector_type(4))) float  f4v;

__device__ __forceinline__ unsigned short f2bf(float x) {
    unsigned u = __float_as_uint(x);
    unsigned r = u + 0x7fffu + ((u >> 16) & 1u);   // RNE
    return (unsigned short)(r >> 16);
}
__device__ __forceinline__ float bf2f(unsigned short b) {
    return __uint_as_float(((unsigned)b) << 16);
}

// ---------------------------------------------------------------------------
// cand[i] = (-2x, -2y, -2z, |c|^2); INF-padded. Shifted distance
// d' = fma(qx,-2x, fma(qy,-2y, fma(qz,-2z, |c|^2))) is per-query monotone.
// Also zeroes the contiguous indeg|cursor|gsum region (replaces memset node).
// ---------------------------------------------------------------------------
__global__ __launch_bounds__(256) void prep_kernel(const float* __restrict__ coords,
                                                   float4* __restrict__ cand,
                                                   int* __restrict__ zero) {
    int i = blockIdx.x * 256 + threadIdx.x;
    int z = i * 2;
    if (z < NZERO) { zero[z] = 0; zero[z + 1] = 0; }
    if (i >= NPAD) return;
    if (i < N_NODES) {
        float x = coords[3 * i], y = coords[3 * i + 1], z2 = coords[3 * i + 2];
        cand[i] = make_float4(-2.f * x, -2.f * y, -2.f * z2, x * x + y * y + z2 * z2);
    } else {
        cand[i] = make_float4(0.f, 0.f, 0.f, INFINITY);
    }
}

#define DIST(qx, qy, qz, c) fmaf(qx, c.x, fmaf(qy, c.y, fmaf(qz, c.z, c.w)))

// ---------------------------------------------------------------------------
// Phase 1: per (query, part, seg) minimum. 8 queries/thread, branchless,
// direct L2 reads (cand is 256 KB, L2-resident).
// ---------------------------------------------------------------------------
__global__ __launch_bounds__(256) void knn_min_kernel(const float* __restrict__ coords,
                                                      const float4* __restrict__ cand,
                                                      float* __restrict__ minv) {
    int tid  = threadIdx.x;
    int seg  = tid & 31;
    int qg   = tid >> 5;
    int qbase = blockIdx.x * 64;
    int part = blockIdx.y;

    float qx[8], qy[8], qz[8], m[8];
#pragma unroll
    for (int i = 0; i < 8; ++i) {
        int q = qbase + i * 8 + qg;
        qx[i] = coords[q * 3]; qy[i] = coords[q * 3 + 1]; qz[i] = coords[q * 3 + 2];
        m[i] = INFINITY;
    }

    int pbase = part * PART_SZ;
#pragma unroll 2
    for (int c0 = 0; c0 < PART_SZ; c0 += 128) {
        float4 v0 = cand[pbase + c0 + seg];
        float4 v1 = cand[pbase + c0 + seg + 32];
        float4 v2 = cand[pbase + c0 + seg + 64];
        float4 v3 = cand[pbase + c0 + seg + 96];
#pragma unroll
        for (int i = 0; i < 8; ++i) {
            float d0 = DIST(qx[i], qy[i], qz[i], v0);
            float d1 = DIST(qx[i], qy[i], qz[i], v1);
            float d2 = DIST(qx[i], qy[i], qz[i], v2);
            float d3 = DIST(qx[i], qy[i], qz[i], v3);
            m[i] = fminf(m[i], fminf(fminf(d0, d1), fminf(d2, d3)));
        }
    }
#pragma unroll
    for (int i = 0; i < 8; ++i) {
        int q = qbase + i * 8 + qg;
        minv[(q * PARTS + part) * SEGS + seg] = m[i];
    }
}

// ---------------------------------------------------------------------------
// Phase 2+3 fused: in-block tau (9th smallest of 16 merged-list minima; each
// list = 8 consecutive segs -> 16 distinct candidates -> valid bound), then
// collect candidates with d <= tau. min4-gate; direct L2 reads; block-local
// LDS counters. Identical fma as phase 1 -> bit-identical d -> bound exact.
// ---------------------------------------------------------------------------
__global__ __launch_bounds__(256) void knn_collect_kernel(const float* __restrict__ coords,
                                                          const float4* __restrict__ cand,
                                                          const float* __restrict__ minv,
                                                          int* __restrict__ cnt,
                                                          float2* __restrict__ cl) {
    __shared__ int scnt[64];
    __shared__ float stau[64];
    int tid  = threadIdx.x;
    int seg  = tid & 31;
    int qg   = tid >> 5;
    int qbase = blockIdx.x * 64;
    int part  = blockIdx.y;

    if (tid < 64) {
        int q = qbase + tid;
        const float4* mv = (const float4*)(minv + (size_t)q * NMIN);
        float b[9];
#pragma unroll
        for (int p = 0; p < 9; ++p) b[p] = INFINITY;
#pragma unroll
        for (int c = 0; c < 16; ++c) {
            float4 a0 = mv[c * 2], a1 = mv[c * 2 + 1];
            float v = fminf(fminf(fminf(a0.x, a0.y), fminf(a0.z, a0.w)),
                            fminf(fminf(a1.x, a1.y), fminf(a1.z, a1.w)));
#pragma unroll
            for (int p = 8; p >= 1; --p) {
                bool  up = v < b[p - 1];
                b[p] = up ? b[p - 1] : (v < b[p] ? v : b[p]);
            }
            if (v < b[0]) b[0] = v;
        }
        stau[tid] = b[8];
        scnt[tid] = 0;
    }

    float qx[8], qy[8], qz[8], tt[8];
#pragma unroll
    for (int i = 0; i < 8; ++i) {
        int q = qbase + i * 8 + qg;
        qx[i] = coords[q * 3]; qy[i] = coords[q * 3 + 1]; qz[i] = coords[q * 3 + 2];
    }
    __syncthreads();
#pragma unroll
    for (int i = 0; i < 8; ++i) tt[i] = stau[i * 8 + qg];

    int pbase = part * PART_SZ;
    for (int c0 = 0; c0 < PART_SZ; c0 += 128) {
        float4 v0 = cand[pbase + c0 + seg];
        float4 v1 = cand[pbase + c0 + seg + 32];
        float4 v2 = cand[pbase + c0 + seg + 64];
        float4 v3 = cand[pbase + c0 + seg + 96];
        int jb = pbase + c0 + seg;
#pragma unroll
        for (int i = 0; i < 8; ++i) {
            float d0 = DIST(qx[i], qy[i], qz[i], v0);
            float d1 = DIST(qx[i], qy[i], qz[i], v1);
            float d2 = DIST(qx[i], qy[i], qz[i], v2);
            float d3 = DIST(qx[i], qy[i], qz[i], v3);
            float m4 = fminf(fminf(d0, d1), fminf(d2, d3));
            if (m4 <= tt[i]) {
                int qi = qbase + i * 8 + qg;
                int cb = (int)(((size_t)qi * PARTS + part) * CAPP);
                if (d0 <= tt[i]) {
                    int pos = atomicAdd(&scnt[i * 8 + qg], 1);
                    if (pos < CAPP) cl[cb + pos] = make_float2(d0, __int_as_float(jb));
                }
                if (d1 <= tt[i]) {
                    int pos = atomicAdd(&scnt[i * 8 + qg], 1);
                    if (pos < CAPP) cl[cb + pos] = make_float2(d1, __int_as_float(jb + 32));
                }
                if (d2 <= tt[i]) {
                    int pos = atomicAdd(&scnt[i * 8 + qg], 1);
                    if (pos < CAPP) cl[cb + pos] = make_float2(d2, __int_as_float(jb + 64));
                }
                if (d3 <= tt[i]) {
                    int pos = atomicAdd(&scnt[i * 8 + qg], 1);
                    if (pos < CAPP) cl[cb + pos] = make_float2(d3, __int_as_float(jb + 96));
                }
            }
        }
    }
    __syncthreads();
    if (tid < 64) cnt[(size_t)(qbase + tid) * PARTS + part] = scnt[tid];
}

// ---------------------------------------------------------------------------
// Phase 4: exact lexicographic (d, idx) top-9 over the 4 part segments.
// Also counts indegree (fused).
// ---------------------------------------------------------------------------
#define INS9L(bd, bi, d, j)                                                   \
    {                                                                         \
        _Pragma("unroll")                                                     \
        for (int p = 8; p >= 1; --p) {                                        \
            bool up = (d) < bd[p-1] || ((d) == bd[p-1] && (j) < bi[p-1]);     \
            bool in = (d) < bd[p]   || ((d) == bd[p]   && (j) < bi[p]);       \
            float nd = up ? bd[p-1] : (in ? (d) : bd[p]);                     \
            int   ni = up ? bi[p-1] : (in ? (j) : bi[p]);                     \
            bd[p] = nd; bi[p] = ni;                                           \
        }                                                                     \
        if ((d) < bd[0] || ((d) == bd[0] && (j) < bi[0])) {                   \
            bd[0] = (d); bi[0] = (j);                                         \
        }                                                                     \
    }

__global__ __launch_bounds__(256) void knn_select_kernel(const float* __restrict__ coords,
                                                         const float4* __restrict__ cand,
                                                         const float2* __restrict__ cl,
                                                         const int* __restrict__ cnt,
                                                         int* __restrict__ nbr,
                                                         int* __restrict__ indeg) {
    int q = blockIdx.x * 256 + threadIdx.x;
    if (q >= N_NODES) return;
    float bd[9]; int bi[9];
#pragma unroll
    for (int p = 0; p < 9; ++p) { bd[p] = INFINITY; bi[p] = 0x7fffffff; }
    int n0 = cnt[(size_t)q * PARTS + 0];
    int n1 = cnt[(size_t)q * PARTS + 1];
    int n2 = cnt[(size_t)q * PARTS + 2];
    int n3 = cnt[(size_t)q * PARTS + 3];
    if (n0 <= CAPP && n1 <= CAPP && n2 <= CAPP && n3 <= CAPP) {
#pragma unroll
        for (int p = 0; p < PARTS; ++p) {
            int n = (p == 0) ? n0 : (p == 1) ? n1 : (p == 2) ? n2 : n3;
            const float2* segp = cl + ((size_t)q * PARTS + p) * CAPP;
            for (int i = 0; i < n; ++i) {
                float2 e = segp[i];
                float d = e.x; int j = __float_as_int(e.y);
                INS9L(bd, bi, d, j);
            }
        }
    } else {
        float qx = coords[q*3], qy = coords[q*3+1], qz = coords[q*3+2];
        for (int j = 0; j < NPAD; ++j) {
            float4 c = cand[j];
            float d = DIST(qx, qy, qz, c);
            if (d < bd[8] || (d == bd[8] && j < bi[8])) INS9L(bd, bi, d, j);
        }
    }
#pragma unroll
    for (int p = 1; p < 9; ++p) {
        nbr[q * 8 + p - 1] = bi[p];
        atomicAdd(&indeg[bi[p]], 1);
    }
}

// ---------------------------------------------------------------------------
// CSR: exclusive scan (+norm) over indegree, then fill.
// ---------------------------------------------------------------------------
__global__ __launch_bounds__(1024) void scan_kernel(const int* __restrict__ indeg,
                                                    int* __restrict__ offs,
                                                    float* __restrict__ norm) {
    __shared__ int ssum[1024];
    int t = threadIdx.x;
    const int CH = 16;
    int base = t * CH;
    int s = 0;
    for (int c = 0; c < CH; ++c) {
        int idx = base + c;
        if (idx < N_NODES) s += indeg[idx];
    }
    ssum[t] = s;
    __syncthreads();
    for (int d = 1; d < 1024; d <<= 1) {
        int v = (t >= d) ? ssum[t - d] : 0;
        __syncthreads();
        ssum[t] += v;
        __syncthreads();
    }
    int run = ssum[t] - s;
    for (int c = 0; c < CH; ++c) {
        int idx = base + c;
        if (idx < N_NODES) {
            int dg = indeg[idx];
            offs[idx] = run;
            run += dg;
            norm[idx] = rsqrtf((float)(1 + dg));
        }
    }
    if (t == 1023) offs[N_NODES] = ssum[1023];
}

__global__ void fill_kernel(const int* __restrict__ nbr, const int* __restrict__ offs,
                            int* __restrict__ cursor, int* __restrict__ adj) {
    int e = blockIdx.x * blockDim.x + threadIdx.x;
    if (e < NEDGE) {
        int d   = nbr[e];
        int src = e >> 3;
        int pos = atomicAdd(&cursor[d], 1);
        adj[offs[d] + pos] = src;
    }
}

// ---------------------------------------------------------------------------
// Encoder GEMM (f32, K=16): h = x @ We + be.  blockIdx.y==4 slice instead
// performs the per-layer W transpose+split (barrier-free branch).
// ---------------------------------------------------------------------------
__global__ __launch_bounds__(256) void gemm_kernel(const float* __restrict__ A,
                                                   const float* __restrict__ B,
                                                   float* __restrict__ C,
                                                   int K,
                                                   const float* __restrict__ bias,
                                                   const float* __restrict__ Wg,
                                                   unsigned short* __restrict__ WThi,
                                                   unsigned short* __restrict__ WTlo) {
    if (blockIdx.y == 4) {       // wsplit slice: whole block, no barriers
        for (int idx = blockIdx.x * 256 + threadIdx.x; idx < LAYERS * 65536;
             idx += 64000) {
            int l = idx >> 16;
            int r = idx & 65535;
            int k = r >> 8, j = r & 255;
            float xv = Wg[idx];
            unsigned short hb = f2bf(xv);
            size_t o = (size_t)l * 65536 + j * 256 + k;
            WThi[o] = hb;
            WTlo[o] = f2bf(xv - bf2f(hb));
        }
        return;
    }
    __shared__ float As[16][68];
    __shared__ float Bs[16][64];
    int tid = threadIdx.x;
    int rowBase = blockIdx.x * 64;
    int colBase = blockIdx.y * 64;
    int rg = tid >> 4;
    int cg = tid & 15;

    int ar = tid >> 2;
    int ac = (tid & 3) * 4;
    int bk = tid >> 4;
    int bn = (tid & 15) * 4;

    float4 acc0 = {0,0,0,0}, acc1 = {0,0,0,0}, acc2 = {0,0,0,0}, acc3 = {0,0,0,0};

    for (int kb = 0; kb < K; kb += 16) {
        float4 av = *(const float4*)(A + (size_t)(rowBase + ar) * K + kb + ac);
        float4 bv = *(const float4*)(B + (size_t)(kb + bk) * HID + colBase + bn);
        __syncthreads();
        As[ac + 0][ar] = av.x; As[ac + 1][ar] = av.y;
        As[ac + 2][ar] = av.z; As[ac + 3][ar] = av.w;
        *(float4*)&Bs[bk][bn] = bv;
        __syncthreads();
#pragma unroll
        for (int k = 0; k < 16; ++k) {
            float4 a = *(const float4*)&As[k][rg * 4];
            float4 b = *(const float4*)&Bs[k][cg * 4];
            acc0.x = fmaf(a.x, b.x, acc0.x); acc0.y = fmaf(a.x, b.y, acc0.y);
            acc0.z = fmaf(a.x, b.z, acc0.z); acc0.w = fmaf(a.x, b.w, acc0.w);
            acc1.x = fmaf(a.y, b.x, acc1.x); acc1.y = fmaf(a.y, b.y, acc1.y);
            acc1.z = fmaf(a.y, b.z, acc1.z); acc1.w = fmaf(a.y, b.w, acc1.w);
            acc2.x = fmaf(a.z, b.x, acc2.x); acc2.y = fmaf(a.z, b.y, acc2.y);
            acc2.z = fmaf(a.z, b.z, acc2.z); acc2.w = fmaf(a.z, b.w, acc2.w);
            acc3.x = fmaf(a.w, b.x, acc3.x); acc3.y = fmaf(a.w, b.y, acc3.y);
            acc3.z = fmaf(a.w, b.z, acc3.z); acc3.w = fmaf(a.w, b.w, acc3.w);
        }
        __syncthreads();
    }

    int row = rowBase + rg * 4;
    int col = colBase + cg * 4;
    float4 bb = *(const float4*)(bias + col);

    float4 v;
    v.x = acc0.x + bb.x; v.y = acc0.y + bb.y; v.z = acc0.z + bb.z; v.w = acc0.w + bb.w;
    *(float4*)(C + (size_t)(row + 0) * HID + col) = v;
    v.x = acc1.x + bb.x; v.y = acc1.y + bb.y; v.z = acc1.z + bb.z; v.w = acc1.w + bb.w;
    *(float4*)(C + (size_t)(row + 1) * HID + col) = v;
    v.x = acc2.x + bb.x; v.y = acc2.y + bb.y; v.z = acc2.z + bb.z; v.w = acc2.w + bb.w;
    *(float4*)(C + (size_t)(row + 2) * HID + col) = v;
    v.x = acc3.x + bb.x; v.y = acc3.y + bb.y; v.z = acc3.z + bb.z; v.w = acc3.w + bb.w;
    *(float4*)(C + (size_t)(row + 3) * HID + col) = v;
}

// ---------------------------------------------------------------------------
// Split-bf16 MFMA GEMM: u16[M x 256] = bf16((h @ W) * norm[row]).
// 64x64 tile, grid (250,4) -> 4 blocks/CU (was 64x128, 2 blocks/CU).
// acc = hh + hl + lh in f32 (a_lo*b_lo ~ 2^-18, dropped).
// ---------------------------------------------------------------------------
__global__ __launch_bounds__(256) void mfma_gemm_kernel(const float* __restrict__ A,
                                                        const unsigned short* __restrict__ WThi,
                                                        const unsigned short* __restrict__ WTlo,
                                                        unsigned short* __restrict__ C,
                                                        const float* __restrict__ rowscale) {
    __shared__ unsigned short Ahi[64][40], Alo[64][40];
    __shared__ unsigned short Bhi[64][40], Blo[64][40];
    int tid = threadIdx.x;
    int rowBase = blockIdx.x * 64;
    int colBase = blockIdx.y * 64;
    int wave = tid >> 6;
    int lane = tid & 63;
    int fr = lane & 15;
    int fg = lane >> 4;

    int asr = tid >> 2;          // 0..63 : A row
    int ask = (tid & 3) * 8;     // A k-offset
    int bsj = tid >> 2;          // 0..63 : B col (WT row)
    int bsk = (tid & 3) * 8;     // B k-offset (8 ushorts = 16 B)

    f4v acc[4];
#pragma unroll
    for (int c = 0; c < 4; ++c) acc[c] = (f4v){0.f, 0.f, 0.f, 0.f};

    for (int kb = 0; kb < HID; kb += 32) {
        const float4* ap = (const float4*)(A + (size_t)(rowBase + asr) * HID + kb + ask);
        float4 a0 = ap[0], a1 = ap[1];
        uint4 bh0 = *(const uint4*)(WThi + (size_t)(colBase + bsj) * HID + kb + bsk);
        uint4 bl0 = *(const uint4*)(WTlo + (size_t)(colBase + bsj) * HID + kb + bsk);

        __syncthreads();
        {
            float xv[8] = {a0.x, a0.y, a0.z, a0.w, a1.x, a1.y, a1.z, a1.w};
            s8v hv, lv;
#pragma unroll
            for (int e = 0; e < 8; ++e) {
                unsigned short hb = f2bf(xv[e]);
                float hf = bf2f(hb);
                hv[e] = (short)hb;
                lv[e] = (short)f2bf(xv[e] - hf);
            }
            *(s8v*)&Ahi[asr][ask] = hv;
            *(s8v*)&Alo[asr][ask] = lv;
        }
        *(uint4*)&Bhi[bsj][bsk] = bh0;
        *(uint4*)&Blo[bsj][bsk] = bl0;
        __syncthreads();

        s8v afh = *(s8v*)&Ahi[wave * 16 + fr][fg * 8];
        s8v afl = *(s8v*)&Alo[wave * 16 + fr][fg * 8];
#pragma unroll
        for (int c = 0; c < 4; ++c) {
            s8v bfh = *(s8v*)&Bhi[c * 16 + fr][fg * 8];
            s8v bfl = *(s8v*)&Blo[c * 16 + fr][fg * 8];
            acc[c] = __builtin_amdgcn_mfma_f32_16x16x32_bf16(afh, bfh, acc[c], 0, 0, 0);
            acc[c] = __builtin_amdgcn_mfma_f32_16x16x32_bf16(afh, bfl, acc[c], 0, 0, 0);
            acc[c] = __builtin_amdgcn_mfma_f32_16x16x32_bf16(afl, bfh, acc[c], 0, 0, 0);
        }
    }

    float sc[4];
#pragma unroll
    for (int r = 0; r < 4; ++r) sc[r] = rowscale[rowBase + wave * 16 + fg * 4 + r];
#pragma unroll
    for (int c = 0; c < 4; ++c) {
        int col = colBase + c * 16 + fr;
#pragma unroll
        for (int r = 0; r < 4; ++r) {
            int row = rowBase + wave * 16 + fg * 4 + r;
            C[(size_t)row * HID + col] = f2bf(acc[c][r] * sc[r]);
        }
    }
}

// ---------------------------------------------------------------------------
// Aggregation: h[j] = relu(norm[j]*(u[j] + sum_{i->j} u[i]) + b); u is bf16.
// ---------------------------------------------------------------------------
__global__ __launch_bounds__(256) void agg_kernel(const unsigned short* __restrict__ u,
                                                  const float* __restrict__ norm,
                                                  const float* __restrict__ bias,
                                                  const int* __restrict__ offs,
                                                  const int* __restrict__ adj,
                                                  float* __restrict__ hout) {
    int node = blockIdx.x * 4 + (threadIdx.x >> 6);
    int lane = threadIdx.x & 63;
    const ushort4* up = (const ushort4*)u;
    ushort4 sv = up[(size_t)node * 64 + lane];
    float ax = bf2f(sv.x), ay = bf2f(sv.y), az = bf2f(sv.z), aw = bf2f(sv.w);
    int e0 = offs[node], e1 = offs[node + 1];
    for (int e = e0; e < e1; ++e) {
        int s = adj[e];
        ushort4 v = up[(size_t)s * 64 + lane];
        ax += bf2f(v.x); ay += bf2f(v.y); az += bf2f(v.z); aw += bf2f(v.w);
    }
    float nm = norm[node];
    float4 bb = ((const float4*)bias)[lane];
    float4 r;
    r.x = fmaxf(fmaf(nm, ax, bb.x), 0.0f);
    r.y = fmaxf(fmaf(nm, ay, bb.y), 0.0f);
    r.z = fmaxf(fmaf(nm, az, bb.z), 0.0f);
    r.w = fmaxf(fmaf(nm, aw, bb.w), 0.0f);
    ((float4*)hout)[(size_t)node * 64 + lane] = r;
}

// ---------------------------------------------------------------------------
// Mean pool and 2-layer MLP head (f32)
// ---------------------------------------------------------------------------
__global__ __launch_bounds__(256) void pool_kernel(const float* __restrict__ h,
                                                   float* __restrict__ gsum) {
    int t = threadIdx.x;
    float acc = 0.f;
    int start = blockIdx.x * 250;
    for (int i = 0; i < 250; ++i) acc += h[(size_t)(start + i) * HID + t];
    atomicAdd(&gsum[t], acc);
}

__global__ __launch_bounds__(128) void head_kernel(const float* __restrict__ gsum,
                                                   const float* __restrict__ Wp1,
                                                   const float* __restrict__ bp1,
                                                   const float* __restrict__ Wp2,
                                                   const float* __restrict__ bp2,
                                                   float* __restrict__ out) {
    __shared__ float gl[256];
    __shared__ float hid[128];
    int t = threadIdx.x;
    const float inv = 1.0f / 16000.0f;
    gl[t]       = gsum[t]       * inv;
    gl[t + 128] = gsum[t + 128] * inv;
    __syncthreads();
    float a = bp1[t];
    for (int k = 0; k < 256; ++k) a = fmaf(gl[k], Wp1[k * 128 + t], a);
    hid[t] = fmaxf(a, 0.0f);
    __syncthreads();
    float o = bp2[t];
    for (int k = 0; k < 128; ++k) o = fmaf(hid[k], Wp2[k * 128 + t], o);
    out[t] = o;
}

// ---------------------------------------------------------------------------
extern "C" void kernel_launch(void* const* d_in, const int* in_sizes, int n_in,
                              void* d_out, int out_size, void* d_ws, size_t ws_size,
                              hipStream_t stream) {
    const float* x      = (const float*)d_in[0];
    const float* coords = (const float*)d_in[1];
    const float* We     = (const float*)d_in[2];
    const float* be     = (const float*)d_in[3];
    const float* gnn_W  = (const float*)d_in[4];
    const float* gnn_b  = (const float*)d_in[5];
    const float* Wp1    = (const float*)d_in[6];
    const float* bp1    = (const float*)d_in[7];
    const float* Wp2    = (const float*)d_in[8];
    const float* bp2    = (const float*)d_in[9];
    float* out = (float*)d_out;

    char* ws = (char*)d_ws;
    // ws layout, high-water 34,311,424 B.
    // NOTE: never end a comment with a backslash (line continuation!).
    float* h     = (float*)(ws + 0);          // 16,384,000 B (f32)
    char*  ureg  = ws + 16384000;             // 16,384,000 B multi-use region
    int*   nbr   = (int*)  (ws + 32768000);   // 512,000 B
    int*   adj   = (int*)  (ws + 33280000);   // 512,000 B
    int*   indeg = (int*)  (ws + 33792000);   // 64,000 B (zero region start)
    int*   cursor= (int*)  (ws + 33856000);   // 64,000 B (zeroed)
    float* gsum  = (float*)(ws + 33920000);   // 1,024 B  (zero region end)
    int*   offs  = (int*)  (ws + 33921024);   // 64,004 B
    float* norm  = (float*)(ws + 33985152);   // 64,000 B
    float4* cand = (float4*)(ws + 34049280);  // 262,144 B

    // ureg during kNN: minv, cnt.  During GNN: u16, WThi, WTlo.
    unsigned short* u16 = (unsigned short*)ureg;              // 8,192,000 B
    float*  minv = (float*)ureg;                              // 8,192,000 B
    int*    cnt  = (int*)  (ureg + 8256000);                  // 256,000 B
    unsigned short* WThi = (unsigned short*)(ureg + 8512000); // 393,216 B
    unsigned short* WTlo = (unsigned short*)(ureg + 8905216); // 393,216 B
    float2* cl   = (float2*)h;                                // 16,384,000 B (kNN phase)

    prep_kernel<<<NPAD / 256, 256, 0, stream>>>(coords, cand, indeg);
    knn_min_kernel<<<dim3(N_NODES / 64, PARTS), 256, 0, stream>>>(coords, cand, minv);
    knn_collect_kernel<<<dim3(N_NODES / 64, PARTS), 256, 0, stream>>>(coords, cand, minv, cnt, cl);
    knn_select_kernel<<<(N_NODES + 255) / 256, 256, 0, stream>>>(coords, cand, cl, cnt, nbr, indeg);

    scan_kernel<<<1, 1024, 0, stream>>>(indeg, offs, norm);
    fill_kernel<<<(NEDGE + 255) / 256, 256, 0, stream>>>(nbr, offs, cursor, adj);

    // encoder GEMM (y=0..3) + wsplit slice (y=4) in one dispatch
    gemm_kernel<<<dim3(N_NODES / 64, 5), 256, 0, stream>>>(x, We, h, F_IN, be,
                                                           gnn_W, WThi, WTlo);
    for (int l = 0; l < LAYERS; ++l) {
        mfma_gemm_kernel<<<dim3(N_NODES / 64, 4), 256, 0, stream>>>(
            h, WThi + (size_t)l * 65536, WTlo + (size_t)l * 65536, u16, norm);
        agg_kernel<<<N_NODES / 4, 256, 0, stream>>>(u16, norm, gnn_b + (size_t)l * HID,
                                                    offs, adj, h);
    }
    pool_kernel<<<64, 256, 0, stream>>>(h, gsum);
    head_kernel<<<1, 128, 0, stream>>>(gsum, Wp1, bp1, Wp2, bp2, out);
}